// Round 6
// baseline (2641.334 us; speedup 1.0000x reference)
//
#include <hip/hip_runtime.h>
#include <math.h>

namespace {

typedef __bf16 bf16_t;
typedef bf16_t bf16x8 __attribute__((ext_vector_type(8)));
typedef float floatx4 __attribute__((ext_vector_type(4)));

constexpr int kN = 1024;      // tokens
constexpr int kM = 64;        // multiplicity
constexpr int kP = 64;        // PE dim
constexpr float kEps = 1e-5f;
constexpr int kFN = 1024;     // FFT length
constexpr size_t kHOFF = 16777216;   // bf16 elems per h plane (65536*256)

__device__ __forceinline__ float sigmoidf(float v) { return 1.0f / (1.0f + expf(-v)); }

__device__ __forceinline__ floatx4 mfma16(bf16x8 a, bf16x8 b, floatx4 c) {
  return __builtin_amdgcn_mfma_f32_16x16x32_bf16(a, b, c, 0, 0, 0);
}

// 3-term split product: acc += (ah+al)*(bh+bl) dropping al*bl
__device__ __forceinline__ void fma3(floatx4& acc, bf16x8 ah, bf16x8 al,
                                     bf16x8 bh, bf16x8 bl) {
  acc = mfma16(ah, bh, acc);
  acc = mfma16(ah, bl, acc);
  acc = mfma16(al, bh, acc);
}

// load 8 contiguous fp32 (LDS), split into hi/lo bf16 fragments
__device__ __forceinline__ void load_split8(const float* p, bf16x8& hi, bf16x8& lo) {
  const float4 u = *(const float4*)p;
  const float4 v = *(const float4*)(p + 4);
  const float a[8] = {u.x, u.y, u.z, u.w, v.x, v.y, v.z, v.w};
#pragma unroll
  for (int i = 0; i < 8; ++i) {
    const bf16_t h_ = (bf16_t)a[i];
    hi[i] = h_;
    lo[i] = (bf16_t)(a[i] - (float)h_);
  }
}

union U2 { uint2 u; bf16_t b[4]; };

// ---------------------------------------------------------------- init
// s0[n, m] = sum_p (pe[n,p] + tok_emb[tt[n],p]) * Wf[p,m]
__global__ void k_s0(const float* __restrict__ tok_emb, const float* __restrict__ Wf,
                     float* __restrict__ s0) {
  __shared__ float f[kP];
  const int n = blockIdx.x;
  const int t = threadIdx.x;                       // 64 threads
  const int tt = (n == kN - 1) ? 2 : (n & 1);
  const int j = t >> 1;
  const float cexp = (float)(-9.210340371976184 / 64.0);   // -ln(10000)/P
  const float divj = expf((float)(2 * j) * cexp);
  const float ang = (float)n * divj;
  const float pe = (t & 1) ? cosf(ang) : sinf(ang);
  f[t] = pe + tok_emb[tt * kP + t];
  __syncthreads();
  float acc = 0.0f;
#pragma unroll 8
  for (int p = 0; p < kP; ++p) acc = fmaf(f[p], Wf[p * kM + t], acc);
  s0[n * kM + t] = acc;
}

// h planes[r, m, 0..3] = (s0[n,m], x[r]*wv[m])
__global__ void k_h0(const float* __restrict__ x, const float* __restrict__ wv,
                     const float* __restrict__ s0, bf16_t* __restrict__ hsh) {
  const int idx = blockIdx.x * 256 + threadIdx.x;  // r*64 + m
  const int r = idx >> 6;
  const int m = idx & 63;
  const int n = r & (kN - 1);
  const float w = wv[m];
  float f[4];
  f[0] = s0[n * kM + m];
  f[1] = x[r * 3 + 0] * w;
  f[2] = x[r * 3 + 1] * w;
  f[3] = x[r * 3 + 2] * w;
  U2 hi, lo;
#pragma unroll
  for (int i = 0; i < 4; ++i) {
    const bf16_t h_ = (bf16_t)f[i];
    hi.b[i] = h_; lo.b[i] = (bf16_t)(f[i] - (float)h_);
  }
  const size_t e = (size_t)idx * 4;
  *(uint2*)(hsh + e) = hi.u;
  *(uint2*)(hsh + kHOFF + e) = lo.u;
}

// ---------------------------------------------------------------- weight prep (hi/lo planes)
// wall planes: 0=Wq_hi 1=Wq_lo 2=Wk_hi 3=Wk_lo 4=Wv_hi 5=Wv_lo, each [c][k] 384x256
__global__ void k_wqkv(const float* __restrict__ Wq, const float* __restrict__ Wk,
                       const float* __restrict__ Wv, int H, bf16_t* __restrict__ wall) {
  const int c = blockIdx.x;    // 0..383
  const int k = threadIdx.x;   // 0..255
  const bool ok = c < H;
  const float wq = ok ? Wq[k * H + c] : 0.f;
  const float wk = ok ? Wk[k * H + c] : 0.f;
  const float wv = ok ? Wv[k * H + c] : 0.f;
  const bf16_t qh = (bf16_t)wq, kh = (bf16_t)wk, vh = (bf16_t)wv;
  const int o = c * 256 + k;
  wall[0 * 98304 + o] = qh; wall[1 * 98304 + o] = (bf16_t)(wq - (float)qh);
  wall[2 * 98304 + o] = kh; wall[3 * 98304 + o] = (bf16_t)(wk - (float)kh);
  wall[4 * 98304 + o] = vh; wall[5 * 98304 + o] = (bf16_t)(wv - (float)vh);
}

__global__ void k_wo(const float* __restrict__ Wo, int H,
                     bf16_t* __restrict__ Wo_hi, bf16_t* __restrict__ Wo_lo) {
  const int d = blockIdx.x;    // 0..255
  const int c = threadIdx.x;   // 0..383
  const float w = (c < H) ? Wo[c * 256 + d] : 0.f;
  const bf16_t hi = (bf16_t)w;
  Wo_hi[d * 384 + c] = hi;
  Wo_lo[d * 384 + c] = (bf16_t)(w - (float)hi);
}

// block-diagonal expanded reg_linear weight, transposed: Bt[col][row]
__global__ void k_bt(const float* __restrict__ W0, const float* __restrict__ W1,
                     bf16_t* __restrict__ Bt_hi, bf16_t* __restrict__ Bt_lo) {
  const int col = blockIdx.x, row = threadIdx.x;
  const int k = col >> 2, ck = col & 3, m = row >> 2, cm = row & 3;
  float v = 0.f;
  if (cm == ck) v = (ck == 0 ? W0 : W1)[m * 64 + k];
  const bf16_t hi = (bf16_t)v;
  Bt_hi[col * 256 + row] = hi;
  Bt_lo[col * 256 + row] = (bf16_t)(v - (float)hi);
}

// ---------------------------------------------------------------- FFT (radix-2, no bit-reversal)
__device__ void fft_build_tw(float2* tw) {
  for (int j = threadIdx.x; j < kFN / 2; j += 256) {
    float s, c;
    sincosf(-6.283185307179586f * (float)j / (float)kFN, &s, &c);
    tw[j].x = c; tw[j].y = s;
  }
}

// forward DIF: natural in -> bit-reversed out
__device__ void fft_dif(float2* z, const float2* tw) {
  for (int span = kFN / 2; span >= 1; span >>= 1) {
    const int tm = (kFN / 2) / span;
    __syncthreads();
#pragma unroll
    for (int it = 0; it < 2; ++it) {
      const int p = threadIdx.x + it * 256;
      const int k = p & (span - 1);
      const int i = ((p & ~(span - 1)) << 1) | k;
      const float2 u = z[i];
      const float2 v = z[i + span];
      const float2 w = tw[k * tm];
      float2 sum, d, o;
      sum.x = u.x + v.x; sum.y = u.y + v.y;
      d.x = u.x - v.x;   d.y = u.y - v.y;
      o.x = d.x * w.x - d.y * w.y;
      o.y = d.x * w.y + d.y * w.x;
      z[i] = sum;
      z[i + span] = o;
    }
  }
}

// inverse DIT: bit-reversed in -> natural out (caller scales by 1/N)
__device__ void fft_dit_inv(float2* z, const float2* tw) {
  for (int span = 1; span <= kFN / 2; span <<= 1) {
    const int tm = (kFN / 2) / span;
    __syncthreads();
#pragma unroll
    for (int it = 0; it < 2; ++it) {
      const int p = threadIdx.x + it * 256;
      const int k = p & (span - 1);
      const int i = ((p & ~(span - 1)) << 1) | k;
      const float2 w = tw[k * tm];         // conj used below
      const float2 v = z[i + span];
      float2 tv, a, bq;
      tv.x = v.x * w.x + v.y * w.y;
      tv.y = v.y * w.x - v.x * w.y;
      const float2 u = z[i];
      a.x = u.x + tv.x;  a.y = u.y + tv.y;
      bq.x = u.x - tv.x; bq.y = u.y - tv.y;
      z[i] = a;
      z[i + span] = bq;
    }
  }
}

// filter spectrum, stored in DIF (bit-reversed) order; one block per channel
__global__ __launch_bounds__(256) void k_kf(const float* __restrict__ filt, int H,
                                            float2* __restrict__ kf) {
  __shared__ float2 z[kFN];
  __shared__ float2 tw[kFN / 2];
  const int c = blockIdx.x;
  fft_build_tw(tw);
  for (int n = threadIdx.x; n < kFN; n += 256) {
    z[n].x = filt[n * H + c];
    z[n].y = 0.0f;
  }
  fft_dif(z, tw);
  __syncthreads();
  for (int j = threadIdx.x; j < kFN; j += 256) kf[c * kFN + j] = z[j];
}

// circular conv in-place on kv_t rows; one block per (b, c)
__global__ __launch_bounds__(256) void k_conv(float* kvt, const float2* __restrict__ kf, int H) {
  __shared__ float2 z[kFN];
  __shared__ float2 tw[kFN / 2];
  const int row = blockIdx.x;              // b*H + c
  const int c = row % H;
  float* sig = kvt + (size_t)row * kFN;
  fft_build_tw(tw);
  for (int n = threadIdx.x; n < kFN; n += 256) {
    z[n].x = sig[n];
    z[n].y = 0.0f;
  }
  fft_dif(z, tw);
  __syncthreads();
  for (int j = threadIdx.x; j < kFN; j += 256) {
    const float2 a = z[j];
    const float2 b = kf[c * kFN + j];
    float2 o;
    o.x = a.x * b.x - a.y * b.y;
    o.y = a.x * b.y + a.y * b.x;
    z[j] = o;
  }
  fft_dit_inv(z, tw);
  __syncthreads();
  const float s = 1.0f / (float)kFN;
  for (int n = threadIdx.x; n < kFN; n += 256) sig[n] = z[n].x * s;
}

// ---------------------------------------------------------------- GEMM 1 (split MFMA): q/k/v
// A from hsh planes (no VALU split), register double-buffered
__global__ __launch_bounds__(256, 2) void k_qkv(const bf16_t* __restrict__ hsh,
    const bf16_t* __restrict__ wall, int H,
    float* __restrict__ qt, float* __restrict__ kvt) {
  const int t = threadIdx.x;
  const int lane = t & 63, wave = t >> 6;
  const int l15 = lane & 15, quad = lane >> 4;
  const int c0 = blockIdx.x * 64, r0 = blockIdx.y * 64;
  const int wr = (wave & 1) * 32, wc = (wave >> 1) * 32;
  floatx4 aq[2][2] = {}, ak_[2][2] = {}, av_[2][2] = {};
  const bf16_t* Ah = hsh + (size_t)(r0 + wr + l15) * 256 + quad * 8;
  const bf16_t* Bp = wall + (size_t)(c0 + wc + l15) * 256 + quad * 8;
  bf16x8 A[2][4], B[2][12];
#pragma unroll
  for (int u = 0; u < 4; ++u)
    A[0][u] = *(const bf16x8*)(Ah + (u & 1) * kHOFF + (u >> 1) * (16 * 256));
#pragma unroll
  for (int u = 0; u < 12; ++u) {
    const int w = u >> 2, q2 = u & 3;
    B[0][u] = *(const bf16x8*)(Bp + (size_t)(w * 2 + (q2 & 1)) * 98304 + (q2 >> 1) * (16 * 256));
  }
#pragma unroll
  for (int kt = 0; kt < 8; ++kt) {
    const int cur = kt & 1, nxt = cur ^ 1;
    if (kt < 7) {
      const int kk = (kt + 1) * 32;
#pragma unroll
      for (int u = 0; u < 4; ++u)
        A[nxt][u] = *(const bf16x8*)(Ah + kk + (u & 1) * kHOFF + (u >> 1) * (16 * 256));
#pragma unroll
      for (int u = 0; u < 12; ++u) {
        const int w = u >> 2, q2 = u & 3;
        B[nxt][u] = *(const bf16x8*)(Bp + kk + (size_t)(w * 2 + (q2 & 1)) * 98304 +
                                     (q2 >> 1) * (16 * 256));
      }
    }
    const bf16x8 ah0 = A[cur][0], al0 = A[cur][1], ah1 = A[cur][2], al1 = A[cur][3];
    fma3(aq[0][0], ah0, al0, B[cur][0], B[cur][1]);
    fma3(aq[0][1], ah0, al0, B[cur][2], B[cur][3]);
    fma3(aq[1][0], ah1, al1, B[cur][0], B[cur][1]);
    fma3(aq[1][1], ah1, al1, B[cur][2], B[cur][3]);
    fma3(ak_[0][0], ah0, al0, B[cur][4], B[cur][5]);
    fma3(ak_[0][1], ah0, al0, B[cur][6], B[cur][7]);
    fma3(ak_[1][0], ah1, al1, B[cur][4], B[cur][5]);
    fma3(ak_[1][1], ah1, al1, B[cur][6], B[cur][7]);
    fma3(av_[0][0], ah0, al0, B[cur][8], B[cur][9]);
    fma3(av_[0][1], ah0, al0, B[cur][10], B[cur][11]);
    fma3(av_[1][0], ah1, al1, B[cur][8], B[cur][9]);
    fma3(av_[1][1], ah1, al1, B[cur][10], B[cur][11]);
  }
  const int b = r0 >> 10;
  const int n0 = r0 & 1023;
#pragma unroll
  for (int j = 0; j < 2; ++j) {
    const int c = c0 + wc + j * 16 + l15;
    if (c < H) {
      const size_t rb = (((size_t)(b * H + c)) << 10) + n0 + wr + quad * 4;
#pragma unroll
      for (int i = 0; i < 2; ++i) {
        float4 p;
        p.x = aq[i][j][0]; p.y = aq[i][j][1];
        p.z = aq[i][j][2]; p.w = aq[i][j][3];
        *(float4*)(qt + rb + i * 16) = p;
      }
#pragma unroll
      for (int i = 0; i < 2; ++i) {
        float4 p;
        p.x = ak_[i][j][0] * av_[i][j][0];
        p.y = ak_[i][j][1] * av_[i][j][1];
        p.z = ak_[i][j][2] * av_[i][j][2];
        p.w = ak_[i][j][3] * av_[i][j][3];
        *(float4*)(kvt + rb + i * 16) = p;
      }
    }
  }
}

// ---------------------------------------------------------------- GEMM 2 (split MFMA): h += (q*conv) @ Wo
// A = qt*kvt (c-major), staged+transposed through LDS per 32-wide K chunk
__global__ __launch_bounds__(256) void k_mix(const float* __restrict__ qt,
    const float* __restrict__ kvt, int H, int KT,
    const bf16_t* __restrict__ Wo_hi, const bf16_t* __restrict__ Wo_lo,
    bf16_t* __restrict__ hsh) {
  __shared__ float smem[4352];             // As: 64 n x 36 (2304) ; epilogue: 64 x 68
  const int t = threadIdx.x;
  const int lane = t & 63, wave = t >> 6;
  const int l15 = lane & 15, quad = lane >> 4;
  const int d0 = blockIdx.x * 64, r0 = blockIdx.y * 64;
  const int b = r0 >> 10, n0 = r0 & 1023;
  const int wr = (wave & 1) * 32, wc = (wave >> 1) * 32;
  floatx4 acc[2][2] = {};
  const int cl = t >> 3, n8 = (t & 7) * 8;
  const size_t boff = (size_t)(d0 + wc + l15) * 384 + quad * 8;
  for (int kt = 0; kt < KT; ++kt) {
    const int ck0 = kt * 32;
    __syncthreads();
    {
      const int c = ck0 + cl;
      float p[8] = {};
      if (c < H) {
        const size_t o = (((size_t)(b * H + c)) << 10) + n0 + n8;
        const float4 q0 = *(const float4*)(qt + o);
        const float4 q1 = *(const float4*)(qt + o + 4);
        const float4 v0 = *(const float4*)(kvt + o);
        const float4 v1 = *(const float4*)(kvt + o + 4);
        p[0] = q0.x * v0.x; p[1] = q0.y * v0.y; p[2] = q0.z * v0.z; p[3] = q0.w * v0.w;
        p[4] = q1.x * v1.x; p[5] = q1.y * v1.y; p[6] = q1.z * v1.z; p[7] = q1.w * v1.w;
      }
#pragma unroll
      for (int u = 0; u < 8; ++u) smem[(n8 + u) * 36 + cl] = p[u];
    }
    __syncthreads();
    bf16x8 ah0, al0, ah1, al1;
    load_split8(smem + (wr + l15) * 36 + quad * 8, ah0, al0);
    load_split8(smem + (wr + 16 + l15) * 36 + quad * 8, ah1, al1);
    const bf16x8 bh0 = *(const bf16x8*)(Wo_hi + boff + ck0);
    const bf16x8 bh1 = *(const bf16x8*)(Wo_hi + boff + 16 * 384 + ck0);
    const bf16x8 bl0 = *(const bf16x8*)(Wo_lo + boff + ck0);
    const bf16x8 bl1 = *(const bf16x8*)(Wo_lo + boff + 16 * 384 + ck0);
    fma3(acc[0][0], ah0, al0, bh0, bl0); fma3(acc[0][1], ah0, al0, bh1, bl1);
    fma3(acc[1][0], ah1, al1, bh0, bl0); fma3(acc[1][1], ah1, al1, bh1, bl1);
  }
  __syncthreads();
#pragma unroll
  for (int i = 0; i < 2; ++i)
#pragma unroll
    for (int j = 0; j < 2; ++j)
#pragma unroll
      for (int r = 0; r < 4; ++r)
        smem[(wr + i * 16 + quad * 4 + r) * 68 + wc + j * 16 + l15] = acc[i][j][r];
  __syncthreads();
  const int nl = t >> 2, q4 = t & 3;
  const size_t gi = (size_t)(r0 + nl) * 256 + d0 + q4 * 16;
#pragma unroll
  for (int u = 0; u < 4; ++u) {
    const size_t e = gi + u * 4;
    U2 uh, ul;
    uh.u = *(const uint2*)(hsh + e);
    ul.u = *(const uint2*)(hsh + kHOFF + e);
    U2 oh, ol;
#pragma unroll
    for (int i = 0; i < 4; ++i) {
      const float f = (float)uh.b[i] + (float)ul.b[i] + smem[nl * 68 + q4 * 16 + u * 4 + i];
      const bf16_t h_ = (bf16_t)f;
      oh.b[i] = h_; ol.b[i] = (bf16_t)(f - (float)h_);
    }
    *(uint2*)(hsh + e) = oh.u;
    *(uint2*)(hsh + kHOFF + e) = ol.u;
  }
}

// ---------------------------------------------------------------- GEMM 3 (split MFMA): reg_linear + BN partials
__global__ __launch_bounds__(256) void k_reg(const bf16_t* __restrict__ hsh,
    const bf16_t* __restrict__ Bt,
    float* __restrict__ y, float* __restrict__ partial) {
  __shared__ float sm[64 * 68];
  __shared__ float red[128];
  const int t = threadIdx.x;
  const int lane = t & 63, wave = t >> 6;
  const int l15 = lane & 15, quad = lane >> 4;
  const int c0 = blockIdx.x * 64, r0 = blockIdx.y * 64;
  const int wr = (wave & 1) * 32, wc = (wave >> 1) * 32;
  floatx4 acc[2][2] = {};
  const bf16_t* Ah = hsh + (size_t)(r0 + wr + l15) * 256 + quad * 8;
  const bf16_t* Bp = Bt + (size_t)(c0 + wc + l15) * 256 + quad * 8;
  bf16x8 A[2][4], B[2][4];
#pragma unroll
  for (int u = 0; u < 4; ++u) {
    A[0][u] = *(const bf16x8*)(Ah + (u & 1) * kHOFF + (u >> 1) * (16 * 256));
    B[0][u] = *(const bf16x8*)(Bp + (u & 1) * 65536 + (u >> 1) * (16 * 256));
  }
#pragma unroll
  for (int kt = 0; kt < 8; ++kt) {
    const int cur = kt & 1, nxt = cur ^ 1;
    if (kt < 7) {
      const int kk = (kt + 1) * 32;
#pragma unroll
      for (int u = 0; u < 4; ++u) {
        A[nxt][u] = *(const bf16x8*)(Ah + kk + (u & 1) * kHOFF + (u >> 1) * (16 * 256));
        B[nxt][u] = *(const bf16x8*)(Bp + kk + (u & 1) * 65536 + (u >> 1) * (16 * 256));
      }
    }
    fma3(acc[0][0], A[cur][0], A[cur][1], B[cur][0], B[cur][1]);
    fma3(acc[0][1], A[cur][0], A[cur][1], B[cur][2], B[cur][3]);
    fma3(acc[1][0], A[cur][2], A[cur][3], B[cur][0], B[cur][1]);
    fma3(acc[1][1], A[cur][2], A[cur][3], B[cur][2], B[cur][3]);
  }
  // per-column sum of squares (lane holds one column per j)
#pragma unroll
  for (int j = 0; j < 2; ++j) {
    float s = 0.f;
#pragma unroll
    for (int i = 0; i < 2; ++i)
#pragma unroll
      for (int r = 0; r < 4; ++r)
        s = fmaf(acc[i][j][r], acc[i][j][r], s);
    s += __shfl_down(s, 32);
    s += __shfl_down(s, 16);
    if (lane < 16) red[wave * 32 + j * 16 + lane] = s;
  }
#pragma unroll
  for (int i = 0; i < 2; ++i)
#pragma unroll
    for (int j = 0; j < 2; ++j)
#pragma unroll
      for (int r = 0; r < 4; ++r)
        sm[(wr + i * 16 + quad * 4 + r) * 68 + wc + j * 16 + l15] = acc[i][j][r];
  __syncthreads();
  const int nl = t >> 2, q4 = t & 3;
  const size_t gi = (size_t)(r0 + nl) * 256 + c0 + q4 * 16;
#pragma unroll
  for (int u = 0; u < 4; ++u) {
    float4 yv;
    yv.x = sm[nl * 68 + q4 * 16 + u * 4 + 0];
    yv.y = sm[nl * 68 + q4 * 16 + u * 4 + 1];
    yv.z = sm[nl * 68 + q4 * 16 + u * 4 + 2];
    yv.w = sm[nl * 68 + q4 * 16 + u * 4 + 3];
    *(float4*)(y + gi + u * 4) = yv;
  }
  if (t < 64) {
    const int w0 = (t >= 32) ? 2 : 0;
    const float v = red[w0 * 32 + (t & 31)] + red[(w0 + 1) * 32 + (t & 31)];
    partial[(size_t)blockIdx.y * 256 + c0 + t] = v;   // race-free: one slot per column
  }
}

// reduce partials over 1024 r-blocks -> stats[128] (s-norms [0,64), v-norms [64,128))
__global__ __launch_bounds__(1024) void k_stat(const float* __restrict__ partial,
                                               float* __restrict__ st) {
  __shared__ float acc[4][256];
  __shared__ float tot[256];
  const int t = threadIdx.x;
  const int slot = t & 255, g = t >> 8;
  float s = 0.f;
  for (int r = g; r < 1024; r += 4) s += partial[(size_t)r * 256 + slot];
  acc[g][slot] = s;
  __syncthreads();
  if (t < 256) tot[t] = acc[0][t] + acc[1][t] + acc[2][t] + acc[3][t];
  __syncthreads();
  if (t < 64) {
    st[t] = tot[4 * t];
    st[64 + t] = tot[4 * t + 1] + tot[4 * t + 2] + tot[4 * t + 3];
  }
}

// ---------------------------------------------------------------- BN + norm-activation + residual
__global__ void k_bnact(const float* __restrict__ y, const float* __restrict__ stats,
    const float* __restrict__ g0, const float* __restrict__ g1, bf16_t* __restrict__ hsh) {
  const int idx = blockIdx.x * 256 + threadIdx.x;  // r*64 + m
  const int m = idx & 63;
  const float inv0 = g0[m] / sqrtf(stats[m] * (1.0f / 65536.0f) + kEps);
  const float inv1 = g1[m] / sqrtf(stats[64 + m] * (1.0f / 65536.0f) + kEps);
  const float4 v = ((const float4*)y)[idx];
  const float s = v.x * inv0;
  const float vx = v.y * inv1, vy = v.z * inv1, vz = v.w * inv1;
  const float so = s * sigmoidf(fabsf(s));
  const float vn = sqrtf(fmaf(vx, vx, fmaf(vy, vy, vz * vz)) + kEps);
  const float gv = sigmoidf(vn);
  const size_t e = (size_t)idx * 4;
  U2 uh, ul;
  uh.u = *(const uint2*)(hsh + e);
  ul.u = *(const uint2*)(hsh + kHOFF + e);
  float f[4];
  f[0] = (float)uh.b[0] + (float)ul.b[0] + so;
  f[1] = (float)uh.b[1] + (float)ul.b[1] + vx * gv;
  f[2] = (float)uh.b[2] + (float)ul.b[2] + vy * gv;
  f[3] = (float)uh.b[3] + (float)ul.b[3] + vz * gv;
  U2 oh, ol;
#pragma unroll
  for (int i = 0; i < 4; ++i) {
    const bf16_t h_ = (bf16_t)f[i];
    oh.b[i] = h_; ol.b[i] = (bf16_t)(f[i] - (float)h_);
  }
  *(uint2*)(hsh + e) = oh.u;
  *(uint2*)(hsh + kHOFF + e) = ol.u;
}

// ---------------------------------------------------------------- mean-pool + einsum
__global__ __launch_bounds__(256) void k_pool(const bf16_t* __restrict__ hsh,
    const float* __restrict__ w_out, float* __restrict__ out) {
  __shared__ float r0s[256], r1s[256], r2s[256];
  const int b = blockIdx.x;
  const int t = threadIdx.x;
  float p0 = 0, p1 = 0, p2 = 0;
  for (int idx = t; idx < kN * kM; idx += 256) {
    const int m = idx & 63;
    const size_t e = ((size_t)b * (kN * kM) + idx) * 4;
    U2 uh, ul;
    uh.u = *(const uint2*)(hsh + e);
    ul.u = *(const uint2*)(hsh + kHOFF + e);
    const float w = w_out[m];
    p0 = fmaf((float)uh.b[1] + (float)ul.b[1], w, p0);
    p1 = fmaf((float)uh.b[2] + (float)ul.b[2], w, p1);
    p2 = fmaf((float)uh.b[3] + (float)ul.b[3], w, p2);
  }
  r0s[t] = p0; r1s[t] = p1; r2s[t] = p2;
  __syncthreads();
  for (int s = 128; s > 0; s >>= 1) {
    if (t < s) { r0s[t] += r0s[t + s]; r1s[t] += r1s[t + s]; r2s[t] += r2s[t + s]; }
    __syncthreads();
  }
  if (t == 0) {
    out[b * 3 + 0] = r0s[0] * (1.0f / kN);
    out[b * 3 + 1] = r1s[0] * (1.0f / kN);
    out[b * 3 + 2] = r2s[0] * (1.0f / kN);
  }
}

} // namespace

extern "C" void kernel_launch(void* const* d_in, const int* in_sizes, int n_in,
                              void* d_out, int out_size, void* d_ws, size_t ws_size,
                              hipStream_t stream) {
  const float* x       = (const float*)d_in[0];
  const float* tok_emb = (const float*)d_in[1];
  const float* Wf      = (const float*)d_in[2];
  const float* wv      = (const float*)d_in[3];
  const float* w_out   = (const float*)d_in[4];

  float* ws    = (float*)d_ws;
  bf16_t* hsh  = (bf16_t*)ws;                          // 2 planes x 16,777,216 bf16 = 16,777,216 fl
  float*  kvt  = ws + 16777216;                        // 23,592,960 fl
  float*  qt   = kvt + 23592960;                       // 23,592,960 fl
  float*  y    = qt;                                   // alias: qt dead once k_mix done
  float*  partial = qt + 20000000;                     // 262,144 fl inside qt region, past y end
  float*  s0   = qt + 23592960;                        //     65,536 fl
  float*  kf   = s0 + 65536;                           //    737,280 fl
  bf16_t* wall = (bf16_t*)(kf + 737280);               // 6 x 98304 bf16 = 294,912 fl
  bf16_t* Wo_hi = wall + 6 * 98304;                    // 98,304 bf16
  bf16_t* Wo_lo = Wo_hi + 98304;
  bf16_t* Bt_hi = Wo_lo + 98304;                       // 65,536 bf16 (lo contiguous after)
  bf16_t* Bt_lo = Bt_hi + 65536;
  float* stats  = (float*)(Bt_lo + 65536);             // 384 fl

  k_s0<<<kN, 64, 0, stream>>>(tok_emb, Wf, s0);
  k_h0<<<(65536 * 64) / 256, 256, 0, stream>>>(x, wv, s0, hsh);

  for (int l = 0; l < 3; ++l) {
    const float* Wq   = (const float*)d_in[5 + 9 * l + 0];
    const float* Wk   = (const float*)d_in[5 + 9 * l + 1];
    const float* Wv   = (const float*)d_in[5 + 9 * l + 2];
    const float* filt = (const float*)d_in[5 + 9 * l + 3];
    const float* Wo   = (const float*)d_in[5 + 9 * l + 4];
    const float* Wm0  = (const float*)d_in[5 + 9 * l + 5];
    const float* Wm1  = (const float*)d_in[5 + 9 * l + 6];
    const float* g0   = (const float*)d_in[5 + 9 * l + 7];
    const float* g1   = (const float*)d_in[5 + 9 * l + 8];
    const int H = (l == 2) ? 160 : 360;
    const int gy = (H + 63) / 64;                      // 6 or 3
    const int KT = gy * 2;                             // K chunks of 32 (zero-padded weights)
    float* st = stats + l * 128;

    k_wqkv<<<384, 256, 0, stream>>>(Wq, Wk, Wv, H, wall);
    k_wo<<<256, 384, 0, stream>>>(Wo, H, Wo_hi, Wo_lo);
    k_bt<<<256, 256, 0, stream>>>(Wm0, Wm1, Bt_hi, Bt_lo);
    k_kf<<<H, 256, 0, stream>>>(filt, H, (float2*)kf);
    k_qkv<<<dim3(gy, 1024), 256, 0, stream>>>(hsh, wall, H, qt, kvt);
    k_conv<<<64 * H, 256, 0, stream>>>(kvt, (const float2*)kf, H);
    k_mix<<<dim3(4, 1024), 256, 0, stream>>>(qt, kvt, H, KT, Wo_hi, Wo_lo, hsh);
    k_reg<<<dim3(4, 1024), 256, 0, stream>>>(hsh, Bt_hi, y, partial);
    k_stat<<<1, 1024, 0, stream>>>(partial, st);
    k_bnact<<<(65536 * 64) / 256, 256, 0, stream>>>(y, st, g0, g1, hsh);
  }

  k_pool<<<64, 256, 0, stream>>>(hsh, w_out, (float*)d_out);
}

// Round 7
// 1856.781 us; speedup vs baseline: 1.4225x; 1.4225x over previous
//
#include <hip/hip_runtime.h>
#include <math.h>

namespace {

typedef __bf16 bf16_t;
typedef bf16_t bf16x8 __attribute__((ext_vector_type(8)));
typedef float floatx4 __attribute__((ext_vector_type(4)));

constexpr int kN = 1024;      // tokens
constexpr int kM = 64;        // multiplicity
constexpr int kP = 64;        // PE dim
constexpr float kEps = 1e-5f;
constexpr int kFN = 1024;     // FFT length

__device__ __forceinline__ float sigmoidf(float v) { return 1.0f / (1.0f + expf(-v)); }

__device__ __forceinline__ floatx4 mfma16(bf16x8 a, bf16x8 b, floatx4 c) {
  return __builtin_amdgcn_mfma_f32_16x16x32_bf16(a, b, c, 0, 0, 0);
}

// 3-term split product: acc += (ah+al)*(bh+bl) dropping al*bl
__device__ __forceinline__ void fma3(floatx4& acc, bf16x8 ah, bf16x8 al,
                                     bf16x8 bh, bf16x8 bl) {
  acc = mfma16(ah, bh, acc);
  acc = mfma16(ah, bl, acc);
  acc = mfma16(al, bh, acc);
}

// load 8 contiguous fp32 (LDS), split into hi/lo bf16 fragments
__device__ __forceinline__ void load_split8(const float* p, bf16x8& hi, bf16x8& lo) {
  const float4 u = *(const float4*)p;
  const float4 v = *(const float4*)(p + 4);
  const float a[8] = {u.x, u.y, u.z, u.w, v.x, v.y, v.z, v.w};
#pragma unroll
  for (int i = 0; i < 8; ++i) {
    const bf16_t h_ = (bf16_t)a[i];
    hi[i] = h_;
    lo[i] = (bf16_t)(a[i] - (float)h_);
  }
}

union U4 { uint4 u; bf16_t b[8]; };

// async 16B/lane global->LDS DMA (wave-uniform LDS base + lane*16 scatter)
__device__ __forceinline__ void glds16(const bf16_t* g, bf16_t* l) {
  __builtin_amdgcn_global_load_lds(
      (const __attribute__((address_space(1))) void*)g,
      (__attribute__((address_space(3))) void*)l, 16, 0, 0);
}

// hsh fragment-major index for (row r, 8-elem group d8), hi plane (lo = +512)
// layout: [rb(1024)][kc(8)][rgrp(4)][p(2)][quad(4)][rl(16)][off(8)]
__device__ __forceinline__ size_t hidx(int r, int d8) {
  const int rb = r >> 6, rr = r & 63;
  return (size_t)(rb * 8 + (d8 >> 2)) * 4096 + (rr >> 4) * 1024 + (d8 & 3) * 128 + (rr & 15) * 8;
}

// ---------------------------------------------------------------- init
// s0[n, m] = sum_p (pe[n,p] + tok_emb[tt[n],p]) * Wf[p,m]
__global__ void k_s0(const float* __restrict__ tok_emb, const float* __restrict__ Wf,
                     float* __restrict__ s0) {
  __shared__ float f[kP];
  const int n = blockIdx.x;
  const int t = threadIdx.x;                       // 64 threads
  const int tt = (n == kN - 1) ? 2 : (n & 1);
  const int j = t >> 1;
  const float cexp = (float)(-9.210340371976184 / 64.0);   // -ln(10000)/P
  const float divj = expf((float)(2 * j) * cexp);
  const float ang = (float)n * divj;
  const float pe = (t & 1) ? cosf(ang) : sinf(ang);
  f[t] = pe + tok_emb[tt * kP + t];
  __syncthreads();
  float acc = 0.0f;
#pragma unroll 8
  for (int p = 0; p < kP; ++p) acc = fmaf(f[p], Wf[p * kM + t], acc);
  s0[n * kM + t] = acc;
}

// h planes (fragment-major): irreps m0=d8*2, m1=m0+1 per thread
__global__ void k_h0(const float* __restrict__ x, const float* __restrict__ wv,
                     const float* __restrict__ s0, bf16_t* __restrict__ hsh) {
  const int idx = blockIdx.x * 256 + threadIdx.x;  // r*32 + d8
  const int r = idx >> 5, d8 = idx & 31;
  const int n = r & (kN - 1);
  const int m0 = d8 * 2, m1 = m0 + 1;
  const float w0 = wv[m0], w1 = wv[m1];
  const float x0 = x[r * 3 + 0], x1 = x[r * 3 + 1], x2 = x[r * 3 + 2];
  float f[8];
  f[0] = s0[n * kM + m0]; f[1] = x0 * w0; f[2] = x1 * w0; f[3] = x2 * w0;
  f[4] = s0[n * kM + m1]; f[5] = x0 * w1; f[6] = x1 * w1; f[7] = x2 * w1;
  U4 oh, ol;
#pragma unroll
  for (int i = 0; i < 8; ++i) {
    const bf16_t h_ = (bf16_t)f[i];
    oh.b[i] = h_; ol.b[i] = (bf16_t)(f[i] - (float)h_);
  }
  const size_t base = hidx(r, d8);
  *(uint4*)(hsh + base) = oh.u;
  *(uint4*)(hsh + base + 512) = ol.u;
}

// ---------------------------------------------------------------- weight prep (fragment-major)
// wall per (ct,kc): [mat(3)][p(2)][cgrp(4)][quad(4)][cl(16)][off(8)] = 12288 elems
__global__ void k_wqkv(const float* __restrict__ Wq, const float* __restrict__ Wk,
                       const float* __restrict__ Wv, int H, bf16_t* __restrict__ wall) {
  const int c = blockIdx.x;    // 0..383
  const int k = threadIdx.x;   // 0..255
  const bool ok = c < H;
  const float w[3] = {ok ? Wq[k * H + c] : 0.f, ok ? Wk[k * H + c] : 0.f,
                      ok ? Wv[k * H + c] : 0.f};
  const int ct = c >> 6, cgrp = (c >> 4) & 3, cl = c & 15;
  const int kc = k >> 5, quad = (k >> 3) & 3, off = k & 7;
  const size_t base = (size_t)(ct * 8 + kc) * 12288 + cgrp * 512 + quad * 128 + cl * 8 + off;
#pragma unroll
  for (int mat = 0; mat < 3; ++mat) {
    const bf16_t hi = (bf16_t)w[mat];
    wall[base + mat * 4096] = hi;
    wall[base + mat * 4096 + 2048] = (bf16_t)(w[mat] - (float)hi);
  }
}

// WoF per (dt,kc of 12): [p(2)][dgrp(4)][quad(4)][dl(16)][off(8)] = 4096 elems
__global__ void k_wo(const float* __restrict__ Wo, int H, bf16_t* __restrict__ WoF) {
  const int d = blockIdx.x;    // 0..255
  const int c = threadIdx.x;   // 0..383
  const float w = (c < H) ? Wo[c * 256 + d] : 0.f;
  const int dt = d >> 6, dgrp = (d >> 4) & 3, dl = d & 15;
  const int kc = c >> 5, quad = (c >> 3) & 3, off = c & 7;
  const size_t base = (size_t)(dt * 12 + kc) * 4096 + dgrp * 512 + quad * 128 + dl * 8 + off;
  const bf16_t hi = (bf16_t)w;
  WoF[base] = hi;
  WoF[base + 2048] = (bf16_t)(w - (float)hi);
}

// BtF per (ct,kc of 8): [p(2)][cgrp(4)][quad(4)][cl(16)][off(8)] = 4096 elems
__global__ void k_bt(const float* __restrict__ W0, const float* __restrict__ W1,
                     bf16_t* __restrict__ BtF) {
  const int col = blockIdx.x, row = threadIdx.x;
  const int k = col >> 2, ck = col & 3, m = row >> 2, cm = row & 3;
  float v = 0.f;
  if (cm == ck) v = (ck == 0 ? W0 : W1)[m * 64 + k];
  const int ct = col >> 6, cgrp = (col >> 4) & 3, cl = col & 15;
  const int kc = row >> 5, quad = (row >> 3) & 3, off = row & 7;
  const size_t base = (size_t)(ct * 8 + kc) * 4096 + cgrp * 512 + quad * 128 + cl * 8 + off;
  const bf16_t hi = (bf16_t)v;
  BtF[base] = hi;
  BtF[base + 2048] = (bf16_t)(v - (float)hi);
}

// ---------------------------------------------------------------- FFT (radix-2, no bit-reversal)
__device__ void fft_build_tw(float2* tw) {
  for (int j = threadIdx.x; j < kFN / 2; j += 256) {
    float s, c;
    sincosf(-6.283185307179586f * (float)j / (float)kFN, &s, &c);
    tw[j].x = c; tw[j].y = s;
  }
}

__device__ void fft_dif(float2* z, const float2* tw) {
  for (int span = kFN / 2; span >= 1; span >>= 1) {
    const int tm = (kFN / 2) / span;
    __syncthreads();
#pragma unroll
    for (int it = 0; it < 2; ++it) {
      const int p = threadIdx.x + it * 256;
      const int k = p & (span - 1);
      const int i = ((p & ~(span - 1)) << 1) | k;
      const float2 u = z[i];
      const float2 v = z[i + span];
      const float2 w = tw[k * tm];
      float2 sum, d, o;
      sum.x = u.x + v.x; sum.y = u.y + v.y;
      d.x = u.x - v.x;   d.y = u.y - v.y;
      o.x = d.x * w.x - d.y * w.y;
      o.y = d.x * w.y + d.y * w.x;
      z[i] = sum;
      z[i + span] = o;
    }
  }
}

__device__ void fft_dit_inv(float2* z, const float2* tw) {
  for (int span = 1; span <= kFN / 2; span <<= 1) {
    const int tm = (kFN / 2) / span;
    __syncthreads();
#pragma unroll
    for (int it = 0; it < 2; ++it) {
      const int p = threadIdx.x + it * 256;
      const int k = p & (span - 1);
      const int i = ((p & ~(span - 1)) << 1) | k;
      const float2 w = tw[k * tm];
      const float2 v = z[i + span];
      float2 tv, a, bq;
      tv.x = v.x * w.x + v.y * w.y;
      tv.y = v.y * w.x - v.x * w.y;
      const float2 u = z[i];
      a.x = u.x + tv.x;  a.y = u.y + tv.y;
      bq.x = u.x - tv.x; bq.y = u.y - tv.y;
      z[i] = a;
      z[i + span] = bq;
    }
  }
}

__global__ __launch_bounds__(256) void k_kf(const float* __restrict__ filt, int H,
                                            float2* __restrict__ kf) {
  __shared__ float2 z[kFN];
  __shared__ float2 tw[kFN / 2];
  const int c = blockIdx.x;
  fft_build_tw(tw);
  for (int n = threadIdx.x; n < kFN; n += 256) {
    z[n].x = filt[n * H + c];
    z[n].y = 0.0f;
  }
  fft_dif(z, tw);
  __syncthreads();
  for (int j = threadIdx.x; j < kFN; j += 256) kf[c * kFN + j] = z[j];
}

__global__ __launch_bounds__(256) void k_conv(float* kvt, const float2* __restrict__ kf, int H) {
  __shared__ float2 z[kFN];
  __shared__ float2 tw[kFN / 2];
  const int row = blockIdx.x;              // b*H + c
  const int c = row % H;
  float* sig = kvt + (size_t)row * kFN;
  fft_build_tw(tw);
  for (int n = threadIdx.x; n < kFN; n += 256) {
    z[n].x = sig[n];
    z[n].y = 0.0f;
  }
  fft_dif(z, tw);
  __syncthreads();
  for (int j = threadIdx.x; j < kFN; j += 256) {
    const float2 a = z[j];
    const float2 b = kf[c * kFN + j];
    float2 o;
    o.x = a.x * b.x - a.y * b.y;
    o.y = a.x * b.y + a.y * b.x;
    z[j] = o;
  }
  fft_dit_inv(z, tw);
  __syncthreads();
  const float s = 1.0f / (float)kFN;
  for (int n = threadIdx.x; n < kFN; n += 256) sig[n] = z[n].x * s;
}

// ---------------------------------------------------------------- GEMM 1 (split MFMA, LDS-DMA): q/k/v
// single-buffer m97-style: DMA 32KB chunk -> barrier -> ds_read frags + 36 MFMA -> barrier
__global__ __launch_bounds__(256) void k_qkv(const bf16_t* __restrict__ hsh,
    const bf16_t* __restrict__ wall, int H,
    float* __restrict__ qt, float* __restrict__ kvt) {
  __shared__ bf16_t lds[16384];            // 32 KB: A 8KB (segs 0-7) + B 24KB (segs 8-31)
  const int t = threadIdx.x;
  const int lane = t & 63, wave = t >> 6;
  const int l15 = lane & 15, quad = lane >> 4;
  const int ct = blockIdx.x, rb = blockIdx.y;
  const int r0 = rb * 64, c0 = ct * 64;
  const int wr = (wave & 1) * 32, wc = (wave >> 1) * 32;
  const int wr16 = (wave & 1) * 2, wc16 = (wave >> 1) * 2;
  const int q128l = quad * 128 + l15 * 8;
  floatx4 aq[2][2] = {}, ak_[2][2] = {}, av_[2][2] = {};
  for (int kt = 0; kt < 8; ++kt) {
    {
      const bf16_t* Asrc = hsh + (size_t)(rb * 8 + kt) * 4096;
      const bf16_t* Bsrc = wall + (size_t)(ct * 8 + kt) * 12288 - 8 * 512;
#pragma unroll
      for (int s = 0; s < 8; ++s) {
        const int seg = wave * 8 + s;
        const bf16_t* src = (wave == 0) ? (Asrc + seg * 512 + lane * 8)
                                        : (Bsrc + seg * 512 + lane * 8);
        glds16(src, &lds[seg * 512]);
      }
    }
    __syncthreads();
    const bf16x8 a0h = *(const bf16x8*)(lds + ((wr16 + 0) * 2 + 0) * 512 + q128l);
    const bf16x8 a0l = *(const bf16x8*)(lds + ((wr16 + 0) * 2 + 1) * 512 + q128l);
    const bf16x8 a1h = *(const bf16x8*)(lds + ((wr16 + 1) * 2 + 0) * 512 + q128l);
    const bf16x8 a1l = *(const bf16x8*)(lds + ((wr16 + 1) * 2 + 1) * 512 + q128l);
    {
      const int bb = 4096;                 // mat 0 (q)
      const bf16x8 bh0 = *(const bf16x8*)(lds + bb + (wc16 + 0) * 512 + q128l);
      const bf16x8 bl0 = *(const bf16x8*)(lds + bb + 2048 + (wc16 + 0) * 512 + q128l);
      const bf16x8 bh1 = *(const bf16x8*)(lds + bb + (wc16 + 1) * 512 + q128l);
      const bf16x8 bl1 = *(const bf16x8*)(lds + bb + 2048 + (wc16 + 1) * 512 + q128l);
      fma3(aq[0][0], a0h, a0l, bh0, bl0); fma3(aq[0][1], a0h, a0l, bh1, bl1);
      fma3(aq[1][0], a1h, a1l, bh0, bl0); fma3(aq[1][1], a1h, a1l, bh1, bl1);
    }
    {
      const int bb = 4096 + 4096;          // mat 1 (k)
      const bf16x8 bh0 = *(const bf16x8*)(lds + bb + (wc16 + 0) * 512 + q128l);
      const bf16x8 bl0 = *(const bf16x8*)(lds + bb + 2048 + (wc16 + 0) * 512 + q128l);
      const bf16x8 bh1 = *(const bf16x8*)(lds + bb + (wc16 + 1) * 512 + q128l);
      const bf16x8 bl1 = *(const bf16x8*)(lds + bb + 2048 + (wc16 + 1) * 512 + q128l);
      fma3(ak_[0][0], a0h, a0l, bh0, bl0); fma3(ak_[0][1], a0h, a0l, bh1, bl1);
      fma3(ak_[1][0], a1h, a1l, bh0, bl0); fma3(ak_[1][1], a1h, a1l, bh1, bl1);
    }
    {
      const int bb = 4096 + 8192;          // mat 2 (v)
      const bf16x8 bh0 = *(const bf16x8*)(lds + bb + (wc16 + 0) * 512 + q128l);
      const bf16x8 bl0 = *(const bf16x8*)(lds + bb + 2048 + (wc16 + 0) * 512 + q128l);
      const bf16x8 bh1 = *(const bf16x8*)(lds + bb + (wc16 + 1) * 512 + q128l);
      const bf16x8 bl1 = *(const bf16x8*)(lds + bb + 2048 + (wc16 + 1) * 512 + q128l);
      fma3(av_[0][0], a0h, a0l, bh0, bl0); fma3(av_[0][1], a0h, a0l, bh1, bl1);
      fma3(av_[1][0], a1h, a1l, bh0, bl0); fma3(av_[1][1], a1h, a1l, bh1, bl1);
    }
    __syncthreads();
  }
  const int b = r0 >> 10;
  const int n0 = r0 & 1023;
#pragma unroll
  for (int j = 0; j < 2; ++j) {
    const int c = c0 + wc + j * 16 + l15;
    if (c < H) {
      const size_t rbw = (((size_t)(b * H + c)) << 10) + n0 + wr + quad * 4;
#pragma unroll
      for (int i = 0; i < 2; ++i) {
        float4 p;
        p.x = aq[i][j][0]; p.y = aq[i][j][1];
        p.z = aq[i][j][2]; p.w = aq[i][j][3];
        *(float4*)(qt + rbw + i * 16) = p;
      }
#pragma unroll
      for (int i = 0; i < 2; ++i) {
        float4 p;
        p.x = ak_[i][j][0] * av_[i][j][0];
        p.y = ak_[i][j][1] * av_[i][j][1];
        p.z = ak_[i][j][2] * av_[i][j][2];
        p.w = ak_[i][j][3] * av_[i][j][3];
        *(float4*)(kvt + rbw + i * 16) = p;
      }
    }
  }
}

// ---------------------------------------------------------------- GEMM 2 (split MFMA): h += (q*conv) @ Wo
__global__ __launch_bounds__(256) void k_mix(const float* __restrict__ qt,
    const float* __restrict__ kvt, int H, int KT,
    const bf16_t* __restrict__ WoF, bf16_t* __restrict__ hsh) {
  __shared__ float smem[4352];             // As: 64 n x 36 ; epilogue: 64 x 68
  const int t = threadIdx.x;
  const int lane = t & 63, wave = t >> 6;
  const int l15 = lane & 15, quad = lane >> 4;
  const int dt = blockIdx.x, r0 = blockIdx.y * 64;
  const int b = r0 >> 10, n0 = r0 & 1023;
  const int wr = (wave & 1) * 32, wc16 = (wave >> 1) * 2;
  const int q128l = quad * 128 + l15 * 8;
  floatx4 acc[2][2] = {};
  const int cl = t >> 3, n8 = (t & 7) * 8;
  for (int kt = 0; kt < KT; ++kt) {
    const int ck0 = kt * 32;
    __syncthreads();
    {
      const int c = ck0 + cl;
      float p[8] = {};
      if (c < H) {
        const size_t o = (((size_t)(b * H + c)) << 10) + n0 + n8;
        const float4 q0 = *(const float4*)(qt + o);
        const float4 q1 = *(const float4*)(qt + o + 4);
        const float4 v0 = *(const float4*)(kvt + o);
        const float4 v1 = *(const float4*)(kvt + o + 4);
        p[0] = q0.x * v0.x; p[1] = q0.y * v0.y; p[2] = q0.z * v0.z; p[3] = q0.w * v0.w;
        p[4] = q1.x * v1.x; p[5] = q1.y * v1.y; p[6] = q1.z * v1.z; p[7] = q1.w * v1.w;
      }
#pragma unroll
      for (int u = 0; u < 8; ++u) smem[(n8 + u) * 36 + cl] = p[u];
    }
    __syncthreads();
    bf16x8 ah0, al0, ah1, al1;
    load_split8(smem + (wr + l15) * 36 + quad * 8, ah0, al0);
    load_split8(smem + (wr + 16 + l15) * 36 + quad * 8, ah1, al1);
    const bf16_t* Bb = WoF + (size_t)(dt * 12 + kt) * 4096;
    const bf16x8 bh0 = *(const bf16x8*)(Bb + (wc16 + 0) * 512 + q128l);
    const bf16x8 bl0 = *(const bf16x8*)(Bb + 2048 + (wc16 + 0) * 512 + q128l);
    const bf16x8 bh1 = *(const bf16x8*)(Bb + (wc16 + 1) * 512 + q128l);
    const bf16x8 bl1 = *(const bf16x8*)(Bb + 2048 + (wc16 + 1) * 512 + q128l);
    fma3(acc[0][0], ah0, al0, bh0, bl0); fma3(acc[0][1], ah0, al0, bh1, bl1);
    fma3(acc[1][0], ah1, al1, bh0, bl0); fma3(acc[1][1], ah1, al1, bh1, bl1);
  }
  __syncthreads();
#pragma unroll
  for (int i = 0; i < 2; ++i)
#pragma unroll
    for (int j = 0; j < 2; ++j)
#pragma unroll
      for (int r = 0; r < 4; ++r)
        smem[(wr + i * 16 + quad * 4 + r) * 68 + (wave >> 1) * 32 + j * 16 + l15] = acc[i][j][r];
  __syncthreads();
  const int nl = t >> 2, q4 = t & 3;
  const int r = r0 + nl;
#pragma unroll
  for (int u8 = 0; u8 < 2; ++u8) {
    const int d8 = blockIdx.x * 8 + q4 * 2 + u8;
    const size_t base = hidx(r, d8);
    U4 hi, lo;
    hi.u = *(const uint4*)(hsh + base);
    lo.u = *(const uint4*)(hsh + base + 512);
    U4 oh, ol;
#pragma unroll
    for (int i = 0; i < 8; ++i) {
      const float f = (float)hi.b[i] + (float)lo.b[i] + smem[nl * 68 + q4 * 16 + u8 * 8 + i];
      const bf16_t h_ = (bf16_t)f;
      oh.b[i] = h_; ol.b[i] = (bf16_t)(f - (float)h_);
    }
    *(uint4*)(hsh + base) = oh.u;
    *(uint4*)(hsh + base + 512) = ol.u;
  }
}

// ---------------------------------------------------------------- GEMM 3 (split MFMA): reg_linear + BN partials
__global__ __launch_bounds__(256) void k_reg(const bf16_t* __restrict__ hsh,
    const bf16_t* __restrict__ BtF,
    float* __restrict__ y, float* __restrict__ partial) {
  __shared__ float sm[64 * 68];
  __shared__ float red[128];
  const int t = threadIdx.x;
  const int lane = t & 63, wave = t >> 6;
  const int l15 = lane & 15, quad = lane >> 4;
  const int ct = blockIdx.x, rb = blockIdx.y;
  const int c0 = ct * 64, r0 = rb * 64;
  const int wr = (wave & 1) * 32, wc = (wave >> 1) * 32;
  const int wr16 = (wave & 1) * 2, wc16 = (wave >> 1) * 2;
  const int q128l = quad * 128 + l15 * 8;
  floatx4 acc[2][2] = {};
  bf16x8 A[2][4], B[2][4];
#pragma unroll
  for (int u = 0; u < 4; ++u) {
    A[0][u] = *(const bf16x8*)(hsh + (size_t)(rb * 8) * 4096 +
                               ((wr16 + (u >> 1)) * 2 + (u & 1)) * 512 + q128l);
    B[0][u] = *(const bf16x8*)(BtF + (size_t)(ct * 8) * 4096 +
                               (u & 1) * 2048 + (wc16 + (u >> 1)) * 512 + q128l);
  }
#pragma unroll
  for (int kt = 0; kt < 8; ++kt) {
    const int cur = kt & 1, nxt = cur ^ 1;
    if (kt < 7) {
#pragma unroll
      for (int u = 0; u < 4; ++u) {
        A[nxt][u] = *(const bf16x8*)(hsh + (size_t)(rb * 8 + kt + 1) * 4096 +
                                     ((wr16 + (u >> 1)) * 2 + (u & 1)) * 512 + q128l);
        B[nxt][u] = *(const bf16x8*)(BtF + (size_t)(ct * 8 + kt + 1) * 4096 +
                                     (u & 1) * 2048 + (wc16 + (u >> 1)) * 512 + q128l);
      }
    }
    fma3(acc[0][0], A[cur][0], A[cur][1], B[cur][0], B[cur][1]);
    fma3(acc[0][1], A[cur][0], A[cur][1], B[cur][2], B[cur][3]);
    fma3(acc[1][0], A[cur][2], A[cur][3], B[cur][0], B[cur][1]);
    fma3(acc[1][1], A[cur][2], A[cur][3], B[cur][2], B[cur][3]);
  }
#pragma unroll
  for (int j = 0; j < 2; ++j) {
    float s = 0.f;
#pragma unroll
    for (int i = 0; i < 2; ++i)
#pragma unroll
      for (int r = 0; r < 4; ++r)
        s = fmaf(acc[i][j][r], acc[i][j][r], s);
    s += __shfl_down(s, 32);
    s += __shfl_down(s, 16);
    if (lane < 16) red[wave * 32 + j * 16 + lane] = s;
  }
#pragma unroll
  for (int i = 0; i < 2; ++i)
#pragma unroll
    for (int j = 0; j < 2; ++j)
#pragma unroll
      for (int r = 0; r < 4; ++r)
        sm[(wr + i * 16 + quad * 4 + r) * 68 + wc + j * 16 + l15] = acc[i][j][r];
  __syncthreads();
  const int nl = t >> 2, q4 = t & 3;
  const size_t gi = (size_t)(r0 + nl) * 256 + c0 + q4 * 16;
#pragma unroll
  for (int u = 0; u < 4; ++u) {
    float4 yv;
    yv.x = sm[nl * 68 + q4 * 16 + u * 4 + 0];
    yv.y = sm[nl * 68 + q4 * 16 + u * 4 + 1];
    yv.z = sm[nl * 68 + q4 * 16 + u * 4 + 2];
    yv.w = sm[nl * 68 + q4 * 16 + u * 4 + 3];
    *(float4*)(y + gi + u * 4) = yv;
  }
  if (t < 64) {
    const int w0 = (t >= 32) ? 2 : 0;
    const float v = red[w0 * 32 + (t & 31)] + red[(w0 + 1) * 32 + (t & 31)];
    partial[(size_t)blockIdx.y * 256 + c0 + t] = v;   // race-free: one slot per column
  }
}

// reduce partials over 1024 r-blocks -> stats[128]
__global__ __launch_bounds__(1024) void k_stat(const float* __restrict__ partial,
                                               float* __restrict__ st) {
  __shared__ float acc[4][256];
  __shared__ float tot[256];
  const int t = threadIdx.x;
  const int slot = t & 255, g = t >> 8;
  float s = 0.f;
  for (int r = g; r < 1024; r += 4) s += partial[(size_t)r * 256 + slot];
  acc[g][slot] = s;
  __syncthreads();
  if (t < 256) tot[t] = acc[0][t] + acc[1][t] + acc[2][t] + acc[3][t];
  __syncthreads();
  if (t < 64) {
    st[t] = tot[4 * t];
    st[64 + t] = tot[4 * t + 1] + tot[4 * t + 2] + tot[4 * t + 3];
  }
}

// ---------------------------------------------------------------- BN + norm-activation + residual
__global__ void k_bnact(const float* __restrict__ y, const float* __restrict__ stats,
    const float* __restrict__ g0, const float* __restrict__ g1, bf16_t* __restrict__ hsh) {
  const int idx = blockIdx.x * 256 + threadIdx.x;  // r*32 + d8
  const int r = idx >> 5, d8 = idx & 31;
  const int m0 = d8 * 2, m1 = m0 + 1;
  const float i00 = g0[m0] / sqrtf(stats[m0] * (1.0f / 65536.0f) + kEps);
  const float i10 = g1[m0] / sqrtf(stats[64 + m0] * (1.0f / 65536.0f) + kEps);
  const float i01 = g0[m1] / sqrtf(stats[m1] * (1.0f / 65536.0f) + kEps);
  const float i11 = g1[m1] / sqrtf(stats[64 + m1] * (1.0f / 65536.0f) + kEps);
  const float* yr = y + (size_t)r * 256 + d8 * 8;
  const float4 ya = *(const float4*)yr;
  const float4 yb = *(const float4*)(yr + 4);
  float a[8];
  {
    const float s = ya.x * i00;
    const float vx = ya.y * i10, vy = ya.z * i10, vz = ya.w * i10;
    const float so = s * sigmoidf(fabsf(s));
    const float vn = sqrtf(fmaf(vx, vx, fmaf(vy, vy, vz * vz)) + kEps);
    const float gv = sigmoidf(vn);
    a[0] = so; a[1] = vx * gv; a[2] = vy * gv; a[3] = vz * gv;
  }
  {
    const float s = yb.x * i01;
    const float vx = yb.y * i11, vy = yb.z * i11, vz = yb.w * i11;
    const float so = s * sigmoidf(fabsf(s));
    const float vn = sqrtf(fmaf(vx, vx, fmaf(vy, vy, vz * vz)) + kEps);
    const float gv = sigmoidf(vn);
    a[4] = so; a[5] = vx * gv; a[6] = vy * gv; a[7] = vz * gv;
  }
  const size_t base = hidx(r, d8);
  U4 hi, lo;
  hi.u = *(const uint4*)(hsh + base);
  lo.u = *(const uint4*)(hsh + base + 512);
  U4 oh, ol;
#pragma unroll
  for (int i = 0; i < 8; ++i) {
    const float f = (float)hi.b[i] + (float)lo.b[i] + a[i];
    const bf16_t h_ = (bf16_t)f;
    oh.b[i] = h_; ol.b[i] = (bf16_t)(f - (float)h_);
  }
  *(uint4*)(hsh + base) = oh.u;
  *(uint4*)(hsh + base + 512) = ol.u;
}

// ---------------------------------------------------------------- mean-pool + einsum
__global__ __launch_bounds__(256) void k_pool(const bf16_t* __restrict__ hsh,
    const float* __restrict__ w_out, float* __restrict__ out) {
  __shared__ float r0s[256], r1s[256], r2s[256];
  const int b = blockIdx.x;
  const int t = threadIdx.x;
  float p0 = 0, p1 = 0, p2 = 0;
  for (int idx = t; idx < kN * 32; idx += 256) {
    const int n = idx >> 5, d8 = idx & 31;
    const int r = (b << 10) + n;
    const size_t base = hidx(r, d8);
    U4 hi, lo;
    hi.u = *(const uint4*)(hsh + base);
    lo.u = *(const uint4*)(hsh + base + 512);
    const float w0 = w_out[d8 * 2], w1 = w_out[d8 * 2 + 1];
    p0 += ((float)hi.b[1] + (float)lo.b[1]) * w0 + ((float)hi.b[5] + (float)lo.b[5]) * w1;
    p1 += ((float)hi.b[2] + (float)lo.b[2]) * w0 + ((float)hi.b[6] + (float)lo.b[6]) * w1;
    p2 += ((float)hi.b[3] + (float)lo.b[3]) * w0 + ((float)hi.b[7] + (float)lo.b[7]) * w1;
  }
  r0s[t] = p0; r1s[t] = p1; r2s[t] = p2;
  __syncthreads();
  for (int s = 128; s > 0; s >>= 1) {
    if (t < s) { r0s[t] += r0s[t + s]; r1s[t] += r1s[t + s]; r2s[t] += r2s[t + s]; }
    __syncthreads();
  }
  if (t == 0) {
    out[b * 3 + 0] = r0s[0] * (1.0f / kN);
    out[b * 3 + 1] = r1s[0] * (1.0f / kN);
    out[b * 3 + 2] = r2s[0] * (1.0f / kN);
  }
}

} // namespace

extern "C" void kernel_launch(void* const* d_in, const int* in_sizes, int n_in,
                              void* d_out, int out_size, void* d_ws, size_t ws_size,
                              hipStream_t stream) {
  const float* x       = (const float*)d_in[0];
  const float* tok_emb = (const float*)d_in[1];
  const float* Wf      = (const float*)d_in[2];
  const float* wv      = (const float*)d_in[3];
  const float* w_out   = (const float*)d_in[4];

  float* ws    = (float*)d_ws;
  bf16_t* hsh  = (bf16_t*)ws;                          // 33,554,432 bf16 = 16,777,216 fl
  float*  kvt  = ws + 16777216;                        // 23,592,960 fl
  float*  qt   = kvt + 23592960;                       // 23,592,960 fl
  float*  y    = qt;                                   // alias: qt dead once k_mix done
  float*  partial = qt + 20000000;                     // 262,144 fl inside qt region, past y end
  float*  s0   = qt + 23592960;                        //     65,536 fl
  float*  kf   = s0 + 65536;                           //    737,280 fl
  bf16_t* wall = (bf16_t*)(kf + 737280);               // 6*8*12288 = 589,824 bf16
  bf16_t* WoF  = wall + 589824;                        // 4*12*4096 = 196,608 bf16
  bf16_t* BtF  = WoF + 196608;                         // 4*8*4096  = 131,072 bf16
  float* stats = (float*)(BtF + 131072);               // 384 fl

  k_s0<<<kN, 64, 0, stream>>>(tok_emb, Wf, s0);
  k_h0<<<8192, 256, 0, stream>>>(x, wv, s0, hsh);

  for (int l = 0; l < 3; ++l) {
    const float* Wq   = (const float*)d_in[5 + 9 * l + 0];
    const float* Wk   = (const float*)d_in[5 + 9 * l + 1];
    const float* Wv   = (const float*)d_in[5 + 9 * l + 2];
    const float* filt = (const float*)d_in[5 + 9 * l + 3];
    const float* Wo   = (const float*)d_in[5 + 9 * l + 4];
    const float* Wm0  = (const float*)d_in[5 + 9 * l + 5];
    const float* Wm1  = (const float*)d_in[5 + 9 * l + 6];
    const float* g0   = (const float*)d_in[5 + 9 * l + 7];
    const float* g1   = (const float*)d_in[5 + 9 * l + 8];
    const int H = (l == 2) ? 160 : 360;
    const int gy = (H + 63) / 64;                      // 6 or 3
    const int KT = gy * 2;                             // K chunks of 32 (zero-padded weights)
    float* st = stats + l * 128;

    k_wqkv<<<384, 256, 0, stream>>>(Wq, Wk, Wv, H, wall);
    k_wo<<<256, 384, 0, stream>>>(Wo, H, WoF);
    k_bt<<<256, 256, 0, stream>>>(Wm0, Wm1, BtF);
    k_kf<<<H, 256, 0, stream>>>(filt, H, (float2*)kf);
    k_qkv<<<dim3(gy, 1024), 256, 0, stream>>>(hsh, wall, H, qt, kvt);
    k_conv<<<64 * H, 256, 0, stream>>>(kvt, (const float2*)kf, H);
    k_mix<<<dim3(4, 1024), 256, 0, stream>>>(qt, kvt, H, KT, WoF, hsh);
    k_reg<<<dim3(4, 1024), 256, 0, stream>>>(hsh, BtF, y, partial);
    k_stat<<<1, 1024, 0, stream>>>(partial, st);
    k_bnact<<<8192, 256, 0, stream>>>(y, st, g0, g1, hsh);
  }

  k_pool<<<64, 256, 0, stream>>>(hsh, w_out, (float*)d_out);
}

// Round 8
// 1626.532 us; speedup vs baseline: 1.6239x; 1.1416x over previous
//
#include <hip/hip_runtime.h>
#include <math.h>

namespace {

typedef __bf16 bf16_t;
typedef bf16_t bf16x8 __attribute__((ext_vector_type(8)));
typedef float floatx4 __attribute__((ext_vector_type(4)));

constexpr int kN = 1024;      // tokens
constexpr int kM = 64;        // multiplicity
constexpr int kP = 64;        // PE dim
constexpr float kEps = 1e-5f;
constexpr int kFN = 1024;     // FFT length

__device__ __forceinline__ float sigmoidf(float v) { return 1.0f / (1.0f + expf(-v)); }

__device__ __forceinline__ floatx4 mfma16(bf16x8 a, bf16x8 b, floatx4 c) {
  return __builtin_amdgcn_mfma_f32_16x16x32_bf16(a, b, c, 0, 0, 0);
}

// 3-term split product: acc += (ah+al)*(bh+bl) dropping al*bl
__device__ __forceinline__ void fma3(floatx4& acc, bf16x8 ah, bf16x8 al,
                                     bf16x8 bh, bf16x8 bl) {
  acc = mfma16(ah, bh, acc);
  acc = mfma16(ah, bl, acc);
  acc = mfma16(al, bh, acc);
}

// load 8 contiguous fp32 (LDS), split into hi/lo bf16 fragments
__device__ __forceinline__ void load_split8(const float* p, bf16x8& hi, bf16x8& lo) {
  const float4 u = *(const float4*)p;
  const float4 v = *(const float4*)(p + 4);
  const float a[8] = {u.x, u.y, u.z, u.w, v.x, v.y, v.z, v.w};
#pragma unroll
  for (int i = 0; i < 8; ++i) {
    const bf16_t h_ = (bf16_t)a[i];
    hi[i] = h_;
    lo[i] = (bf16_t)(a[i] - (float)h_);
  }
}

union U4 { uint4 u; bf16_t b[8]; };

// async 16B/lane global->LDS DMA (wave-uniform LDS base + lane*16 scatter)
__device__ __forceinline__ void glds16(const bf16_t* g, bf16_t* l) {
  __builtin_amdgcn_global_load_lds(
      (const __attribute__((address_space(1))) void*)g,
      (__attribute__((address_space(3))) void*)l, 16, 0, 0);
}

// hsh fragment-major index for (row r, 8-elem group d8), hi plane (lo = +512)
// layout: [rb(1024)][kc(8)][rgrp(4)][p(2)][quad(4)][rl(16)][off(8)]
__device__ __forceinline__ size_t hidx(int r, int d8) {
  const int rb = r >> 6, rr = r & 63;
  return (size_t)(rb * 8 + (d8 >> 2)) * 4096 + (rr >> 4) * 1024 + (d8 & 3) * 128 + (rr & 15) * 8;
}

// padded LDS index for FFT work array (breaks small-span bank conflicts)
__device__ __forceinline__ int zi(int i) { return i + (i >> 4); }

// ---------------------------------------------------------------- init
// s0[n, m] = sum_p (pe[n,p] + tok_emb[tt[n],p]) * Wf[p,m]
__global__ void k_s0(const float* __restrict__ tok_emb, const float* __restrict__ Wf,
                     float* __restrict__ s0) {
  __shared__ float f[kP];
  const int n = blockIdx.x;
  const int t = threadIdx.x;                       // 64 threads
  const int tt = (n == kN - 1) ? 2 : (n & 1);
  const int j = t >> 1;
  const float cexp = (float)(-9.210340371976184 / 64.0);   // -ln(10000)/P
  const float divj = expf((float)(2 * j) * cexp);
  const float ang = (float)n * divj;
  const float pe = (t & 1) ? cosf(ang) : sinf(ang);
  f[t] = pe + tok_emb[tt * kP + t];
  __syncthreads();
  float acc = 0.0f;
#pragma unroll 8
  for (int p = 0; p < kP; ++p) acc = fmaf(f[p], Wf[p * kM + t], acc);
  s0[n * kM + t] = acc;
}

// h planes (fragment-major): irreps m0=d8*2, m1=m0+1 per thread
__global__ void k_h0(const float* __restrict__ x, const float* __restrict__ wv,
                     const float* __restrict__ s0, bf16_t* __restrict__ hsh) {
  const int idx = blockIdx.x * 256 + threadIdx.x;  // r*32 + d8
  const int r = idx >> 5, d8 = idx & 31;
  const int n = r & (kN - 1);
  const int m0 = d8 * 2, m1 = m0 + 1;
  const float w0 = wv[m0], w1 = wv[m1];
  const float x0 = x[r * 3 + 0], x1 = x[r * 3 + 1], x2 = x[r * 3 + 2];
  float f[8];
  f[0] = s0[n * kM + m0]; f[1] = x0 * w0; f[2] = x1 * w0; f[3] = x2 * w0;
  f[4] = s0[n * kM + m1]; f[5] = x0 * w1; f[6] = x1 * w1; f[7] = x2 * w1;
  U4 oh, ol;
#pragma unroll
  for (int i = 0; i < 8; ++i) {
    const bf16_t h_ = (bf16_t)f[i];
    oh.b[i] = h_; ol.b[i] = (bf16_t)(f[i] - (float)h_);
  }
  const size_t base = hidx(r, d8);
  *(uint4*)(hsh + base) = oh.u;
  *(uint4*)(hsh + base + 512) = ol.u;
}

// ---------------------------------------------------------------- weight prep (fragment-major)
// wall per (ct,kc): [mat(3)][p(2)][cgrp(4)][quad(4)][cl(16)][off(8)] = 12288 elems
__global__ void k_wqkv(const float* __restrict__ Wq, const float* __restrict__ Wk,
                       const float* __restrict__ Wv, int H, bf16_t* __restrict__ wall) {
  const int c = blockIdx.x;    // 0..383
  const int k = threadIdx.x;   // 0..255
  const bool ok = c < H;
  const float w[3] = {ok ? Wq[k * H + c] : 0.f, ok ? Wk[k * H + c] : 0.f,
                      ok ? Wv[k * H + c] : 0.f};
  const int ct = c >> 6, cgrp = (c >> 4) & 3, cl = c & 15;
  const int kc = k >> 5, quad = (k >> 3) & 3, off = k & 7;
  const size_t base = (size_t)(ct * 8 + kc) * 12288 + cgrp * 512 + quad * 128 + cl * 8 + off;
#pragma unroll
  for (int mat = 0; mat < 3; ++mat) {
    const bf16_t hi = (bf16_t)w[mat];
    wall[base + mat * 4096] = hi;
    wall[base + mat * 4096 + 2048] = (bf16_t)(w[mat] - (float)hi);
  }
}

// WoF per (dt,kc of 12): [p(2)][dgrp(4)][quad(4)][dl(16)][off(8)] = 4096 elems
__global__ void k_wo(const float* __restrict__ Wo, int H, bf16_t* __restrict__ WoF) {
  const int d = blockIdx.x;    // 0..255
  const int c = threadIdx.x;   // 0..383
  const float w = (c < H) ? Wo[c * 256 + d] : 0.f;
  const int dt = d >> 6, dgrp = (d >> 4) & 3, dl = d & 15;
  const int kc = c >> 5, quad = (c >> 3) & 3, off = c & 7;
  const size_t base = (size_t)(dt * 12 + kc) * 4096 + dgrp * 512 + quad * 128 + dl * 8 + off;
  const bf16_t hi = (bf16_t)w;
  WoF[base] = hi;
  WoF[base + 2048] = (bf16_t)(w - (float)hi);
}

// BtF per (ct,kc of 8): [p(2)][cgrp(4)][quad(4)][cl(16)][off(8)] = 4096 elems
__global__ void k_bt(const float* __restrict__ W0, const float* __restrict__ W1,
                     bf16_t* __restrict__ BtF) {
  const int col = blockIdx.x, row = threadIdx.x;
  const int k = col >> 2, ck = col & 3, m = row >> 2, cm = row & 3;
  float v = 0.f;
  if (cm == ck) v = (ck == 0 ? W0 : W1)[m * 64 + k];
  const int ct = col >> 6, cgrp = (col >> 4) & 3, cl = col & 15;
  const int kc = row >> 5, quad = (row >> 3) & 3, off = row & 7;
  const size_t base = (size_t)(ct * 8 + kc) * 4096 + cgrp * 512 + quad * 128 + cl * 8 + off;
  const bf16_t hi = (bf16_t)v;
  BtF[base] = hi;
  BtF[base + 2048] = (bf16_t)(v - (float)hi);
}

// ---------------------------------------------------------------- FFT (radix-2, no bit-reversal)
// twiddle table -> global (once per launch)
__global__ void k_tw(float2* __restrict__ twg) {
  const int j = blockIdx.x * 256 + threadIdx.x;
  if (j < kFN / 2) {
    float s, c;
    sincosf(-6.283185307179586f * (float)j / (float)kFN, &s, &c);
    twg[j].x = c; twg[j].y = s;
  }
}

// forward DIF on padded z: natural in -> bit-reversed out
__device__ void fft_dif(float2* z, const float2* tw) {
  for (int span = kFN / 2; span >= 1; span >>= 1) {
    const int tm = (kFN / 2) / span;
    __syncthreads();
#pragma unroll
    for (int it = 0; it < 2; ++it) {
      const int p = threadIdx.x + it * 256;
      const int k = p & (span - 1);
      const int i = ((p & ~(span - 1)) << 1) | k;
      const float2 u = z[zi(i)];
      const float2 v = z[zi(i + span)];
      const float2 w = tw[k * tm];
      float2 sum, d, o;
      sum.x = u.x + v.x; sum.y = u.y + v.y;
      d.x = u.x - v.x;   d.y = u.y - v.y;
      o.x = d.x * w.x - d.y * w.y;
      o.y = d.x * w.y + d.y * w.x;
      z[zi(i)] = sum;
      z[zi(i + span)] = o;
    }
  }
}

// inverse DIT on padded z: bit-reversed in -> natural out (caller scales by 1/N)
__device__ void fft_dit_inv(float2* z, const float2* tw) {
  for (int span = 1; span <= kFN / 2; span <<= 1) {
    const int tm = (kFN / 2) / span;
    __syncthreads();
#pragma unroll
    for (int it = 0; it < 2; ++it) {
      const int p = threadIdx.x + it * 256;
      const int k = p & (span - 1);
      const int i = ((p & ~(span - 1)) << 1) | k;
      const float2 w = tw[k * tm];
      const float2 v = z[zi(i + span)];
      float2 tv, a, bq;
      tv.x = v.x * w.x + v.y * w.y;
      tv.y = v.y * w.x - v.x * w.y;
      const float2 u = z[zi(i)];
      a.x = u.x + tv.x;  a.y = u.y + tv.y;
      bq.x = u.x - tv.x; bq.y = u.y - tv.y;
      z[zi(i)] = a;
      z[zi(i + span)] = bq;
    }
  }
}

// filter spectrum, stored in DIF (bit-reversed) order; one block per channel
__global__ __launch_bounds__(256) void k_kf(const float* __restrict__ filt, int H,
                                            const float2* __restrict__ twg,
                                            float2* __restrict__ kf) {
  __shared__ float2 z[kFN + kFN / 16];
  __shared__ float2 tw[kFN / 2];
  const int c = blockIdx.x;
  for (int j = threadIdx.x; j < kFN / 2; j += 256) tw[j] = twg[j];
  for (int n = threadIdx.x; n < kFN; n += 256) {
    z[zi(n)].x = filt[n * H + c];
    z[zi(n)].y = 0.0f;
  }
  fft_dif(z, tw);
  __syncthreads();
  for (int j = threadIdx.x; j < kFN; j += 256) kf[c * kFN + j] = z[zi(j)];
}

// packed circular conv: two batch rows (same channel) per complex FFT
// IFFT(FFT(kv[b0] + i*kv[b1]) * F) = conv(b0) + i*conv(b1)  (conv real, F shared)
__global__ __launch_bounds__(256) void k_conv(float* kvt, const float2* __restrict__ kf,
                                              const float2* __restrict__ twg, int H) {
  __shared__ float2 z[kFN + kFN / 16];
  __shared__ float2 tw[kFN / 2];
  const int blk = blockIdx.x;              // pb*H + c
  const int c = blk % H;
  const int pb = blk / H;
  float* sig0 = kvt + (((size_t)((2 * pb) * H + c)) << 10);
  float* sig1 = kvt + (((size_t)((2 * pb + 1) * H + c)) << 10);
  for (int j = threadIdx.x; j < kFN / 2; j += 256) tw[j] = twg[j];
  for (int n = threadIdx.x; n < kFN; n += 256) {
    z[zi(n)].x = sig0[n];
    z[zi(n)].y = sig1[n];
  }
  fft_dif(z, tw);
  __syncthreads();
  for (int j = threadIdx.x; j < kFN; j += 256) {
    const float2 a = z[zi(j)];
    const float2 b = kf[c * kFN + j];
    float2 o;
    o.x = a.x * b.x - a.y * b.y;
    o.y = a.x * b.y + a.y * b.x;
    z[zi(j)] = o;
  }
  fft_dit_inv(z, tw);
  __syncthreads();
  const float s = 1.0f / (float)kFN;
  for (int n = threadIdx.x; n < kFN; n += 256) {
    sig0[n] = z[zi(n)].x * s;
    sig1[n] = z[zi(n)].y * s;
  }
}

// ---------------------------------------------------------------- GEMM 1 (split MFMA, LDS-DMA): q/k/v
// single-buffer m97-style: DMA 32KB chunk -> barrier -> ds_read frags + 36 MFMA -> barrier
__global__ __launch_bounds__(256) void k_qkv(const bf16_t* __restrict__ hsh,
    const bf16_t* __restrict__ wall, int H,
    float* __restrict__ qt, float* __restrict__ kvt) {
  __shared__ bf16_t lds[16384];            // 32 KB: A 8KB (segs 0-7) + B 24KB (segs 8-31)
  const int t = threadIdx.x;
  const int lane = t & 63, wave = t >> 6;
  const int l15 = lane & 15, quad = lane >> 4;
  const int ct = blockIdx.x, rb = blockIdx.y;
  const int r0 = rb * 64, c0 = ct * 64;
  const int wr = (wave & 1) * 32, wc = (wave >> 1) * 32;
  const int wr16 = (wave & 1) * 2, wc16 = (wave >> 1) * 2;
  const int q128l = quad * 128 + l15 * 8;
  floatx4 aq[2][2] = {}, ak_[2][2] = {}, av_[2][2] = {};
  for (int kt = 0; kt < 8; ++kt) {
    {
      const bf16_t* Asrc = hsh + (size_t)(rb * 8 + kt) * 4096;
      const bf16_t* Bsrc = wall + (size_t)(ct * 8 + kt) * 12288 - 8 * 512;
#pragma unroll
      for (int s = 0; s < 8; ++s) {
        const int seg = wave * 8 + s;
        const bf16_t* src = (wave == 0) ? (Asrc + seg * 512 + lane * 8)
                                        : (Bsrc + seg * 512 + lane * 8);
        glds16(src, &lds[seg * 512]);
      }
    }
    __syncthreads();
    const bf16x8 a0h = *(const bf16x8*)(lds + ((wr16 + 0) * 2 + 0) * 512 + q128l);
    const bf16x8 a0l = *(const bf16x8*)(lds + ((wr16 + 0) * 2 + 1) * 512 + q128l);
    const bf16x8 a1h = *(const bf16x8*)(lds + ((wr16 + 1) * 2 + 0) * 512 + q128l);
    const bf16x8 a1l = *(const bf16x8*)(lds + ((wr16 + 1) * 2 + 1) * 512 + q128l);
    {
      const int bb = 4096;                 // mat 0 (q)
      const bf16x8 bh0 = *(const bf16x8*)(lds + bb + (wc16 + 0) * 512 + q128l);
      const bf16x8 bl0 = *(const bf16x8*)(lds + bb + 2048 + (wc16 + 0) * 512 + q128l);
      const bf16x8 bh1 = *(const bf16x8*)(lds + bb + (wc16 + 1) * 512 + q128l);
      const bf16x8 bl1 = *(const bf16x8*)(lds + bb + 2048 + (wc16 + 1) * 512 + q128l);
      fma3(aq[0][0], a0h, a0l, bh0, bl0); fma3(aq[0][1], a0h, a0l, bh1, bl1);
      fma3(aq[1][0], a1h, a1l, bh0, bl0); fma3(aq[1][1], a1h, a1l, bh1, bl1);
    }
    {
      const int bb = 4096 + 4096;          // mat 1 (k)
      const bf16x8 bh0 = *(const bf16x8*)(lds + bb + (wc16 + 0) * 512 + q128l);
      const bf16x8 bl0 = *(const bf16x8*)(lds + bb + 2048 + (wc16 + 0) * 512 + q128l);
      const bf16x8 bh1 = *(const bf16x8*)(lds + bb + (wc16 + 1) * 512 + q128l);
      const bf16x8 bl1 = *(const bf16x8*)(lds + bb + 2048 + (wc16 + 1) * 512 + q128l);
      fma3(ak_[0][0], a0h, a0l, bh0, bl0); fma3(ak_[0][1], a0h, a0l, bh1, bl1);
      fma3(ak_[1][0], a1h, a1l, bh0, bl0); fma3(ak_[1][1], a1h, a1l, bh1, bl1);
    }
    {
      const int bb = 4096 + 8192;          // mat 2 (v)
      const bf16x8 bh0 = *(const bf16x8*)(lds + bb + (wc16 + 0) * 512 + q128l);
      const bf16x8 bl0 = *(const bf16x8*)(lds + bb + 2048 + (wc16 + 0) * 512 + q128l);
      const bf16x8 bh1 = *(const bf16x8*)(lds + bb + (wc16 + 1) * 512 + q128l);
      const bf16x8 bl1 = *(const bf16x8*)(lds + bb + 2048 + (wc16 + 1) * 512 + q128l);
      fma3(av_[0][0], a0h, a0l, bh0, bl0); fma3(av_[0][1], a0h, a0l, bh1, bl1);
      fma3(av_[1][0], a1h, a1l, bh0, bl0); fma3(av_[1][1], a1h, a1l, bh1, bl1);
    }
    __syncthreads();
  }
  const int b = r0 >> 10;
  const int n0 = r0 & 1023;
#pragma unroll
  for (int j = 0; j < 2; ++j) {
    const int c = c0 + wc + j * 16 + l15;
    if (c < H) {
      const size_t rbw = (((size_t)(b * H + c)) << 10) + n0 + wr + quad * 4;
#pragma unroll
      for (int i = 0; i < 2; ++i) {
        float4 p;
        p.x = aq[i][j][0]; p.y = aq[i][j][1];
        p.z = aq[i][j][2]; p.w = aq[i][j][3];
        *(float4*)(qt + rbw + i * 16) = p;
      }
#pragma unroll
      for (int i = 0; i < 2; ++i) {
        float4 p;
        p.x = ak_[i][j][0] * av_[i][j][0];
        p.y = ak_[i][j][1] * av_[i][j][1];
        p.z = ak_[i][j][2] * av_[i][j][2];
        p.w = ak_[i][j][3] * av_[i][j][3];
        *(float4*)(kvt + rbw + i * 16) = p;
      }
    }
  }
}

// ---------------------------------------------------------------- GEMM 2 (split MFMA): h += (q*conv) @ Wo
__global__ __launch_bounds__(256) void k_mix(const float* __restrict__ qt,
    const float* __restrict__ kvt, int H, int KT,
    const bf16_t* __restrict__ WoF, bf16_t* __restrict__ hsh) {
  __shared__ float smem[4352];             // As: 64 n x 36 ; epilogue: 64 x 68
  const int t = threadIdx.x;
  const int lane = t & 63, wave = t >> 6;
  const int l15 = lane & 15, quad = lane >> 4;
  const int dt = blockIdx.x, r0 = blockIdx.y * 64;
  const int b = r0 >> 10, n0 = r0 & 1023;
  const int wr = (wave & 1) * 32, wc16 = (wave >> 1) * 2;
  const int q128l = quad * 128 + l15 * 8;
  floatx4 acc[2][2] = {};
  const int cl = t >> 3, n8 = (t & 7) * 8;
  for (int kt = 0; kt < KT; ++kt) {
    const int ck0 = kt * 32;
    __syncthreads();
    {
      const int c = ck0 + cl;
      float p[8] = {};
      if (c < H) {
        const size_t o = (((size_t)(b * H + c)) << 10) + n0 + n8;
        const float4 q0 = *(const float4*)(qt + o);
        const float4 q1 = *(const float4*)(qt + o + 4);
        const float4 v0 = *(const float4*)(kvt + o);
        const float4 v1 = *(const float4*)(kvt + o + 4);
        p[0] = q0.x * v0.x; p[1] = q0.y * v0.y; p[2] = q0.z * v0.z; p[3] = q0.w * v0.w;
        p[4] = q1.x * v1.x; p[5] = q1.y * v1.y; p[6] = q1.z * v1.z; p[7] = q1.w * v1.w;
      }
#pragma unroll
      for (int u = 0; u < 8; ++u) smem[(n8 + u) * 36 + cl] = p[u];
    }
    __syncthreads();
    bf16x8 ah0, al0, ah1, al1;
    load_split8(smem + (wr + l15) * 36 + quad * 8, ah0, al0);
    load_split8(smem + (wr + 16 + l15) * 36 + quad * 8, ah1, al1);
    const bf16_t* Bb = WoF + (size_t)(dt * 12 + kt) * 4096;
    const bf16x8 bh0 = *(const bf16x8*)(Bb + (wc16 + 0) * 512 + q128l);
    const bf16x8 bl0 = *(const bf16x8*)(Bb + 2048 + (wc16 + 0) * 512 + q128l);
    const bf16x8 bh1 = *(const bf16x8*)(Bb + (wc16 + 1) * 512 + q128l);
    const bf16x8 bl1 = *(const bf16x8*)(Bb + 2048 + (wc16 + 1) * 512 + q128l);
    fma3(acc[0][0], ah0, al0, bh0, bl0); fma3(acc[0][1], ah0, al0, bh1, bl1);
    fma3(acc[1][0], ah1, al1, bh0, bl0); fma3(acc[1][1], ah1, al1, bh1, bl1);
  }
  __syncthreads();
#pragma unroll
  for (int i = 0; i < 2; ++i)
#pragma unroll
    for (int j = 0; j < 2; ++j)
#pragma unroll
      for (int r = 0; r < 4; ++r)
        smem[(wr + i * 16 + quad * 4 + r) * 68 + (wave >> 1) * 32 + j * 16 + l15] = acc[i][j][r];
  __syncthreads();
  const int nl = t >> 2, q4 = t & 3;
  const int r = r0 + nl;
#pragma unroll
  for (int u8 = 0; u8 < 2; ++u8) {
    const int d8 = blockIdx.x * 8 + q4 * 2 + u8;
    const size_t base = hidx(r, d8);
    U4 hi, lo;
    hi.u = *(const uint4*)(hsh + base);
    lo.u = *(const uint4*)(hsh + base + 512);
    U4 oh, ol;
#pragma unroll
    for (int i = 0; i < 8; ++i) {
      const float f = (float)hi.b[i] + (float)lo.b[i] + smem[nl * 68 + q4 * 16 + u8 * 8 + i];
      const bf16_t h_ = (bf16_t)f;
      oh.b[i] = h_; ol.b[i] = (bf16_t)(f - (float)h_);
    }
    *(uint4*)(hsh + base) = oh.u;
    *(uint4*)(hsh + base + 512) = ol.u;
  }
}

// ---------------------------------------------------------------- GEMM 3 (split MFMA): reg_linear + BN partials
__global__ __launch_bounds__(256) void k_reg(const bf16_t* __restrict__ hsh,
    const bf16_t* __restrict__ BtF,
    float* __restrict__ y, float* __restrict__ partial) {
  __shared__ float sm[64 * 68];
  __shared__ float red[128];
  const int t = threadIdx.x;
  const int lane = t & 63, wave = t >> 6;
  const int l15 = lane & 15, quad = lane >> 4;
  const int ct = blockIdx.x, rb = blockIdx.y;
  const int c0 = ct * 64, r0 = rb * 64;
  const int wr = (wave & 1) * 32, wc = (wave >> 1) * 32;
  const int wr16 = (wave & 1) * 2, wc16 = (wave >> 1) * 2;
  const int q128l = quad * 128 + l15 * 8;
  floatx4 acc[2][2] = {};
  bf16x8 A[2][4], B[2][4];
#pragma unroll
  for (int u = 0; u < 4; ++u) {
    A[0][u] = *(const bf16x8*)(hsh + (size_t)(rb * 8) * 4096 +
                               ((wr16 + (u >> 1)) * 2 + (u & 1)) * 512 + q128l);
    B[0][u] = *(const bf16x8*)(BtF + (size_t)(ct * 8) * 4096 +
                               (u & 1) * 2048 + (wc16 + (u >> 1)) * 512 + q128l);
  }
#pragma unroll
  for (int kt = 0; kt < 8; ++kt) {
    const int cur = kt & 1, nxt = cur ^ 1;
    if (kt < 7) {
#pragma unroll
      for (int u = 0; u < 4; ++u) {
        A[nxt][u] = *(const bf16x8*)(hsh + (size_t)(rb * 8 + kt + 1) * 4096 +
                                     ((wr16 + (u >> 1)) * 2 + (u & 1)) * 512 + q128l);
        B[nxt][u] = *(const bf16x8*)(BtF + (size_t)(ct * 8 + kt + 1) * 4096 +
                                     (u & 1) * 2048 + (wc16 + (u >> 1)) * 512 + q128l);
      }
    }
    fma3(acc[0][0], A[cur][0], A[cur][1], B[cur][0], B[cur][1]);
    fma3(acc[0][1], A[cur][0], A[cur][1], B[cur][2], B[cur][3]);
    fma3(acc[1][0], A[cur][2], A[cur][3], B[cur][0], B[cur][1]);
    fma3(acc[1][1], A[cur][2], A[cur][3], B[cur][2], B[cur][3]);
  }
#pragma unroll
  for (int j = 0; j < 2; ++j) {
    float s = 0.f;
#pragma unroll
    for (int i = 0; i < 2; ++i)
#pragma unroll
      for (int r = 0; r < 4; ++r)
        s = fmaf(acc[i][j][r], acc[i][j][r], s);
    s += __shfl_down(s, 32);
    s += __shfl_down(s, 16);
    if (lane < 16) red[wave * 32 + j * 16 + lane] = s;
  }
#pragma unroll
  for (int i = 0; i < 2; ++i)
#pragma unroll
    for (int j = 0; j < 2; ++j)
#pragma unroll
      for (int r = 0; r < 4; ++r)
        sm[(wr + i * 16 + quad * 4 + r) * 68 + wc + j * 16 + l15] = acc[i][j][r];
  __syncthreads();
  const int nl = t >> 2, q4 = t & 3;
  const size_t gi = (size_t)(r0 + nl) * 256 + c0 + q4 * 16;
#pragma unroll
  for (int u = 0; u < 4; ++u) {
    float4 yv;
    yv.x = sm[nl * 68 + q4 * 16 + u * 4 + 0];
    yv.y = sm[nl * 68 + q4 * 16 + u * 4 + 1];
    yv.z = sm[nl * 68 + q4 * 16 + u * 4 + 2];
    yv.w = sm[nl * 68 + q4 * 16 + u * 4 + 3];
    *(float4*)(y + gi + u * 4) = yv;
  }
  if (t < 64) {
    const int w0 = (t >= 32) ? 2 : 0;
    const float v = red[w0 * 32 + (t & 31)] + red[(w0 + 1) * 32 + (t & 31)];
    partial[(size_t)blockIdx.y * 256 + c0 + t] = v;   // race-free: one slot per column
  }
}

// reduce partials over 1024 r-blocks -> stats[128]
__global__ __launch_bounds__(1024) void k_stat(const float* __restrict__ partial,
                                               float* __restrict__ st) {
  __shared__ float acc[4][256];
  __shared__ float tot[256];
  const int t = threadIdx.x;
  const int slot = t & 255, g = t >> 8;
  float s = 0.f;
  for (int r = g; r < 1024; r += 4) s += partial[(size_t)r * 256 + slot];
  acc[g][slot] = s;
  __syncthreads();
  if (t < 256) tot[t] = acc[0][t] + acc[1][t] + acc[2][t] + acc[3][t];
  __syncthreads();
  if (t < 64) {
    st[t] = tot[4 * t];
    st[64 + t] = tot[4 * t + 1] + tot[4 * t + 2] + tot[4 * t + 3];
  }
}

// ---------------------------------------------------------------- BN + norm-activation + residual
__global__ void k_bnact(const float* __restrict__ y, const float* __restrict__ stats,
    const float* __restrict__ g0, const float* __restrict__ g1, bf16_t* __restrict__ hsh) {
  const int idx = blockIdx.x * 256 + threadIdx.x;  // r*32 + d8
  const int r = idx >> 5, d8 = idx & 31;
  const int m0 = d8 * 2, m1 = m0 + 1;
  const float i00 = g0[m0] / sqrtf(stats[m0] * (1.0f / 65536.0f) + kEps);
  const float i10 = g1[m0] / sqrtf(stats[64 + m0] * (1.0f / 65536.0f) + kEps);
  const float i01 = g0[m1] / sqrtf(stats[m1] * (1.0f / 65536.0f) + kEps);
  const float i11 = g1[m1] / sqrtf(stats[64 + m1] * (1.0f / 65536.0f) + kEps);
  const float* yr = y + (size_t)r * 256 + d8 * 8;
  const float4 ya = *(const float4*)yr;
  const float4 yb = *(const float4*)(yr + 4);
  float a[8];
  {
    const float s = ya.x * i00;
    const float vx = ya.y * i10, vy = ya.z * i10, vz = ya.w * i10;
    const float so = s * sigmoidf(fabsf(s));
    const float vn = sqrtf(fmaf(vx, vx, fmaf(vy, vy, vz * vz)) + kEps);
    const float gv = sigmoidf(vn);
    a[0] = so; a[1] = vx * gv; a[2] = vy * gv; a[3] = vz * gv;
  }
  {
    const float s = yb.x * i01;
    const float vx = yb.y * i11, vy = yb.z * i11, vz = yb.w * i11;
    const float so = s * sigmoidf(fabsf(s));
    const float vn = sqrtf(fmaf(vx, vx, fmaf(vy, vy, vz * vz)) + kEps);
    const float gv = sigmoidf(vn);
    a[4] = so; a[5] = vx * gv; a[6] = vy * gv; a[7] = vz * gv;
  }
  const size_t base = hidx(r, d8);
  U4 hi, lo;
  hi.u = *(const uint4*)(hsh + base);
  lo.u = *(const uint4*)(hsh + base + 512);
  U4 oh, ol;
#pragma unroll
  for (int i = 0; i < 8; ++i) {
    const float f = (float)hi.b[i] + (float)lo.b[i] + a[i];
    const bf16_t h_ = (bf16_t)f;
    oh.b[i] = h_; ol.b[i] = (bf16_t)(f - (float)h_);
  }
  *(uint4*)(hsh + base) = oh.u;
  *(uint4*)(hsh + base + 512) = ol.u;
}

// ---------------------------------------------------------------- mean-pool + einsum
__global__ __launch_bounds__(256) void k_pool(const bf16_t* __restrict__ hsh,
    const float* __restrict__ w_out, float* __restrict__ out) {
  __shared__ float r0s[256], r1s[256], r2s[256];
  const int b = blockIdx.x;
  const int t = threadIdx.x;
  float p0 = 0, p1 = 0, p2 = 0;
  for (int idx = t; idx < kN * 32; idx += 256) {
    const int n = idx >> 5, d8 = idx & 31;
    const int r = (b << 10) + n;
    const size_t base = hidx(r, d8);
    U4 hi, lo;
    hi.u = *(const uint4*)(hsh + base);
    lo.u = *(const uint4*)(hsh + base + 512);
    const float w0 = w_out[d8 * 2], w1 = w_out[d8 * 2 + 1];
    p0 += ((float)hi.b[1] + (float)lo.b[1]) * w0 + ((float)hi.b[5] + (float)lo.b[5]) * w1;
    p1 += ((float)hi.b[2] + (float)lo.b[2]) * w0 + ((float)hi.b[6] + (float)lo.b[6]) * w1;
    p2 += ((float)hi.b[3] + (float)lo.b[3]) * w0 + ((float)hi.b[7] + (float)lo.b[7]) * w1;
  }
  r0s[t] = p0; r1s[t] = p1; r2s[t] = p2;
  __syncthreads();
  for (int s = 128; s > 0; s >>= 1) {
    if (t < s) { r0s[t] += r0s[t + s]; r1s[t] += r1s[t + s]; r2s[t] += r2s[t + s]; }
    __syncthreads();
  }
  if (t == 0) {
    out[b * 3 + 0] = r0s[0] * (1.0f / kN);
    out[b * 3 + 1] = r1s[0] * (1.0f / kN);
    out[b * 3 + 2] = r2s[0] * (1.0f / kN);
  }
}

} // namespace

extern "C" void kernel_launch(void* const* d_in, const int* in_sizes, int n_in,
                              void* d_out, int out_size, void* d_ws, size_t ws_size,
                              hipStream_t stream) {
  const float* x       = (const float*)d_in[0];
  const float* tok_emb = (const float*)d_in[1];
  const float* Wf      = (const float*)d_in[2];
  const float* wv      = (const float*)d_in[3];
  const float* w_out   = (const float*)d_in[4];

  float* ws    = (float*)d_ws;
  bf16_t* hsh  = (bf16_t*)ws;                          // 33,554,432 bf16 = 16,777,216 fl
  float*  kvt  = ws + 16777216;                        // 23,592,960 fl
  float*  qt   = kvt + 23592960;                       // 23,592,960 fl
  float*  y    = qt;                                   // alias: qt dead once k_mix done
  float*  partial = qt + 20000000;                     // 262,144 fl inside qt region, past y end
  float*  s0   = qt + 23592960;                        //     65,536 fl
  float*  kf   = s0 + 65536;                           //    737,280 fl
  bf16_t* wall = (bf16_t*)(kf + 737280);               // 6*8*12288 = 589,824 bf16
  bf16_t* WoF  = wall + 589824;                        // 4*12*4096 = 196,608 bf16
  bf16_t* BtF  = WoF + 196608;                         // 4*8*4096  = 131,072 bf16
  float* stats = (float*)(BtF + 131072);               // 384 fl
  float* twg   = stats + 384;                          // 1,024 fl (512 float2)

  k_tw<<<2, 256, 0, stream>>>((float2*)twg);
  k_s0<<<kN, 64, 0, stream>>>(tok_emb, Wf, s0);
  k_h0<<<8192, 256, 0, stream>>>(x, wv, s0, hsh);

  for (int l = 0; l < 3; ++l) {
    const float* Wq   = (const float*)d_in[5 + 9 * l + 0];
    const float* Wk   = (const float*)d_in[5 + 9 * l + 1];
    const float* Wv   = (const float*)d_in[5 + 9 * l + 2];
    const float* filt = (const float*)d_in[5 + 9 * l + 3];
    const float* Wo   = (const float*)d_in[5 + 9 * l + 4];
    const float* Wm0  = (const float*)d_in[5 + 9 * l + 5];
    const float* Wm1  = (const float*)d_in[5 + 9 * l + 6];
    const float* g0   = (const float*)d_in[5 + 9 * l + 7];
    const float* g1   = (const float*)d_in[5 + 9 * l + 8];
    const int H = (l == 2) ? 160 : 360;
    const int gy = (H + 63) / 64;                      // 6 or 3
    const int KT = gy * 2;                             // K chunks of 32 (zero-padded weights)
    float* st = stats + l * 128;

    k_wqkv<<<384, 256, 0, stream>>>(Wq, Wk, Wv, H, wall);
    k_wo<<<256, 384, 0, stream>>>(Wo, H, WoF);
    k_bt<<<256, 256, 0, stream>>>(Wm0, Wm1, BtF);
    k_kf<<<H, 256, 0, stream>>>(filt, H, (const float2*)twg, (float2*)kf);
    k_qkv<<<dim3(gy, 1024), 256, 0, stream>>>(hsh, wall, H, qt, kvt);
    k_conv<<<32 * H, 256, 0, stream>>>(kvt, (const float2*)kf, (const float2*)twg, H);
    k_mix<<<dim3(4, 1024), 256, 0, stream>>>(qt, kvt, H, KT, WoF, hsh);
    k_reg<<<dim3(4, 1024), 256, 0, stream>>>(hsh, BtF, y, partial);
    k_stat<<<1, 1024, 0, stream>>>(partial, st);
    k_bnact<<<8192, 256, 0, stream>>>(y, st, g0, g1, hsh);
  }

  k_pool<<<64, 256, 0, stream>>>(hsh, w_out, (float*)d_out);
}

// Round 9
// 1595.398 us; speedup vs baseline: 1.6556x; 1.0195x over previous
//
#include <hip/hip_runtime.h>
#include <math.h>

namespace {

typedef __bf16 bf16_t;
typedef bf16_t bf16x8 __attribute__((ext_vector_type(8)));
typedef float floatx4 __attribute__((ext_vector_type(4)));

constexpr int kN = 1024;      // tokens
constexpr int kM = 64;        // multiplicity
constexpr int kP = 64;        // PE dim
constexpr float kEps = 1e-5f;
constexpr int kFN = 1024;     // FFT length

__device__ __forceinline__ float sigmoidf(float v) { return 1.0f / (1.0f + expf(-v)); }

__device__ __forceinline__ floatx4 mfma16(bf16x8 a, bf16x8 b, floatx4 c) {
  return __builtin_amdgcn_mfma_f32_16x16x32_bf16(a, b, c, 0, 0, 0);
}

// 3-term split product: acc += (ah+al)*(bh+bl) dropping al*bl
__device__ __forceinline__ void fma3(floatx4& acc, bf16x8 ah, bf16x8 al,
                                     bf16x8 bh, bf16x8 bl) {
  acc = mfma16(ah, bh, acc);
  acc = mfma16(ah, bl, acc);
  acc = mfma16(al, bh, acc);
}

// load 8 contiguous fp32 (LDS), split into hi/lo bf16 fragments
__device__ __forceinline__ void load_split8(const float* p, bf16x8& hi, bf16x8& lo) {
  const float4 u = *(const float4*)p;
  const float4 v = *(const float4*)(p + 4);
  const float a[8] = {u.x, u.y, u.z, u.w, v.x, v.y, v.z, v.w};
#pragma unroll
  for (int i = 0; i < 8; ++i) {
    const bf16_t h_ = (bf16_t)a[i];
    hi[i] = h_;
    lo[i] = (bf16_t)(a[i] - (float)h_);
  }
}

union U4 { uint4 u; bf16_t b[8]; };

// async 16B/lane global->LDS DMA (wave-uniform LDS base + lane*16 scatter)
__device__ __forceinline__ void glds16(const bf16_t* g, bf16_t* l) {
  __builtin_amdgcn_global_load_lds(
      (const __attribute__((address_space(1))) void*)g,
      (__attribute__((address_space(3))) void*)l, 16, 0, 0);
}

// hsh fragment-major index for (row r, 8-elem group d8), hi plane (lo = +512)
// layout: [rb(1024)][kc(8)][rgrp(4)][p(2)][quad(4)][rl(16)][off(8)]
__device__ __forceinline__ size_t hidx(int r, int d8) {
  const int rb = r >> 6, rr = r & 63;
  return (size_t)(rb * 8 + (d8 >> 2)) * 4096 + (rr >> 4) * 1024 + (d8 & 3) * 128 + (rr & 15) * 8;
}

// padded LDS index for FFT work array (breaks small-span bank conflicts)
__device__ __forceinline__ int zi(int i) { return i + (i >> 4); }

__device__ __forceinline__ float2 cadd(float2 a, float2 b) { return {a.x + b.x, a.y + b.y}; }
__device__ __forceinline__ float2 csub(float2 a, float2 b) { return {a.x - b.x, a.y - b.y}; }
__device__ __forceinline__ float2 cmul(float2 a, float2 w) {
  return {a.x * w.x - a.y * w.y, a.x * w.y + a.y * w.x};
}
__device__ __forceinline__ float2 cmulc(float2 a, float2 w) {   // a * conj(w)
  return {a.x * w.x + a.y * w.y, a.y * w.x - a.x * w.y};
}

// ---------------------------------------------------------------- init
// s0[n, m] = sum_p (pe[n,p] + tok_emb[tt[n],p]) * Wf[p,m]
__global__ void k_s0(const float* __restrict__ tok_emb, const float* __restrict__ Wf,
                     float* __restrict__ s0) {
  __shared__ float f[kP];
  const int n = blockIdx.x;
  const int t = threadIdx.x;                       // 64 threads
  const int tt = (n == kN - 1) ? 2 : (n & 1);
  const int j = t >> 1;
  const float cexp = (float)(-9.210340371976184 / 64.0);   // -ln(10000)/P
  const float divj = expf((float)(2 * j) * cexp);
  const float ang = (float)n * divj;
  const float pe = (t & 1) ? cosf(ang) : sinf(ang);
  f[t] = pe + tok_emb[tt * kP + t];
  __syncthreads();
  float acc = 0.0f;
#pragma unroll 8
  for (int p = 0; p < kP; ++p) acc = fmaf(f[p], Wf[p * kM + t], acc);
  s0[n * kM + t] = acc;
}

// h planes (fragment-major): irreps m0=d8*2, m1=m0+1 per thread
__global__ void k_h0(const float* __restrict__ x, const float* __restrict__ wv,
                     const float* __restrict__ s0, bf16_t* __restrict__ hsh) {
  const int idx = blockIdx.x * 256 + threadIdx.x;  // r*32 + d8
  const int r = idx >> 5, d8 = idx & 31;
  const int n = r & (kN - 1);
  const int m0 = d8 * 2, m1 = m0 + 1;
  const float w0 = wv[m0], w1 = wv[m1];
  const float x0 = x[r * 3 + 0], x1 = x[r * 3 + 1], x2 = x[r * 3 + 2];
  float f[8];
  f[0] = s0[n * kM + m0]; f[1] = x0 * w0; f[2] = x1 * w0; f[3] = x2 * w0;
  f[4] = s0[n * kM + m1]; f[5] = x0 * w1; f[6] = x1 * w1; f[7] = x2 * w1;
  U4 oh, ol;
#pragma unroll
  for (int i = 0; i < 8; ++i) {
    const bf16_t h_ = (bf16_t)f[i];
    oh.b[i] = h_; ol.b[i] = (bf16_t)(f[i] - (float)h_);
  }
  const size_t base = hidx(r, d8);
  *(uint4*)(hsh + base) = oh.u;
  *(uint4*)(hsh + base + 512) = ol.u;
}

// ---------------------------------------------------------------- weight prep (batched, all 3 layers)
// wall per (ct,kc): [mat(3)][p(2)][cgrp(4)][quad(4)][cl(16)][off(8)] = 12288 elems
__global__ void k_wqkv3(const float* __restrict__ Wq0, const float* __restrict__ Wk0,
                        const float* __restrict__ Wv0,
                        const float* __restrict__ Wq1, const float* __restrict__ Wk1,
                        const float* __restrict__ Wv1,
                        const float* __restrict__ Wq2, const float* __restrict__ Wk2,
                        const float* __restrict__ Wv2, bf16_t* __restrict__ wall3) {
  const int l = blockIdx.y;
  const int H = (l == 2) ? 160 : 360;
  const int gy = (l == 2) ? 3 : 6;
  const int c = blockIdx.x;    // 0..383
  if (c >= gy * 64) return;
  const int k = threadIdx.x;   // 0..255
  const float* Wq = (l == 0) ? Wq0 : ((l == 1) ? Wq1 : Wq2);
  const float* Wk = (l == 0) ? Wk0 : ((l == 1) ? Wk1 : Wk2);
  const float* Wv = (l == 0) ? Wv0 : ((l == 1) ? Wv1 : Wv2);
  bf16_t* wall = wall3 + ((l == 2) ? 1179648 : (size_t)l * 589824);
  const bool ok = c < H;
  const float w[3] = {ok ? Wq[k * H + c] : 0.f, ok ? Wk[k * H + c] : 0.f,
                      ok ? Wv[k * H + c] : 0.f};
  const int ct = c >> 6, cgrp = (c >> 4) & 3, cl = c & 15;
  const int kc = k >> 5, quad = (k >> 3) & 3, off = k & 7;
  const size_t base = (size_t)(ct * 8 + kc) * 12288 + cgrp * 512 + quad * 128 + cl * 8 + off;
#pragma unroll
  for (int mat = 0; mat < 3; ++mat) {
    const bf16_t hi = (bf16_t)w[mat];
    wall[base + mat * 4096] = hi;
    wall[base + mat * 4096 + 2048] = (bf16_t)(w[mat] - (float)hi);
  }
}

// WoF per (dt,kc of 12): [p(2)][dgrp(4)][quad(4)][dl(16)][off(8)] = 4096 elems
__global__ void k_wo3(const float* __restrict__ Wo0, const float* __restrict__ Wo1,
                      const float* __restrict__ Wo2, bf16_t* __restrict__ WoF3) {
  const int l = blockIdx.y;
  const int H = (l == 2) ? 160 : 360;
  const float* Wo = (l == 0) ? Wo0 : ((l == 1) ? Wo1 : Wo2);
  bf16_t* WoF = WoF3 + (size_t)l * 196608;
  const int d = blockIdx.x;    // 0..255
  const int c = threadIdx.x;   // 0..383
  const float w = (c < H) ? Wo[c * 256 + d] : 0.f;
  const int dt = d >> 6, dgrp = (d >> 4) & 3, dl = d & 15;
  const int kc = c >> 5, quad = (c >> 3) & 3, off = c & 7;
  const size_t base = (size_t)(dt * 12 + kc) * 4096 + dgrp * 512 + quad * 128 + dl * 8 + off;
  const bf16_t hi = (bf16_t)w;
  WoF[base] = hi;
  WoF[base + 2048] = (bf16_t)(w - (float)hi);
}

// BtF per (ct,kc of 8): [p(2)][cgrp(4)][quad(4)][cl(16)][off(8)] = 4096 elems
__global__ void k_bt3(const float* __restrict__ W00, const float* __restrict__ W10,
                      const float* __restrict__ W01, const float* __restrict__ W11,
                      const float* __restrict__ W02, const float* __restrict__ W12,
                      bf16_t* __restrict__ BtF3) {
  const int l = blockIdx.y;
  const float* W0 = (l == 0) ? W00 : ((l == 1) ? W01 : W02);
  const float* W1 = (l == 0) ? W10 : ((l == 1) ? W11 : W12);
  bf16_t* BtF = BtF3 + (size_t)l * 131072;
  const int col = blockIdx.x, row = threadIdx.x;
  const int k = col >> 2, ck = col & 3, m = row >> 2, cm = row & 3;
  float v = 0.f;
  if (cm == ck) v = (ck == 0 ? W0 : W1)[m * 64 + k];
  const int ct = col >> 6, cgrp = (col >> 4) & 3, cl = col & 15;
  const int kc = row >> 5, quad = (row >> 3) & 3, off = row & 7;
  const size_t base = (size_t)(ct * 8 + kc) * 4096 + cgrp * 512 + quad * 128 + cl * 8 + off;
  const bf16_t hi = (bf16_t)v;
  BtF[base] = hi;
  BtF[base + 2048] = (bf16_t)(v - (float)hi);
}

// ---------------------------------------------------------------- FFT (fused radix-2 pairs)
// twiddle table -> global (once per launch)
__global__ void k_tw(float2* __restrict__ twg) {
  const int j = blockIdx.x * 256 + threadIdx.x;
  if (j < kFN / 2) {
    float s, c;
    sincosf(-6.283185307179586f * (float)j / (float)kFN, &s, &c);
    twg[j].x = c; twg[j].y = s;
  }
}

// forward DIF, two radix-2 stages fused per barrier: natural in -> bit-reversed out
__device__ void fft_dif(float2* z, const float2* tw) {
  const int p = threadIdx.x;
#pragma unroll
  for (int m = 256; m >= 1; m >>= 2) {     // fused spans (2m, m): (512,256)...(2,1)
    __syncthreads();
    const int pm = p & (m - 1);
    const int j = ((p & ~(m - 1)) << 2) | pm;
    const int tm2 = 512 / (2 * m), tm1 = 512 / m;
    const float2 x0 = z[zi(j)], x1 = z[zi(j + m)];
    const float2 x2 = z[zi(j + 2 * m)], x3 = z[zi(j + 3 * m)];
    const float2 w2 = tw[pm * tm2], w2b = tw[(pm + m) * tm2], w1 = tw[pm * tm1];
    const float2 a0 = cadd(x0, x2), a2 = cmul(csub(x0, x2), w2);
    const float2 a1 = cadd(x1, x3), a3 = cmul(csub(x1, x3), w2b);
    z[zi(j)]         = cadd(a0, a1);
    z[zi(j + m)]     = cmul(csub(a0, a1), w1);
    z[zi(j + 2 * m)] = cadd(a2, a3);
    z[zi(j + 3 * m)] = cmul(csub(a2, a3), w1);
  }
}

// inverse DIT, fused: bit-reversed in -> natural out (caller scales by 1/N)
__device__ void fft_dit_inv(float2* z, const float2* tw) {
  const int p = threadIdx.x;
#pragma unroll
  for (int m = 1; m <= 256; m <<= 2) {     // fused spans (m, 2m): (1,2)...(256,512)
    __syncthreads();
    const int pm = p & (m - 1);
    const int j = ((p & ~(m - 1)) << 2) | pm;
    const int tm2 = 512 / (2 * m), tm1 = 512 / m;
    const float2 x0 = z[zi(j)], x1 = z[zi(j + m)];
    const float2 x2 = z[zi(j + 2 * m)], x3 = z[zi(j + 3 * m)];
    const float2 w1 = tw[pm * tm1], w2 = tw[pm * tm2], w2b = tw[(pm + m) * tm2];
    const float2 c1 = cmulc(x1, w1), c3 = cmulc(x3, w1);
    const float2 b0 = cadd(x0, c1), b1 = csub(x0, c1);
    const float2 b2 = cadd(x2, c3), b3 = csub(x2, c3);
    const float2 d2 = cmulc(b2, w2), d3 = cmulc(b3, w2b);
    z[zi(j)]         = cadd(b0, d2);
    z[zi(j + 2 * m)] = csub(b0, d2);
    z[zi(j + m)]     = cadd(b1, d3);
    z[zi(j + 3 * m)] = csub(b1, d3);
  }
}

// filter spectrum, stored in DIF (bit-reversed) order; one block per channel
__global__ __launch_bounds__(256) void k_kf(const float* __restrict__ filt, int H,
                                            const float2* __restrict__ twg,
                                            float2* __restrict__ kf) {
  __shared__ float2 z[kFN + kFN / 16];
  __shared__ float2 tw[kFN / 2];
  const int c = blockIdx.x;
  for (int j = threadIdx.x; j < kFN / 2; j += 256) tw[j] = twg[j];
  for (int n = threadIdx.x; n < kFN; n += 256) {
    z[zi(n)].x = filt[n * H + c];
    z[zi(n)].y = 0.0f;
  }
  fft_dif(z, tw);
  __syncthreads();
  for (int j = threadIdx.x; j < kFN; j += 256) kf[c * kFN + j] = z[zi(j)];
}

// packed circular conv: two batch rows (same channel) per complex FFT
// IFFT(FFT(kv[b0] + i*kv[b1]) * F) = conv(b0) + i*conv(b1)  (conv real, F shared)
__global__ __launch_bounds__(256) void k_conv(float* kvt, const float2* __restrict__ kf,
                                              const float2* __restrict__ twg, int H) {
  __shared__ float2 z[kFN + kFN / 16];
  __shared__ float2 tw[kFN / 2];
  const int blk = blockIdx.x;              // pb*H + c
  const int c = blk % H;
  const int pb = blk / H;
  float* sig0 = kvt + (((size_t)((2 * pb) * H + c)) << 10);
  float* sig1 = kvt + (((size_t)((2 * pb + 1) * H + c)) << 10);
  for (int j = threadIdx.x; j < kFN / 2; j += 256) tw[j] = twg[j];
  for (int n = threadIdx.x; n < kFN; n += 256) {
    z[zi(n)].x = sig0[n];
    z[zi(n)].y = sig1[n];
  }
  fft_dif(z, tw);
  __syncthreads();
  for (int j = threadIdx.x; j < kFN; j += 256) {
    const float2 a = z[zi(j)];
    const float2 b = kf[c * kFN + j];
    float2 o;
    o.x = a.x * b.x - a.y * b.y;
    o.y = a.x * b.y + a.y * b.x;
    z[zi(j)] = o;
  }
  fft_dit_inv(z, tw);
  __syncthreads();
  const float s = 1.0f / (float)kFN;
  for (int n = threadIdx.x; n < kFN; n += 256) {
    sig0[n] = z[zi(n)].x * s;
    sig1[n] = z[zi(n)].y * s;
  }
}

// ---------------------------------------------------------------- GEMM 1 (split MFMA, LDS-DMA): q/k/v
__global__ __launch_bounds__(256) void k_qkv(const bf16_t* __restrict__ hsh,
    const bf16_t* __restrict__ wall, int H,
    float* __restrict__ qt, float* __restrict__ kvt) {
  __shared__ bf16_t lds[16384];            // 32 KB: A 8KB (segs 0-7) + B 24KB (segs 8-31)
  const int t = threadIdx.x;
  const int lane = t & 63, wave = t >> 6;
  const int l15 = lane & 15, quad = lane >> 4;
  const int ct = blockIdx.x, rb = blockIdx.y;
  const int r0 = rb * 64, c0 = ct * 64;
  const int wr = (wave & 1) * 32, wc = (wave >> 1) * 32;
  const int wr16 = (wave & 1) * 2, wc16 = (wave >> 1) * 2;
  const int q128l = quad * 128 + l15 * 8;
  floatx4 aq[2][2] = {}, ak_[2][2] = {}, av_[2][2] = {};
  for (int kt = 0; kt < 8; ++kt) {
    {
      const bf16_t* Asrc = hsh + (size_t)(rb * 8 + kt) * 4096;
      const bf16_t* Bsrc = wall + (size_t)(ct * 8 + kt) * 12288 - 8 * 512;
#pragma unroll
      for (int s = 0; s < 8; ++s) {
        const int seg = wave * 8 + s;
        const bf16_t* src = (wave == 0) ? (Asrc + seg * 512 + lane * 8)
                                        : (Bsrc + seg * 512 + lane * 8);
        glds16(src, &lds[seg * 512]);
      }
    }
    __syncthreads();
    const bf16x8 a0h = *(const bf16x8*)(lds + ((wr16 + 0) * 2 + 0) * 512 + q128l);
    const bf16x8 a0l = *(const bf16x8*)(lds + ((wr16 + 0) * 2 + 1) * 512 + q128l);
    const bf16x8 a1h = *(const bf16x8*)(lds + ((wr16 + 1) * 2 + 0) * 512 + q128l);
    const bf16x8 a1l = *(const bf16x8*)(lds + ((wr16 + 1) * 2 + 1) * 512 + q128l);
    {
      const int bb = 4096;                 // mat 0 (q)
      const bf16x8 bh0 = *(const bf16x8*)(lds + bb + (wc16 + 0) * 512 + q128l);
      const bf16x8 bl0 = *(const bf16x8*)(lds + bb + 2048 + (wc16 + 0) * 512 + q128l);
      const bf16x8 bh1 = *(const bf16x8*)(lds + bb + (wc16 + 1) * 512 + q128l);
      const bf16x8 bl1 = *(const bf16x8*)(lds + bb + 2048 + (wc16 + 1) * 512 + q128l);
      fma3(aq[0][0], a0h, a0l, bh0, bl0); fma3(aq[0][1], a0h, a0l, bh1, bl1);
      fma3(aq[1][0], a1h, a1l, bh0, bl0); fma3(aq[1][1], a1h, a1l, bh1, bl1);
    }
    {
      const int bb = 4096 + 4096;          // mat 1 (k)
      const bf16x8 bh0 = *(const bf16x8*)(lds + bb + (wc16 + 0) * 512 + q128l);
      const bf16x8 bl0 = *(const bf16x8*)(lds + bb + 2048 + (wc16 + 0) * 512 + q128l);
      const bf16x8 bh1 = *(const bf16x8*)(lds + bb + (wc16 + 1) * 512 + q128l);
      const bf16x8 bl1 = *(const bf16x8*)(lds + bb + 2048 + (wc16 + 1) * 512 + q128l);
      fma3(ak_[0][0], a0h, a0l, bh0, bl0); fma3(ak_[0][1], a0h, a0l, bh1, bl1);
      fma3(ak_[1][0], a1h, a1l, bh0, bl0); fma3(ak_[1][1], a1h, a1l, bh1, bl1);
    }
    {
      const int bb = 4096 + 8192;          // mat 2 (v)
      const bf16x8 bh0 = *(const bf16x8*)(lds + bb + (wc16 + 0) * 512 + q128l);
      const bf16x8 bl0 = *(const bf16x8*)(lds + bb + 2048 + (wc16 + 0) * 512 + q128l);
      const bf16x8 bh1 = *(const bf16x8*)(lds + bb + (wc16 + 1) * 512 + q128l);
      const bf16x8 bl1 = *(const bf16x8*)(lds + bb + 2048 + (wc16 + 1) * 512 + q128l);
      fma3(av_[0][0], a0h, a0l, bh0, bl0); fma3(av_[0][1], a0h, a0l, bh1, bl1);
      fma3(av_[1][0], a1h, a1l, bh0, bl0); fma3(av_[1][1], a1h, a1l, bh1, bl1);
    }
    __syncthreads();
  }
  const int b = r0 >> 10;
  const int n0 = r0 & 1023;
#pragma unroll
  for (int j = 0; j < 2; ++j) {
    const int c = c0 + wc + j * 16 + l15;
    if (c < H) {
      const size_t rbw = (((size_t)(b * H + c)) << 10) + n0 + wr + quad * 4;
#pragma unroll
      for (int i = 0; i < 2; ++i) {
        float4 p;
        p.x = aq[i][j][0]; p.y = aq[i][j][1];
        p.z = aq[i][j][2]; p.w = aq[i][j][3];
        *(float4*)(qt + rbw + i * 16) = p;
      }
#pragma unroll
      for (int i = 0; i < 2; ++i) {
        float4 p;
        p.x = ak_[i][j][0] * av_[i][j][0];
        p.y = ak_[i][j][1] * av_[i][j][1];
        p.z = ak_[i][j][2] * av_[i][j][2];
        p.w = ak_[i][j][3] * av_[i][j][3];
        *(float4*)(kvt + rbw + i * 16) = p;
      }
    }
  }
}

// ---------------------------------------------------------------- GEMM 2 (split MFMA): h += (q*conv) @ Wo
__global__ __launch_bounds__(256) void k_mix(const float* __restrict__ qt,
    const float* __restrict__ kvt, int H, int KT,
    const bf16_t* __restrict__ WoF, bf16_t* __restrict__ hsh) {
  __shared__ float smem[4352];             // As: 64 n x 36 ; epilogue: 64 x 68
  const int t = threadIdx.x;
  const int lane = t & 63, wave = t >> 6;
  const int l15 = lane & 15, quad = lane >> 4;
  const int dt = blockIdx.x, r0 = blockIdx.y * 64;
  const int b = r0 >> 10, n0 = r0 & 1023;
  const int wr = (wave & 1) * 32, wc16 = (wave >> 1) * 2;
  const int q128l = quad * 128 + l15 * 8;
  floatx4 acc[2][2] = {};
  const int cl = t >> 3, n8 = (t & 7) * 8;
  for (int kt = 0; kt < KT; ++kt) {
    const int ck0 = kt * 32;
    __syncthreads();
    {
      const int c = ck0 + cl;
      float p[8] = {};
      if (c < H) {
        const size_t o = (((size_t)(b * H + c)) << 10) + n0 + n8;
        const float4 q0 = *(const float4*)(qt + o);
        const float4 q1 = *(const float4*)(qt + o + 4);
        const float4 v0 = *(const float4*)(kvt + o);
        const float4 v1 = *(const float4*)(kvt + o + 4);
        p[0] = q0.x * v0.x; p[1] = q0.y * v0.y; p[2] = q0.z * v0.z; p[3] = q0.w * v0.w;
        p[4] = q1.x * v1.x; p[5] = q1.y * v1.y; p[6] = q1.z * v1.z; p[7] = q1.w * v1.w;
      }
#pragma unroll
      for (int u = 0; u < 8; ++u) smem[(n8 + u) * 36 + cl] = p[u];
    }
    __syncthreads();
    bf16x8 ah0, al0, ah1, al1;
    load_split8(smem + (wr + l15) * 36 + quad * 8, ah0, al0);
    load_split8(smem + (wr + 16 + l15) * 36 + quad * 8, ah1, al1);
    const bf16_t* Bb = WoF + (size_t)(dt * 12 + kt) * 4096;
    const bf16x8 bh0 = *(const bf16x8*)(Bb + (wc16 + 0) * 512 + q128l);
    const bf16x8 bl0 = *(const bf16x8*)(Bb + 2048 + (wc16 + 0) * 512 + q128l);
    const bf16x8 bh1 = *(const bf16x8*)(Bb + (wc16 + 1) * 512 + q128l);
    const bf16x8 bl1 = *(const bf16x8*)(Bb + 2048 + (wc16 + 1) * 512 + q128l);
    fma3(acc[0][0], ah0, al0, bh0, bl0); fma3(acc[0][1], ah0, al0, bh1, bl1);
    fma3(acc[1][0], ah1, al1, bh0, bl0); fma3(acc[1][1], ah1, al1, bh1, bl1);
  }
  __syncthreads();
#pragma unroll
  for (int i = 0; i < 2; ++i)
#pragma unroll
    for (int j = 0; j < 2; ++j)
#pragma unroll
      for (int r = 0; r < 4; ++r)
        smem[(wr + i * 16 + quad * 4 + r) * 68 + (wave >> 1) * 32 + j * 16 + l15] = acc[i][j][r];
  __syncthreads();
  const int nl = t >> 2, q4 = t & 3;
  const int r = r0 + nl;
#pragma unroll
  for (int u8 = 0; u8 < 2; ++u8) {
    const int d8 = blockIdx.x * 8 + q4 * 2 + u8;
    const size_t base = hidx(r, d8);
    U4 hi, lo;
    hi.u = *(const uint4*)(hsh + base);
    lo.u = *(const uint4*)(hsh + base + 512);
    U4 oh, ol;
#pragma unroll
    for (int i = 0; i < 8; ++i) {
      const float f = (float)hi.b[i] + (float)lo.b[i] + smem[nl * 68 + q4 * 16 + u8 * 8 + i];
      const bf16_t h_ = (bf16_t)f;
      oh.b[i] = h_; ol.b[i] = (bf16_t)(f - (float)h_);
    }
    *(uint4*)(hsh + base) = oh.u;
    *(uint4*)(hsh + base + 512) = ol.u;
  }
}

// ---------------------------------------------------------------- GEMM 3 (split MFMA, LDS-DMA): reg_linear + BN partials
__global__ __launch_bounds__(256) void k_reg(const bf16_t* __restrict__ hsh,
    const bf16_t* __restrict__ BtF,
    float* __restrict__ y, float* __restrict__ partial) {
  __shared__ float smf[64 * 68];           // epilogue buffer; aliased as 16KB DMA staging
  __shared__ float red[128];
  bf16_t* lds = (bf16_t*)smf;
  const int t = threadIdx.x;
  const int lane = t & 63, wave = t >> 6;
  const int l15 = lane & 15, quad = lane >> 4;
  const int ct = blockIdx.x, rb = blockIdx.y;
  const int c0 = ct * 64, r0 = rb * 64;
  const int wr = (wave & 1) * 32, wc = (wave >> 1) * 32;
  const int wr16 = (wave & 1) * 2, wc16 = (wave >> 1) * 2;
  const int q128l = quad * 128 + l15 * 8;
  floatx4 acc[2][2] = {};
  for (int kt = 0; kt < 8; ++kt) {
    {
      const bf16_t* Asrc = hsh + (size_t)(rb * 8 + kt) * 4096;
      const bf16_t* Bsrc = BtF + (size_t)(ct * 8 + kt) * 4096 - 8 * 512;
#pragma unroll
      for (int s = 0; s < 4; ++s) {
        const int seg = wave * 4 + s;
        const bf16_t* src = (seg < 8) ? (Asrc + seg * 512 + lane * 8)
                                      : (Bsrc + seg * 512 + lane * 8);
        glds16(src, &lds[seg * 512]);
      }
    }
    __syncthreads();
    const bf16x8 a0h = *(const bf16x8*)(lds + ((wr16 + 0) * 2 + 0) * 512 + q128l);
    const bf16x8 a0l = *(const bf16x8*)(lds + ((wr16 + 0) * 2 + 1) * 512 + q128l);
    const bf16x8 a1h = *(const bf16x8*)(lds + ((wr16 + 1) * 2 + 0) * 512 + q128l);
    const bf16x8 a1l = *(const bf16x8*)(lds + ((wr16 + 1) * 2 + 1) * 512 + q128l);
    const bf16x8 bh0 = *(const bf16x8*)(lds + 4096 + (wc16 + 0) * 512 + q128l);
    const bf16x8 bl0 = *(const bf16x8*)(lds + 4096 + 2048 + (wc16 + 0) * 512 + q128l);
    const bf16x8 bh1 = *(const bf16x8*)(lds + 4096 + (wc16 + 1) * 512 + q128l);
    const bf16x8 bl1 = *(const bf16x8*)(lds + 4096 + 2048 + (wc16 + 1) * 512 + q128l);
    fma3(acc[0][0], a0h, a0l, bh0, bl0); fma3(acc[0][1], a0h, a0l, bh1, bl1);
    fma3(acc[1][0], a1h, a1l, bh0, bl0); fma3(acc[1][1], a1h, a1l, bh1, bl1);
    __syncthreads();
  }
#pragma unroll
  for (int j = 0; j < 2; ++j) {
    float s = 0.f;
#pragma unroll
    for (int i = 0; i < 2; ++i)
#pragma unroll
      for (int r = 0; r < 4; ++r)
        s = fmaf(acc[i][j][r], acc[i][j][r], s);
    s += __shfl_down(s, 32);
    s += __shfl_down(s, 16);
    if (lane < 16) red[wave * 32 + j * 16 + lane] = s;
  }
#pragma unroll
  for (int i = 0; i < 2; ++i)
#pragma unroll
    for (int j = 0; j < 2; ++j)
#pragma unroll
      for (int r = 0; r < 4; ++r)
        smf[(wr + i * 16 + quad * 4 + r) * 68 + wc + j * 16 + l15] = acc[i][j][r];
  __syncthreads();
  const int nl = t >> 2, q4 = t & 3;
  const size_t gi = (size_t)(r0 + nl) * 256 + c0 + q4 * 16;
#pragma unroll
  for (int u = 0; u < 4; ++u) {
    float4 yv;
    yv.x = smf[nl * 68 + q4 * 16 + u * 4 + 0];
    yv.y = smf[nl * 68 + q4 * 16 + u * 4 + 1];
    yv.z = smf[nl * 68 + q4 * 16 + u * 4 + 2];
    yv.w = smf[nl * 68 + q4 * 16 + u * 4 + 3];
    *(float4*)(y + gi + u * 4) = yv;
  }
  if (t < 64) {
    const int w0 = (t >= 32) ? 2 : 0;
    const float v = red[w0 * 32 + (t & 31)] + red[(w0 + 1) * 32 + (t & 31)];
    partial[(size_t)blockIdx.y * 256 + c0 + t] = v;   // race-free: one slot per column
  }
}

// reduce partials over 1024 r-blocks -> stats[128]
__global__ __launch_bounds__(1024) void k_stat(const float* __restrict__ partial,
                                               float* __restrict__ st) {
  __shared__ float acc[4][256];
  __shared__ float tot[256];
  const int t = threadIdx.x;
  const int slot = t & 255, g = t >> 8;
  float s = 0.f;
  for (int r = g; r < 1024; r += 4) s += partial[(size_t)r * 256 + slot];
  acc[g][slot] = s;
  __syncthreads();
  if (t < 256) tot[t] = acc[0][t] + acc[1][t] + acc[2][t] + acc[3][t];
  __syncthreads();
  if (t < 64) {
    st[t] = tot[4 * t];
    st[64 + t] = tot[4 * t + 1] + tot[4 * t + 2] + tot[4 * t + 3];
  }
}

// ---------------------------------------------------------------- BN + norm-activation + residual
__global__ void k_bnact(const float* __restrict__ y, const float* __restrict__ stats,
    const float* __restrict__ g0, const float* __restrict__ g1, bf16_t* __restrict__ hsh) {
  const int idx = blockIdx.x * 256 + threadIdx.x;  // r*32 + d8
  const int r = idx >> 5, d8 = idx & 31;
  const int m0 = d8 * 2, m1 = m0 + 1;
  const float i00 = g0[m0] / sqrtf(stats[m0] * (1.0f / 65536.0f) + kEps);
  const float i10 = g1[m0] / sqrtf(stats[64 + m0] * (1.0f / 65536.0f) + kEps);
  const float i01 = g0[m1] / sqrtf(stats[m1] * (1.0f / 65536.0f) + kEps);
  const float i11 = g1[m1] / sqrtf(stats[64 + m1] * (1.0f / 65536.0f) + kEps);
  const float* yr = y + (size_t)r * 256 + d8 * 8;
  const float4 ya = *(const float4*)yr;
  const float4 yb = *(const float4*)(yr + 4);
  float a[8];
  {
    const float s = ya.x * i00;
    const float vx = ya.y * i10, vy = ya.z * i10, vz = ya.w * i10;
    const float so = s * sigmoidf(fabsf(s));
    const float vn = sqrtf(fmaf(vx, vx, fmaf(vy, vy, vz * vz)) + kEps);
    const float gv = sigmoidf(vn);
    a[0] = so; a[1] = vx * gv; a[2] = vy * gv; a[3] = vz * gv;
  }
  {
    const float s = yb.x * i01;
    const float vx = yb.y * i11, vy = yb.z * i11, vz = yb.w * i11;
    const float so = s * sigmoidf(fabsf(s));
    const float vn = sqrtf(fmaf(vx, vx, fmaf(vy, vy, vz * vz)) + kEps);
    const float gv = sigmoidf(vn);
    a[4] = so; a[5] = vx * gv; a[6] = vy * gv; a[7] = vz * gv;
  }
  const size_t base = hidx(r, d8);
  U4 hi, lo;
  hi.u = *(const uint4*)(hsh + base);
  lo.u = *(const uint4*)(hsh + base + 512);
  U4 oh, ol;
#pragma unroll
  for (int i = 0; i < 8; ++i) {
    const float f = (float)hi.b[i] + (float)lo.b[i] + a[i];
    const bf16_t h_ = (bf16_t)f;
    oh.b[i] = h_; ol.b[i] = (bf16_t)(f - (float)h_);
  }
  *(uint4*)(hsh + base) = oh.u;
  *(uint4*)(hsh + base + 512) = ol.u;
}

// ---------------------------------------------------------------- mean-pool + einsum
__global__ __launch_bounds__(256) void k_pool(const bf16_t* __restrict__ hsh,
    const float* __restrict__ w_out, float* __restrict__ out) {
  __shared__ float r0s[256], r1s[256], r2s[256];
  const int b = blockIdx.x;
  const int t = threadIdx.x;
  float p0 = 0, p1 = 0, p2 = 0;
  for (int idx = t; idx < kN * 32; idx += 256) {
    const int n = idx >> 5, d8 = idx & 31;
    const int r = (b << 10) + n;
    const size_t base = hidx(r, d8);
    U4 hi, lo;
    hi.u = *(const uint4*)(hsh + base);
    lo.u = *(const uint4*)(hsh + base + 512);
    const float w0 = w_out[d8 * 2], w1 = w_out[d8 * 2 + 1];
    p0 += ((float)hi.b[1] + (float)lo.b[1]) * w0 + ((float)hi.b[5] + (float)lo.b[5]) * w1;
    p1 += ((float)hi.b[2] + (float)lo.b[2]) * w0 + ((float)hi.b[6] + (float)lo.b[6]) * w1;
    p2 += ((float)hi.b[3] + (float)lo.b[3]) * w0 + ((float)hi.b[7] + (float)lo.b[7]) * w1;
  }
  r0s[t] = p0; r1s[t] = p1; r2s[t] = p2;
  __syncthreads();
  for (int s = 128; s > 0; s >>= 1) {
    if (t < s) { r0s[t] += r0s[t + s]; r1s[t] += r1s[t + s]; r2s[t] += r2s[t + s]; }
    __syncthreads();
  }
  if (t == 0) {
    out[b * 3 + 0] = r0s[0] * (1.0f / kN);
    out[b * 3 + 1] = r1s[0] * (1.0f / kN);
    out[b * 3 + 2] = r2s[0] * (1.0f / kN);
  }
}

} // namespace

extern "C" void kernel_launch(void* const* d_in, const int* in_sizes, int n_in,
                              void* d_out, int out_size, void* d_ws, size_t ws_size,
                              hipStream_t stream) {
  const float* x       = (const float*)d_in[0];
  const float* tok_emb = (const float*)d_in[1];
  const float* Wf      = (const float*)d_in[2];
  const float* wv      = (const float*)d_in[3];
  const float* w_out   = (const float*)d_in[4];

  float* ws    = (float*)d_ws;
  bf16_t* hsh  = (bf16_t*)ws;                          // 33,554,432 bf16 = 16,777,216 fl
  float*  kvt  = ws + 16777216;                        // 23,592,960 fl
  float*  qt   = kvt + 23592960;                       // 23,592,960 fl
  float*  y    = qt;                                   // alias: qt dead once k_mix done
  float*  partial = qt + 20000000;                     // 262,144 fl inside qt region, past y end
  float*  s0   = qt + 23592960;                        //     65,536 fl
  float*  kf   = s0 + 65536;                           //    737,280 fl
  bf16_t* wall3 = (bf16_t*)(kf + 737280);              // 1,474,560 bf16 (l0:589824, l1:589824, l2:294912)
  bf16_t* WoF3  = wall3 + 1474560;                     // 3 x 196,608 bf16
  bf16_t* BtF3  = WoF3 + 589824;                       // 3 x 131,072 bf16
  float* stats = (float*)(BtF3 + 393216);              // 384 fl
  float* twg   = stats + 384;                          // 1,024 fl (512 float2)

  k_tw<<<2, 256, 0, stream>>>((float2*)twg);
  k_s0<<<kN, 64, 0, stream>>>(tok_emb, Wf, s0);
  k_h0<<<8192, 256, 0, stream>>>(x, wv, s0, hsh);
  k_wqkv3<<<dim3(384, 3), 256, 0, stream>>>(
      (const float*)d_in[5], (const float*)d_in[6], (const float*)d_in[7],
      (const float*)d_in[14], (const float*)d_in[15], (const float*)d_in[16],
      (const float*)d_in[23], (const float*)d_in[24], (const float*)d_in[25], wall3);
  k_wo3<<<dim3(256, 3), 384, 0, stream>>>(
      (const float*)d_in[9], (const float*)d_in[18], (const float*)d_in[27], WoF3);
  k_bt3<<<dim3(256, 3), 256, 0, stream>>>(
      (const float*)d_in[10], (const float*)d_in[11],
      (const float*)d_in[19], (const float*)d_in[20],
      (const float*)d_in[28], (const float*)d_in[29], BtF3);

  for (int l = 0; l < 3; ++l) {
    const float* filt = (const float*)d_in[5 + 9 * l + 3];
    const float* g0   = (const float*)d_in[5 + 9 * l + 7];
    const float* g1   = (const float*)d_in[5 + 9 * l + 8];
    const int H = (l == 2) ? 160 : 360;
    const int gy = (H + 63) / 64;                      // 6 or 3
    const int KT = gy * 2;                             // K chunks of 32 (zero-padded weights)
    bf16_t* wall = wall3 + ((l == 2) ? 1179648 : (size_t)l * 589824);
    bf16_t* WoF  = WoF3 + (size_t)l * 196608;
    bf16_t* BtF  = BtF3 + (size_t)l * 131072;
    float* st = stats + l * 128;

    k_kf<<<H, 256, 0, stream>>>(filt, H, (const float2*)twg, (float2*)kf);
    k_qkv<<<dim3(gy, 1024), 256, 0, stream>>>(hsh, wall, H, qt, kvt);
    k_conv<<<32 * H, 256, 0, stream>>>(kvt, (const float2*)kf, (const float2*)twg, H);
    k_mix<<<dim3(4, 1024), 256, 0, stream>>>(qt, kvt, H, KT, WoF, hsh);
    k_reg<<<dim3(4, 1024), 256, 0, stream>>>(hsh, BtF, y, partial);
    k_stat<<<1, 1024, 0, stream>>>(partial, st);
    k_bnact<<<8192, 256, 0, stream>>>(y, st, g0, g1, hsh);
  }

  k_pool<<<64, 256, 0, stream>>>(hsh, w_out, (float*)d_out);
}

// Round 10
// 1362.470 us; speedup vs baseline: 1.9386x; 1.1710x over previous
//
#include <hip/hip_runtime.h>
#include <math.h>

namespace {

typedef __bf16 bf16_t;
typedef bf16_t bf16x8 __attribute__((ext_vector_type(8)));
typedef float floatx4 __attribute__((ext_vector_type(4)));

constexpr int kN = 1024;      // tokens
constexpr int kM = 64;        // multiplicity
constexpr int kP = 64;        // PE dim
constexpr float kEps = 1e-5f;
constexpr int kFN = 1024;     // FFT length

__device__ __forceinline__ float sigmoidf(float v) { return 1.0f / (1.0f + expf(-v)); }

__device__ __forceinline__ floatx4 mfma16(bf16x8 a, bf16x8 b, floatx4 c) {
  return __builtin_amdgcn_mfma_f32_16x16x32_bf16(a, b, c, 0, 0, 0);
}

// 3-term split product: acc += (ah+al)*(bh+bl) dropping al*bl
__device__ __forceinline__ void fma3(floatx4& acc, bf16x8 ah, bf16x8 al,
                                     bf16x8 bh, bf16x8 bl) {
  acc = mfma16(ah, bh, acc);
  acc = mfma16(ah, bl, acc);
  acc = mfma16(al, bh, acc);
}

// load 8 contiguous fp32 (LDS), split into hi/lo bf16 fragments
__device__ __forceinline__ void load_split8(const float* p, bf16x8& hi, bf16x8& lo) {
  const float4 u = *(const float4*)p;
  const float4 v = *(const float4*)(p + 4);
  const float a[8] = {u.x, u.y, u.z, u.w, v.x, v.y, v.z, v.w};
#pragma unroll
  for (int i = 0; i < 8; ++i) {
    const bf16_t h_ = (bf16_t)a[i];
    hi[i] = h_;
    lo[i] = (bf16_t)(a[i] - (float)h_);
  }
}

union U4 { uint4 u; bf16_t b[8]; };

// async 16B/lane global->LDS DMA (wave-uniform LDS base + lane*16 scatter)
__device__ __forceinline__ void glds16(const bf16_t* g, bf16_t* l) {
  __builtin_amdgcn_global_load_lds(
      (const __attribute__((address_space(1))) void*)g,
      (__attribute__((address_space(3))) void*)l, 16, 0, 0);
}

// hsh fragment-major index for (row r, 8-elem group d8), hi plane (lo = +512)
// layout: [rb(1024)][kc(8)][rgrp(4)][p(2)][quad(4)][rl(16)][off(8)]
__device__ __forceinline__ size_t hidx(int r, int d8) {
  const int rb = r >> 6, rr = r & 63;
  return (size_t)(rb * 8 + (d8 >> 2)) * 4096 + (rr >> 4) * 1024 + (d8 & 3) * 128 + (rr & 15) * 8;
}

// padded LDS index for FFT work array (breaks small-span bank conflicts)
__device__ __forceinline__ int zi(int i) { return i + (i >> 4); }

__device__ __forceinline__ float2 cadd(float2 a, float2 b) { return {a.x + b.x, a.y + b.y}; }
__device__ __forceinline__ float2 csub(float2 a, float2 b) { return {a.x - b.x, a.y - b.y}; }
__device__ __forceinline__ float2 cmul(float2 a, float2 w) {
  return {a.x * w.x - a.y * w.y, a.x * w.y + a.y * w.x};
}
__device__ __forceinline__ float2 cmulc(float2 a, float2 w) {   // a * conj(w)
  return {a.x * w.x + a.y * w.y, a.y * w.x - a.x * w.y};
}

// ---------------------------------------------------------------- init
// s0[n, m] = sum_p (pe[n,p] + tok_emb[tt[n],p]) * Wf[p,m]
__global__ void k_s0(const float* __restrict__ tok_emb, const float* __restrict__ Wf,
                     float* __restrict__ s0) {
  __shared__ float f[kP];
  const int n = blockIdx.x;
  const int t = threadIdx.x;                       // 64 threads
  const int tt = (n == kN - 1) ? 2 : (n & 1);
  const int j = t >> 1;
  const float cexp = (float)(-9.210340371976184 / 64.0);   // -ln(10000)/P
  const float divj = expf((float)(2 * j) * cexp);
  const float ang = (float)n * divj;
  const float pe = (t & 1) ? cosf(ang) : sinf(ang);
  f[t] = pe + tok_emb[tt * kP + t];
  __syncthreads();
  float acc = 0.0f;
#pragma unroll 8
  for (int p = 0; p < kP; ++p) acc = fmaf(f[p], Wf[p * kM + t], acc);
  s0[n * kM + t] = acc;
}

// h planes (fragment-major): irreps m0=d8*2, m1=m0+1 per thread
__global__ void k_h0(const float* __restrict__ x, const float* __restrict__ wv,
                     const float* __restrict__ s0, bf16_t* __restrict__ hsh) {
  const int idx = blockIdx.x * 256 + threadIdx.x;  // r*32 + d8
  const int r = idx >> 5, d8 = idx & 31;
  const int n = r & (kN - 1);
  const int m0 = d8 * 2, m1 = m0 + 1;
  const float w0 = wv[m0], w1 = wv[m1];
  const float x0 = x[r * 3 + 0], x1 = x[r * 3 + 1], x2 = x[r * 3 + 2];
  float f[8];
  f[0] = s0[n * kM + m0]; f[1] = x0 * w0; f[2] = x1 * w0; f[3] = x2 * w0;
  f[4] = s0[n * kM + m1]; f[5] = x0 * w1; f[6] = x1 * w1; f[7] = x2 * w1;
  U4 oh, ol;
#pragma unroll
  for (int i = 0; i < 8; ++i) {
    const bf16_t h_ = (bf16_t)f[i];
    oh.b[i] = h_; ol.b[i] = (bf16_t)(f[i] - (float)h_);
  }
  const size_t base = hidx(r, d8);
  *(uint4*)(hsh + base) = oh.u;
  *(uint4*)(hsh + base + 512) = ol.u;
}

// ---------------------------------------------------------------- weight prep (batched, all 3 layers)
// wall per (ct,kc): [mat(3)][p(2)][cgrp(4)][quad(4)][cl(16)][off(8)] = 12288 elems
__global__ void k_wqkv3(const float* __restrict__ Wq0, const float* __restrict__ Wk0,
                        const float* __restrict__ Wv0,
                        const float* __restrict__ Wq1, const float* __restrict__ Wk1,
                        const float* __restrict__ Wv1,
                        const float* __restrict__ Wq2, const float* __restrict__ Wk2,
                        const float* __restrict__ Wv2, bf16_t* __restrict__ wall3) {
  const int l = blockIdx.y;
  const int H = (l == 2) ? 160 : 360;
  const int gy = (l == 2) ? 3 : 6;
  const int c = blockIdx.x;    // 0..383
  if (c >= gy * 64) return;
  const int k = threadIdx.x;   // 0..255
  const float* Wq = (l == 0) ? Wq0 : ((l == 1) ? Wq1 : Wq2);
  const float* Wk = (l == 0) ? Wk0 : ((l == 1) ? Wk1 : Wk2);
  const float* Wv = (l == 0) ? Wv0 : ((l == 1) ? Wv1 : Wv2);
  bf16_t* wall = wall3 + ((l == 2) ? 1179648 : (size_t)l * 589824);
  const bool ok = c < H;
  const float w[3] = {ok ? Wq[k * H + c] : 0.f, ok ? Wk[k * H + c] : 0.f,
                      ok ? Wv[k * H + c] : 0.f};
  const int ct = c >> 6, cgrp = (c >> 4) & 3, cl = c & 15;
  const int kc = k >> 5, quad = (k >> 3) & 3, off = k & 7;
  const size_t base = (size_t)(ct * 8 + kc) * 12288 + cgrp * 512 + quad * 128 + cl * 8 + off;
#pragma unroll
  for (int mat = 0; mat < 3; ++mat) {
    const bf16_t hi = (bf16_t)w[mat];
    wall[base + mat * 4096] = hi;
    wall[base + mat * 4096 + 2048] = (bf16_t)(w[mat] - (float)hi);
  }
}

// WoF per (dt,kc of 12): [p(2)][dgrp(4)][quad(4)][dl(16)][off(8)] = 4096 elems
__global__ void k_wo3(const float* __restrict__ Wo0, const float* __restrict__ Wo1,
                      const float* __restrict__ Wo2, bf16_t* __restrict__ WoF3) {
  const int l = blockIdx.y;
  const int H = (l == 2) ? 160 : 360;
  const float* Wo = (l == 0) ? Wo0 : ((l == 1) ? Wo1 : Wo2);
  bf16_t* WoF = WoF3 + (size_t)l * 196608;
  const int d = blockIdx.x;    // 0..255
  const int c = threadIdx.x;   // 0..383
  const float w = (c < H) ? Wo[c * 256 + d] : 0.f;
  const int dt = d >> 6, dgrp = (d >> 4) & 3, dl = d & 15;
  const int kc = c >> 5, quad = (c >> 3) & 3, off = c & 7;
  const size_t base = (size_t)(dt * 12 + kc) * 4096 + dgrp * 512 + quad * 128 + dl * 8 + off;
  const bf16_t hi = (bf16_t)w;
  WoF[base] = hi;
  WoF[base + 2048] = (bf16_t)(w - (float)hi);
}

// BtF per (ct,kc of 8): [p(2)][cgrp(4)][quad(4)][cl(16)][off(8)] = 4096 elems
__global__ void k_bt3(const float* __restrict__ W00, const float* __restrict__ W10,
                      const float* __restrict__ W01, const float* __restrict__ W11,
                      const float* __restrict__ W02, const float* __restrict__ W12,
                      bf16_t* __restrict__ BtF3) {
  const int l = blockIdx.y;
  const float* W0 = (l == 0) ? W00 : ((l == 1) ? W01 : W02);
  const float* W1 = (l == 0) ? W10 : ((l == 1) ? W11 : W12);
  bf16_t* BtF = BtF3 + (size_t)l * 131072;
  const int col = blockIdx.x, row = threadIdx.x;
  const int k = col >> 2, ck = col & 3, m = row >> 2, cm = row & 3;
  float v = 0.f;
  if (cm == ck) v = (ck == 0 ? W0 : W1)[m * 64 + k];
  const int ct = col >> 6, cgrp = (col >> 4) & 3, cl = col & 15;
  const int kc = row >> 5, quad = (row >> 3) & 3, off = row & 7;
  const size_t base = (size_t)(ct * 8 + kc) * 4096 + cgrp * 512 + quad * 128 + cl * 8 + off;
  const bf16_t hi = (bf16_t)v;
  BtF[base] = hi;
  BtF[base + 2048] = (bf16_t)(v - (float)hi);
}

// ---------------------------------------------------------------- FFT (fused radix-2 pairs)
// twiddle table -> global (once per launch)
__global__ void k_tw(float2* __restrict__ twg) {
  const int j = blockIdx.x * 256 + threadIdx.x;
  if (j < kFN / 2) {
    float s, c;
    sincosf(-6.283185307179586f * (float)j / (float)kFN, &s, &c);
    twg[j].x = c; twg[j].y = s;
  }
}

// forward DIF, two radix-2 stages fused per barrier: natural in -> bit-reversed out
__device__ void fft_dif(float2* z, const float2* tw) {
  const int p = threadIdx.x;
#pragma unroll
  for (int m = 256; m >= 1; m >>= 2) {     // fused spans (2m, m): (512,256)...(2,1)
    __syncthreads();
    const int pm = p & (m - 1);
    const int j = ((p & ~(m - 1)) << 2) | pm;
    const int tm2 = 512 / (2 * m), tm1 = 512 / m;
    const float2 x0 = z[zi(j)], x1 = z[zi(j + m)];
    const float2 x2 = z[zi(j + 2 * m)], x3 = z[zi(j + 3 * m)];
    const float2 w2 = tw[pm * tm2], w2b = tw[(pm + m) * tm2], w1 = tw[pm * tm1];
    const float2 a0 = cadd(x0, x2), a2 = cmul(csub(x0, x2), w2);
    const float2 a1 = cadd(x1, x3), a3 = cmul(csub(x1, x3), w2b);
    z[zi(j)]         = cadd(a0, a1);
    z[zi(j + m)]     = cmul(csub(a0, a1), w1);
    z[zi(j + 2 * m)] = cadd(a2, a3);
    z[zi(j + 3 * m)] = cmul(csub(a2, a3), w1);
  }
}

// inverse DIT, fused: bit-reversed in -> natural out (caller scales by 1/N)
__device__ void fft_dit_inv(float2* z, const float2* tw) {
  const int p = threadIdx.x;
#pragma unroll
  for (int m = 1; m <= 256; m <<= 2) {     // fused spans (m, 2m): (1,2)...(256,512)
    __syncthreads();
    const int pm = p & (m - 1);
    const int j = ((p & ~(m - 1)) << 2) | pm;
    const int tm2 = 512 / (2 * m), tm1 = 512 / m;
    const float2 x0 = z[zi(j)], x1 = z[zi(j + m)];
    const float2 x2 = z[zi(j + 2 * m)], x3 = z[zi(j + 3 * m)];
    const float2 w1 = tw[pm * tm1], w2 = tw[pm * tm2], w2b = tw[(pm + m) * tm2];
    const float2 c1 = cmulc(x1, w1), c3 = cmulc(x3, w1);
    const float2 b0 = cadd(x0, c1), b1 = csub(x0, c1);
    const float2 b2 = cadd(x2, c3), b3 = csub(x2, c3);
    const float2 d2 = cmulc(b2, w2), d3 = cmulc(b3, w2b);
    z[zi(j)]         = cadd(b0, d2);
    z[zi(j + 2 * m)] = csub(b0, d2);
    z[zi(j + m)]     = cadd(b1, d3);
    z[zi(j + 3 * m)] = csub(b1, d3);
  }
}

// filter spectrum, stored in DIF (bit-reversed) order; one block per channel
__global__ __launch_bounds__(256) void k_kf(const float* __restrict__ filt, int H,
                                            const float2* __restrict__ twg,
                                            float2* __restrict__ kf) {
  __shared__ float2 z[kFN + kFN / 16];
  __shared__ float2 tw[kFN / 2];
  const int c = blockIdx.x;
  for (int j = threadIdx.x; j < kFN / 2; j += 256) tw[j] = twg[j];
  for (int n = threadIdx.x; n < kFN; n += 256) {
    z[zi(n)].x = filt[n * H + c];
    z[zi(n)].y = 0.0f;
  }
  fft_dif(z, tw);
  __syncthreads();
  for (int j = threadIdx.x; j < kFN; j += 256) kf[c * kFN + j] = z[zi(j)];
}

// packed circular conv: two batch rows (same channel) per complex FFT
__global__ __launch_bounds__(256) void k_conv(float* kvt, const float2* __restrict__ kf,
                                              const float2* __restrict__ twg, int H) {
  __shared__ float2 z[kFN + kFN / 16];
  __shared__ float2 tw[kFN / 2];
  const int blk = blockIdx.x;              // pb*H + c
  const int c = blk % H;
  const int pb = blk / H;
  float* sig0 = kvt + (((size_t)((2 * pb) * H + c)) << 10);
  float* sig1 = kvt + (((size_t)((2 * pb + 1) * H + c)) << 10);
  for (int j = threadIdx.x; j < kFN / 2; j += 256) tw[j] = twg[j];
  for (int n = threadIdx.x; n < kFN; n += 256) {
    z[zi(n)].x = sig0[n];
    z[zi(n)].y = sig1[n];
  }
  fft_dif(z, tw);
  __syncthreads();
  for (int j = threadIdx.x; j < kFN; j += 256) {
    const float2 a = z[zi(j)];
    const float2 b = kf[c * kFN + j];
    float2 o;
    o.x = a.x * b.x - a.y * b.y;
    o.y = a.x * b.y + a.y * b.x;
    z[zi(j)] = o;
  }
  fft_dit_inv(z, tw);
  __syncthreads();
  const float s = 1.0f / (float)kFN;
  for (int n = threadIdx.x; n < kFN; n += 256) {
    sig0[n] = z[zi(n)].x * s;
    sig1[n] = z[zi(n)].y * s;
  }
}

// ---------------------------------------------------------------- GEMM 1 (split MFMA, LDS-DMA): q/k/v
// XCD-swizzled 1D grid: same-rb blocks run consecutively on one XCD (A-chunk L2 reuse)
__global__ __launch_bounds__(256) void k_qkv(const bf16_t* __restrict__ hsh,
    const bf16_t* __restrict__ wall, int H,
    float* __restrict__ qt, float* __restrict__ kvt) {
  __shared__ bf16_t lds[16384];            // 32 KB: A 8KB (segs 0-7) + B 24KB (segs 8-31)
  const int gy = (H + 63) >> 6;
  const int bid = blockIdx.x;
  const int xcd = bid & 7, sseq = bid >> 3;
  const int ct = sseq % gy;
  const int rb = (sseq / gy) * 8 + xcd;
  const int t = threadIdx.x;
  const int lane = t & 63, wave = t >> 6;
  const int l15 = lane & 15, quad = lane >> 4;
  const int r0 = rb * 64, c0 = ct * 64;
  const int wr = (wave & 1) * 32, wc = (wave >> 1) * 32;
  const int wr16 = (wave & 1) * 2, wc16 = (wave >> 1) * 2;
  const int q128l = quad * 128 + l15 * 8;
  floatx4 aq[2][2] = {}, ak_[2][2] = {}, av_[2][2] = {};
  for (int kt = 0; kt < 8; ++kt) {
    {
      const bf16_t* Asrc = hsh + (size_t)(rb * 8 + kt) * 4096;
      const bf16_t* Bsrc = wall + (size_t)(ct * 8 + kt) * 12288 - 8 * 512;
#pragma unroll
      for (int s = 0; s < 8; ++s) {
        const int seg = wave * 8 + s;
        const bf16_t* src = (wave == 0) ? (Asrc + seg * 512 + lane * 8)
                                        : (Bsrc + seg * 512 + lane * 8);
        glds16(src, &lds[seg * 512]);
      }
    }
    __syncthreads();
    const bf16x8 a0h = *(const bf16x8*)(lds + ((wr16 + 0) * 2 + 0) * 512 + q128l);
    const bf16x8 a0l = *(const bf16x8*)(lds + ((wr16 + 0) * 2 + 1) * 512 + q128l);
    const bf16x8 a1h = *(const bf16x8*)(lds + ((wr16 + 1) * 2 + 0) * 512 + q128l);
    const bf16x8 a1l = *(const bf16x8*)(lds + ((wr16 + 1) * 2 + 1) * 512 + q128l);
    {
      const int bb = 4096;                 // mat 0 (q)
      const bf16x8 bh0 = *(const bf16x8*)(lds + bb + (wc16 + 0) * 512 + q128l);
      const bf16x8 bl0 = *(const bf16x8*)(lds + bb + 2048 + (wc16 + 0) * 512 + q128l);
      const bf16x8 bh1 = *(const bf16x8*)(lds + bb + (wc16 + 1) * 512 + q128l);
      const bf16x8 bl1 = *(const bf16x8*)(lds + bb + 2048 + (wc16 + 1) * 512 + q128l);
      fma3(aq[0][0], a0h, a0l, bh0, bl0); fma3(aq[0][1], a0h, a0l, bh1, bl1);
      fma3(aq[1][0], a1h, a1l, bh0, bl0); fma3(aq[1][1], a1h, a1l, bh1, bl1);
    }
    {
      const int bb = 4096 + 4096;          // mat 1 (k)
      const bf16x8 bh0 = *(const bf16x8*)(lds + bb + (wc16 + 0) * 512 + q128l);
      const bf16x8 bl0 = *(const bf16x8*)(lds + bb + 2048 + (wc16 + 0) * 512 + q128l);
      const bf16x8 bh1 = *(const bf16x8*)(lds + bb + (wc16 + 1) * 512 + q128l);
      const bf16x8 bl1 = *(const bf16x8*)(lds + bb + 2048 + (wc16 + 1) * 512 + q128l);
      fma3(ak_[0][0], a0h, a0l, bh0, bl0); fma3(ak_[0][1], a0h, a0l, bh1, bl1);
      fma3(ak_[1][0], a1h, a1l, bh0, bl0); fma3(ak_[1][1], a1h, a1l, bh1, bl1);
    }
    {
      const int bb = 4096 + 8192;          // mat 2 (v)
      const bf16x8 bh0 = *(const bf16x8*)(lds + bb + (wc16 + 0) * 512 + q128l);
      const bf16x8 bl0 = *(const bf16x8*)(lds + bb + 2048 + (wc16 + 0) * 512 + q128l);
      const bf16x8 bh1 = *(const bf16x8*)(lds + bb + (wc16 + 1) * 512 + q128l);
      const bf16x8 bl1 = *(const bf16x8*)(lds + bb + 2048 + (wc16 + 1) * 512 + q128l);
      fma3(av_[0][0], a0h, a0l, bh0, bl0); fma3(av_[0][1], a0h, a0l, bh1, bl1);
      fma3(av_[1][0], a1h, a1l, bh0, bl0); fma3(av_[1][1], a1h, a1l, bh1, bl1);
    }
    __syncthreads();
  }
  const int b = r0 >> 10;
  const int n0 = r0 & 1023;
#pragma unroll
  for (int j = 0; j < 2; ++j) {
    const int c = c0 + wc + j * 16 + l15;
    if (c < H) {
      const size_t rbw = (((size_t)(b * H + c)) << 10) + n0 + wr + quad * 4;
#pragma unroll
      for (int i = 0; i < 2; ++i) {
        float4 p;
        p.x = aq[i][j][0]; p.y = aq[i][j][1];
        p.z = aq[i][j][2]; p.w = aq[i][j][3];
        *(float4*)(qt + rbw + i * 16) = p;
      }
#pragma unroll
      for (int i = 0; i < 2; ++i) {
        float4 p;
        p.x = ak_[i][j][0] * av_[i][j][0];
        p.y = ak_[i][j][1] * av_[i][j][1];
        p.z = ak_[i][j][2] * av_[i][j][2];
        p.w = ak_[i][j][3] * av_[i][j][3];
        *(float4*)(kvt + rbw + i * 16) = p;
      }
    }
  }
}

// ---------------------------------------------------------------- GEMM 2 (split MFMA): h += (q*conv) @ Wo
// XCD-swizzled: the 4 dt-blocks sharing one r0's qt/kvt strips run on one XCD
__global__ __launch_bounds__(256) void k_mix(const float* __restrict__ qt,
    const float* __restrict__ kvt, int H, int KT,
    const bf16_t* __restrict__ WoF, bf16_t* __restrict__ hsh) {
  __shared__ float smem[4352];             // As: 64 n x 36 ; epilogue: 64 x 68
  const int bid = blockIdx.x;
  const int xcd = bid & 7, sseq = bid >> 3;
  const int dt = sseq & 3;
  const int r0 = ((sseq >> 2) * 8 + xcd) * 64;
  const int t = threadIdx.x;
  const int lane = t & 63, wave = t >> 6;
  const int l15 = lane & 15, quad = lane >> 4;
  const int b = r0 >> 10, n0 = r0 & 1023;
  const int wr = (wave & 1) * 32, wc16 = (wave >> 1) * 2;
  const int q128l = quad * 128 + l15 * 8;
  floatx4 acc[2][2] = {};
  const int cl = t >> 3, n8 = (t & 7) * 8;
  for (int kt = 0; kt < KT; ++kt) {
    const int ck0 = kt * 32;
    __syncthreads();
    {
      const int c = ck0 + cl;
      float p[8] = {};
      if (c < H) {
        const size_t o = (((size_t)(b * H + c)) << 10) + n0 + n8;
        const float4 q0 = *(const float4*)(qt + o);
        const float4 q1 = *(const float4*)(qt + o + 4);
        const float4 v0 = *(const float4*)(kvt + o);
        const float4 v1 = *(const float4*)(kvt + o + 4);
        p[0] = q0.x * v0.x; p[1] = q0.y * v0.y; p[2] = q0.z * v0.z; p[3] = q0.w * v0.w;
        p[4] = q1.x * v1.x; p[5] = q1.y * v1.y; p[6] = q1.z * v1.z; p[7] = q1.w * v1.w;
      }
#pragma unroll
      for (int u = 0; u < 8; ++u) smem[(n8 + u) * 36 + cl] = p[u];
    }
    __syncthreads();
    bf16x8 ah0, al0, ah1, al1;
    load_split8(smem + (wr + l15) * 36 + quad * 8, ah0, al0);
    load_split8(smem + (wr + 16 + l15) * 36 + quad * 8, ah1, al1);
    const bf16_t* Bb = WoF + (size_t)(dt * 12 + kt) * 4096;
    const bf16x8 bh0 = *(const bf16x8*)(Bb + (wc16 + 0) * 512 + q128l);
    const bf16x8 bl0 = *(const bf16x8*)(Bb + 2048 + (wc16 + 0) * 512 + q128l);
    const bf16x8 bh1 = *(const bf16x8*)(Bb + (wc16 + 1) * 512 + q128l);
    const bf16x8 bl1 = *(const bf16x8*)(Bb + 2048 + (wc16 + 1) * 512 + q128l);
    fma3(acc[0][0], ah0, al0, bh0, bl0); fma3(acc[0][1], ah0, al0, bh1, bl1);
    fma3(acc[1][0], ah1, al1, bh0, bl0); fma3(acc[1][1], ah1, al1, bh1, bl1);
  }
  __syncthreads();
#pragma unroll
  for (int i = 0; i < 2; ++i)
#pragma unroll
    for (int j = 0; j < 2; ++j)
#pragma unroll
      for (int r = 0; r < 4; ++r)
        smem[(wr + i * 16 + quad * 4 + r) * 68 + (wave >> 1) * 32 + j * 16 + l15] = acc[i][j][r];
  __syncthreads();
  const int nl = t >> 2, q4 = t & 3;
  const int r = r0 + nl;
#pragma unroll
  for (int u8 = 0; u8 < 2; ++u8) {
    const int d8 = dt * 8 + q4 * 2 + u8;
    const size_t base = hidx(r, d8);
    U4 hi, lo;
    hi.u = *(const uint4*)(hsh + base);
    lo.u = *(const uint4*)(hsh + base + 512);
    U4 oh, ol;
#pragma unroll
    for (int i = 0; i < 8; ++i) {
      const float f = (float)hi.b[i] + (float)lo.b[i] + smem[nl * 68 + q4 * 16 + u8 * 8 + i];
      const bf16_t h_ = (bf16_t)f;
      oh.b[i] = h_; ol.b[i] = (bf16_t)(f - (float)h_);
    }
    *(uint4*)(hsh + base) = oh.u;
    *(uint4*)(hsh + base + 512) = ol.u;
  }
}

// ---------------------------------------------------------------- GEMM 3 (split MFMA, LDS-DMA): reg_linear + BN partials
// XCD-swizzled: 4 ct-blocks of one rb co-located per XCD
__global__ __launch_bounds__(256) void k_reg(const bf16_t* __restrict__ hsh,
    const bf16_t* __restrict__ BtF,
    float* __restrict__ y, float* __restrict__ partial) {
  __shared__ float smf[64 * 68];           // epilogue buffer; aliased as 16KB DMA staging
  __shared__ float red[128];
  bf16_t* lds = (bf16_t*)smf;
  const int bid = blockIdx.x;
  const int xcd = bid & 7, sseq = bid >> 3;
  const int ct = sseq & 3;
  const int rb = (sseq >> 2) * 8 + xcd;
  const int t = threadIdx.x;
  const int lane = t & 63, wave = t >> 6;
  const int l15 = lane & 15, quad = lane >> 4;
  const int c0 = ct * 64, r0 = rb * 64;
  const int wr = (wave & 1) * 32, wc = (wave >> 1) * 32;
  const int wr16 = (wave & 1) * 2, wc16 = (wave >> 1) * 2;
  const int q128l = quad * 128 + l15 * 8;
  floatx4 acc[2][2] = {};
  for (int kt = 0; kt < 8; ++kt) {
    {
      const bf16_t* Asrc = hsh + (size_t)(rb * 8 + kt) * 4096;
      const bf16_t* Bsrc = BtF + (size_t)(ct * 8 + kt) * 4096 - 8 * 512;
#pragma unroll
      for (int s = 0; s < 4; ++s) {
        const int seg = wave * 4 + s;
        const bf16_t* src = (seg < 8) ? (Asrc + seg * 512 + lane * 8)
                                      : (Bsrc + seg * 512 + lane * 8);
        glds16(src, &lds[seg * 512]);
      }
    }
    __syncthreads();
    const bf16x8 a0h = *(const bf16x8*)(lds + ((wr16 + 0) * 2 + 0) * 512 + q128l);
    const bf16x8 a0l = *(const bf16x8*)(lds + ((wr16 + 0) * 2 + 1) * 512 + q128l);
    const bf16x8 a1h = *(const bf16x8*)(lds + ((wr16 + 1) * 2 + 0) * 512 + q128l);
    const bf16x8 a1l = *(const bf16x8*)(lds + ((wr16 + 1) * 2 + 1) * 512 + q128l);
    const bf16x8 bh0 = *(const bf16x8*)(lds + 4096 + (wc16 + 0) * 512 + q128l);
    const bf16x8 bl0 = *(const bf16x8*)(lds + 4096 + 2048 + (wc16 + 0) * 512 + q128l);
    const bf16x8 bh1 = *(const bf16x8*)(lds + 4096 + (wc16 + 1) * 512 + q128l);
    const bf16x8 bl1 = *(const bf16x8*)(lds + 4096 + 2048 + (wc16 + 1) * 512 + q128l);
    fma3(acc[0][0], a0h, a0l, bh0, bl0); fma3(acc[0][1], a0h, a0l, bh1, bl1);
    fma3(acc[1][0], a1h, a1l, bh0, bl0); fma3(acc[1][1], a1h, a1l, bh1, bl1);
    __syncthreads();
  }
#pragma unroll
  for (int j = 0; j < 2; ++j) {
    float s = 0.f;
#pragma unroll
    for (int i = 0; i < 2; ++i)
#pragma unroll
      for (int r = 0; r < 4; ++r)
        s = fmaf(acc[i][j][r], acc[i][j][r], s);
    s += __shfl_down(s, 32);
    s += __shfl_down(s, 16);
    if (lane < 16) red[wave * 32 + j * 16 + lane] = s;
  }
#pragma unroll
  for (int i = 0; i < 2; ++i)
#pragma unroll
    for (int j = 0; j < 2; ++j)
#pragma unroll
      for (int r = 0; r < 4; ++r)
        smf[(wr + i * 16 + quad * 4 + r) * 68 + wc + j * 16 + l15] = acc[i][j][r];
  __syncthreads();
  const int nl = t >> 2, q4 = t & 3;
  const size_t gi = (size_t)(r0 + nl) * 256 + c0 + q4 * 16;
#pragma unroll
  for (int u = 0; u < 4; ++u) {
    float4 yv;
    yv.x = smf[nl * 68 + q4 * 16 + u * 4 + 0];
    yv.y = smf[nl * 68 + q4 * 16 + u * 4 + 1];
    yv.z = smf[nl * 68 + q4 * 16 + u * 4 + 2];
    yv.w = smf[nl * 68 + q4 * 16 + u * 4 + 3];
    *(float4*)(y + gi + u * 4) = yv;
  }
  if (t < 64) {
    const int w0 = (t >= 32) ? 2 : 0;
    const float v = red[w0 * 32 + (t & 31)] + red[(w0 + 1) * 32 + (t & 31)];
    partial[(size_t)rb * 256 + c0 + t] = v;   // race-free: one slot per column
  }
}

// reduce partials over 1024 r-blocks -> stats[128]; 16 blocks, each owns 16 columns
__global__ __launch_bounds__(256) void k_stat(const float* __restrict__ partial,
                                              float* __restrict__ st) {
  __shared__ float sm1[16][16];
  __shared__ float tot[16];
  const int bb = blockIdx.x;               // 0..15
  const int t = threadIdx.x;
  const int col16 = t & 15, rgrp = t >> 4; // 16 cols x 16 row-groups
  const int c = bb * 16 + col16;
  float s = 0.f;
  for (int r = rgrp; r < 1024; r += 16) s += partial[(size_t)r * 256 + c];
  sm1[rgrp][col16] = s;
  __syncthreads();
  if (t < 16) {
    float v = 0.f;
#pragma unroll
    for (int g = 0; g < 16; ++g) v += sm1[g][t];
    tot[t] = v;
  }
  __syncthreads();
  if (t < 4) {
    const int m = bb * 4 + t;
    st[m] = tot[4 * t];
    st[64 + m] = tot[4 * t + 1] + tot[4 * t + 2] + tot[4 * t + 3];
  }
}

// ---------------------------------------------------------------- BN + norm-activation + residual
__global__ void k_bnact(const float* __restrict__ y, const float* __restrict__ stats,
    const float* __restrict__ g0, const float* __restrict__ g1, bf16_t* __restrict__ hsh) {
  const int idx = blockIdx.x * 256 + threadIdx.x;  // r*32 + d8
  const int r = idx >> 5, d8 = idx & 31;
  const int m0 = d8 * 2, m1 = m0 + 1;
  const float i00 = g0[m0] / sqrtf(stats[m0] * (1.0f / 65536.0f) + kEps);
  const float i10 = g1[m0] / sqrtf(stats[64 + m0] * (1.0f / 65536.0f) + kEps);
  const float i01 = g0[m1] / sqrtf(stats[m1] * (1.0f / 65536.0f) + kEps);
  const float i11 = g1[m1] / sqrtf(stats[64 + m1] * (1.0f / 65536.0f) + kEps);
  const float* yr = y + (size_t)r * 256 + d8 * 8;
  const float4 ya = *(const float4*)yr;
  const float4 yb = *(const float4*)(yr + 4);
  float a[8];
  {
    const float s = ya.x * i00;
    const float vx = ya.y * i10, vy = ya.z * i10, vz = ya.w * i10;
    const float so = s * sigmoidf(fabsf(s));
    const float vn = sqrtf(fmaf(vx, vx, fmaf(vy, vy, vz * vz)) + kEps);
    const float gv = sigmoidf(vn);
    a[0] = so; a[1] = vx * gv; a[2] = vy * gv; a[3] = vz * gv;
  }
  {
    const float s = yb.x * i01;
    const float vx = yb.y * i11, vy = yb.z * i11, vz = yb.w * i11;
    const float so = s * sigmoidf(fabsf(s));
    const float vn = sqrtf(fmaf(vx, vx, fmaf(vy, vy, vz * vz)) + kEps);
    const float gv = sigmoidf(vn);
    a[4] = so; a[5] = vx * gv; a[6] = vy * gv; a[7] = vz * gv;
  }
  const size_t base = hidx(r, d8);
  U4 hi, lo;
  hi.u = *(const uint4*)(hsh + base);
  lo.u = *(const uint4*)(hsh + base + 512);
  U4 oh, ol;
#pragma unroll
  for (int i = 0; i < 8; ++i) {
    const float f = (float)hi.b[i] + (float)lo.b[i] + a[i];
    const bf16_t h_ = (bf16_t)f;
    oh.b[i] = h_; ol.b[i] = (bf16_t)(f - (float)h_);
  }
  *(uint4*)(hsh + base) = oh.u;
  *(uint4*)(hsh + base + 512) = ol.u;
}

// ---------------------------------------------------------------- mean-pool + einsum
__global__ __launch_bounds__(256) void k_pool(const bf16_t* __restrict__ hsh,
    const float* __restrict__ w_out, float* __restrict__ out) {
  __shared__ float r0s[256], r1s[256], r2s[256];
  const int b = blockIdx.x;
  const int t = threadIdx.x;
  float p0 = 0, p1 = 0, p2 = 0;
  for (int idx = t; idx < kN * 32; idx += 256) {
    const int n = idx >> 5, d8 = idx & 31;
    const int r = (b << 10) + n;
    const size_t base = hidx(r, d8);
    U4 hi, lo;
    hi.u = *(const uint4*)(hsh + base);
    lo.u = *(const uint4*)(hsh + base + 512);
    const float w0 = w_out[d8 * 2], w1 = w_out[d8 * 2 + 1];
    p0 += ((float)hi.b[1] + (float)lo.b[1]) * w0 + ((float)hi.b[5] + (float)lo.b[5]) * w1;
    p1 += ((float)hi.b[2] + (float)lo.b[2]) * w0 + ((float)hi.b[6] + (float)lo.b[6]) * w1;
    p2 += ((float)hi.b[3] + (float)lo.b[3]) * w0 + ((float)hi.b[7] + (float)lo.b[7]) * w1;
  }
  r0s[t] = p0; r1s[t] = p1; r2s[t] = p2;
  __syncthreads();
  for (int s = 128; s > 0; s >>= 1) {
    if (t < s) { r0s[t] += r0s[t + s]; r1s[t] += r1s[t + s]; r2s[t] += r2s[t + s]; }
    __syncthreads();
  }
  if (t == 0) {
    out[b * 3 + 0] = r0s[0] * (1.0f / kN);
    out[b * 3 + 1] = r1s[0] * (1.0f / kN);
    out[b * 3 + 2] = r2s[0] * (1.0f / kN);
  }
}

} // namespace

extern "C" void kernel_launch(void* const* d_in, const int* in_sizes, int n_in,
                              void* d_out, int out_size, void* d_ws, size_t ws_size,
                              hipStream_t stream) {
  const float* x       = (const float*)d_in[0];
  const float* tok_emb = (const float*)d_in[1];
  const float* Wf      = (const float*)d_in[2];
  const float* wv      = (const float*)d_in[3];
  const float* w_out   = (const float*)d_in[4];

  float* ws    = (float*)d_ws;
  bf16_t* hsh  = (bf16_t*)ws;                          // 33,554,432 bf16 = 16,777,216 fl
  float*  kvt  = ws + 16777216;                        // 23,592,960 fl
  float*  qt   = kvt + 23592960;                       // 23,592,960 fl
  float*  y    = qt;                                   // alias: qt dead once k_mix done
  float*  partial = qt + 20000000;                     // 262,144 fl inside qt region, past y end
  float*  s0   = qt + 23592960;                        //     65,536 fl
  float*  kf   = s0 + 65536;                           //    737,280 fl
  bf16_t* wall3 = (bf16_t*)(kf + 737280);              // 1,474,560 bf16
  bf16_t* WoF3  = wall3 + 1474560;                     // 3 x 196,608 bf16
  bf16_t* BtF3  = WoF3 + 589824;                       // 3 x 131,072 bf16
  float* stats = (float*)(BtF3 + 393216);              // 384 fl
  float* twg   = stats + 384;                          // 1,024 fl (512 float2)

  k_tw<<<2, 256, 0, stream>>>((float2*)twg);
  k_s0<<<kN, 64, 0, stream>>>(tok_emb, Wf, s0);
  k_h0<<<8192, 256, 0, stream>>>(x, wv, s0, hsh);
  k_wqkv3<<<dim3(384, 3), 256, 0, stream>>>(
      (const float*)d_in[5], (const float*)d_in[6], (const float*)d_in[7],
      (const float*)d_in[14], (const float*)d_in[15], (const float*)d_in[16],
      (const float*)d_in[23], (const float*)d_in[24], (const float*)d_in[25], wall3);
  k_wo3<<<dim3(256, 3), 384, 0, stream>>>(
      (const float*)d_in[9], (const float*)d_in[18], (const float*)d_in[27], WoF3);
  k_bt3<<<dim3(256, 3), 256, 0, stream>>>(
      (const float*)d_in[10], (const float*)d_in[11],
      (const float*)d_in[19], (const float*)d_in[20],
      (const float*)d_in[28], (const float*)d_in[29], BtF3);

  for (int l = 0; l < 3; ++l) {
    const float* filt = (const float*)d_in[5 + 9 * l + 3];
    const float* g0   = (const float*)d_in[5 + 9 * l + 7];
    const float* g1   = (const float*)d_in[5 + 9 * l + 8];
    const int H = (l == 2) ? 160 : 360;
    const int gy = (H + 63) / 64;                      // 6 or 3
    const int KT = gy * 2;                             // K chunks of 32 (zero-padded weights)
    bf16_t* wall = wall3 + ((l == 2) ? 1179648 : (size_t)l * 589824);
    bf16_t* WoF  = WoF3 + (size_t)l * 196608;
    bf16_t* BtF  = BtF3 + (size_t)l * 131072;
    float* st = stats + l * 128;

    k_kf<<<H, 256, 0, stream>>>(filt, H, (const float2*)twg, (float2*)kf);
    k_qkv<<<gy * 1024, 256, 0, stream>>>(hsh, wall, H, qt, kvt);
    k_conv<<<32 * H, 256, 0, stream>>>(kvt, (const float2*)kf, (const float2*)twg, H);
    k_mix<<<4096, 256, 0, stream>>>(qt, kvt, H, KT, WoF, hsh);
    k_reg<<<4096, 256, 0, stream>>>(hsh, BtF, y, partial);
    k_stat<<<16, 256, 0, stream>>>(partial, st);
    k_bnact<<<8192, 256, 0, stream>>>(y, st, g0, g1, hsh);
  }

  k_pool<<<64, 256, 0, stream>>>(hsh, w_out, (float*)d_out);
}

// Round 11
// 1281.070 us; speedup vs baseline: 2.0618x; 1.0635x over previous
//
#include <hip/hip_runtime.h>
#include <math.h>

namespace {

typedef __bf16 bf16_t;
typedef bf16_t bf16x8 __attribute__((ext_vector_type(8)));
typedef float floatx4 __attribute__((ext_vector_type(4)));

constexpr int kN = 1024;      // tokens
constexpr int kM = 64;        // multiplicity
constexpr int kP = 64;        // PE dim
constexpr float kEps = 1e-5f;
constexpr int kFN = 1024;     // FFT length

__device__ __forceinline__ float sigmoidf(float v) { return 1.0f / (1.0f + expf(-v)); }

__device__ __forceinline__ floatx4 mfma16(bf16x8 a, bf16x8 b, floatx4 c) {
  return __builtin_amdgcn_mfma_f32_16x16x32_bf16(a, b, c, 0, 0, 0);
}

// 3-term split product: acc += (ah+al)*(bh+bl) dropping al*bl
__device__ __forceinline__ void fma3(floatx4& acc, bf16x8 ah, bf16x8 al,
                                     bf16x8 bh, bf16x8 bl) {
  acc = mfma16(ah, bh, acc);
  acc = mfma16(ah, bl, acc);
  acc = mfma16(al, bh, acc);
}

// load 8 contiguous fp32 (LDS), split into hi/lo bf16 fragments
__device__ __forceinline__ void load_split8(const float* p, bf16x8& hi, bf16x8& lo) {
  const float4 u = *(const float4*)p;
  const float4 v = *(const float4*)(p + 4);
  const float a[8] = {u.x, u.y, u.z, u.w, v.x, v.y, v.z, v.w};
#pragma unroll
  for (int i = 0; i < 8; ++i) {
    const bf16_t h_ = (bf16_t)a[i];
    hi[i] = h_;
    lo[i] = (bf16_t)(a[i] - (float)h_);
  }
}

union U4 { uint4 u; bf16_t b[8]; };

// async 16B/lane global->LDS DMA (wave-uniform LDS base + lane*16 scatter)
__device__ __forceinline__ void glds16(const bf16_t* g, bf16_t* l) {
  __builtin_amdgcn_global_load_lds(
      (const __attribute__((address_space(1))) void*)g,
      (__attribute__((address_space(3))) void*)l, 16, 0, 0);
}

// hsh fragment-major index for (row r, 8-elem group d8), hi plane (lo = +512)
// layout: [rb(1024)][kc(8)][rgrp(4)][p(2)][quad(4)][rl(16)][off(8)]
__device__ __forceinline__ size_t hidx(int r, int d8) {
  const int rb = r >> 6, rr = r & 63;
  return (size_t)(rb * 8 + (d8 >> 2)) * 4096 + (rr >> 4) * 1024 + (d8 & 3) * 128 + (rr & 15) * 8;
}

// padded LDS index for FFT work array (breaks small-span bank conflicts)
__device__ __forceinline__ int zi(int i) { return i + (i >> 4); }

__device__ __forceinline__ float2 cadd(float2 a, float2 b) { return {a.x + b.x, a.y + b.y}; }
__device__ __forceinline__ float2 csub(float2 a, float2 b) { return {a.x - b.x, a.y - b.y}; }
__device__ __forceinline__ float2 cmul(float2 a, float2 w) {
  return {a.x * w.x - a.y * w.y, a.x * w.y + a.y * w.x};
}
__device__ __forceinline__ float2 cmulc(float2 a, float2 w) {   // a * conj(w)
  return {a.x * w.x + a.y * w.y, a.y * w.x - a.x * w.y};
}

// ---------------------------------------------------------------- init
// s0[n, m] = sum_p (pe[n,p] + tok_emb[tt[n],p]) * Wf[p,m]
__global__ void k_s0(const float* __restrict__ tok_emb, const float* __restrict__ Wf,
                     float* __restrict__ s0) {
  __shared__ float f[kP];
  const int n = blockIdx.x;
  const int t = threadIdx.x;                       // 64 threads
  const int tt = (n == kN - 1) ? 2 : (n & 1);
  const int j = t >> 1;
  const float cexp = (float)(-9.210340371976184 / 64.0);   // -ln(10000)/P
  const float divj = expf((float)(2 * j) * cexp);
  const float ang = (float)n * divj;
  const float pe = (t & 1) ? cosf(ang) : sinf(ang);
  f[t] = pe + tok_emb[tt * kP + t];
  __syncthreads();
  float acc = 0.0f;
#pragma unroll 8
  for (int p = 0; p < kP; ++p) acc = fmaf(f[p], Wf[p * kM + t], acc);
  s0[n * kM + t] = acc;
}

// h planes (fragment-major): irreps m0=d8*2, m1=m0+1 per thread
__global__ void k_h0(const float* __restrict__ x, const float* __restrict__ wv,
                     const float* __restrict__ s0, bf16_t* __restrict__ hsh) {
  const int idx = blockIdx.x * 256 + threadIdx.x;  // r*32 + d8
  const int r = idx >> 5, d8 = idx & 31;
  const int n = r & (kN - 1);
  const int m0 = d8 * 2, m1 = m0 + 1;
  const float w0 = wv[m0], w1 = wv[m1];
  const float x0 = x[r * 3 + 0], x1 = x[r * 3 + 1], x2 = x[r * 3 + 2];
  float f[8];
  f[0] = s0[n * kM + m0]; f[1] = x0 * w0; f[2] = x1 * w0; f[3] = x2 * w0;
  f[4] = s0[n * kM + m1]; f[5] = x0 * w1; f[6] = x1 * w1; f[7] = x2 * w1;
  U4 oh, ol;
#pragma unroll
  for (int i = 0; i < 8; ++i) {
    const bf16_t h_ = (bf16_t)f[i];
    oh.b[i] = h_; ol.b[i] = (bf16_t)(f[i] - (float)h_);
  }
  const size_t base = hidx(r, d8);
  *(uint4*)(hsh + base) = oh.u;
  *(uint4*)(hsh + base + 512) = ol.u;
}

// ---------------------------------------------------------------- weight prep (batched, all 3 layers)
// wall per (ct,kc): [mat(3)][p(2)][cgrp(4)][quad(4)][cl(16)][off(8)] = 12288 elems
__global__ void k_wqkv3(const float* __restrict__ Wq0, const float* __restrict__ Wk0,
                        const float* __restrict__ Wv0,
                        const float* __restrict__ Wq1, const float* __restrict__ Wk1,
                        const float* __restrict__ Wv1,
                        const float* __restrict__ Wq2, const float* __restrict__ Wk2,
                        const float* __restrict__ Wv2, bf16_t* __restrict__ wall3) {
  const int l = blockIdx.y;
  const int H = (l == 2) ? 160 : 360;
  const int gy = (l == 2) ? 3 : 6;
  const int c = blockIdx.x;    // 0..383
  if (c >= gy * 64) return;
  const int k = threadIdx.x;   // 0..255
  const float* Wq = (l == 0) ? Wq0 : ((l == 1) ? Wq1 : Wq2);
  const float* Wk = (l == 0) ? Wk0 : ((l == 1) ? Wk1 : Wk2);
  const float* Wv = (l == 0) ? Wv0 : ((l == 1) ? Wv1 : Wv2);
  bf16_t* wall = wall3 + ((l == 2) ? 1179648 : (size_t)l * 589824);
  const bool ok = c < H;
  const float w[3] = {ok ? Wq[k * H + c] : 0.f, ok ? Wk[k * H + c] : 0.f,
                      ok ? Wv[k * H + c] : 0.f};
  const int ct = c >> 6, cgrp = (c >> 4) & 3, cl = c & 15;
  const int kc = k >> 5, quad = (k >> 3) & 3, off = k & 7;
  const size_t base = (size_t)(ct * 8 + kc) * 12288 + cgrp * 512 + quad * 128 + cl * 8 + off;
#pragma unroll
  for (int mat = 0; mat < 3; ++mat) {
    const bf16_t hi = (bf16_t)w[mat];
    wall[base + mat * 4096] = hi;
    wall[base + mat * 4096 + 2048] = (bf16_t)(w[mat] - (float)hi);
  }
}

// WoF per (dt,kc of 12): [p(2)][dgrp(4)][quad(4)][dl(16)][off(8)] = 4096 elems
__global__ void k_wo3(const float* __restrict__ Wo0, const float* __restrict__ Wo1,
                      const float* __restrict__ Wo2, bf16_t* __restrict__ WoF3) {
  const int l = blockIdx.y;
  const int H = (l == 2) ? 160 : 360;
  const float* Wo = (l == 0) ? Wo0 : ((l == 1) ? Wo1 : Wo2);
  bf16_t* WoF = WoF3 + (size_t)l * 196608;
  const int d = blockIdx.x;    // 0..255
  const int c = threadIdx.x;   // 0..383
  const float w = (c < H) ? Wo[c * 256 + d] : 0.f;
  const int dt = d >> 6, dgrp = (d >> 4) & 3, dl = d & 15;
  const int kc = c >> 5, quad = (c >> 3) & 3, off = c & 7;
  const size_t base = (size_t)(dt * 12 + kc) * 4096 + dgrp * 512 + quad * 128 + dl * 8 + off;
  const bf16_t hi = (bf16_t)w;
  WoF[base] = hi;
  WoF[base + 2048] = (bf16_t)(w - (float)hi);
}

// BtF per (ct,kc of 8): [p(2)][cgrp(4)][quad(4)][cl(16)][off(8)] = 4096 elems
__global__ void k_bt3(const float* __restrict__ W00, const float* __restrict__ W10,
                      const float* __restrict__ W01, const float* __restrict__ W11,
                      const float* __restrict__ W02, const float* __restrict__ W12,
                      bf16_t* __restrict__ BtF3) {
  const int l = blockIdx.y;
  const float* W0 = (l == 0) ? W00 : ((l == 1) ? W01 : W02);
  const float* W1 = (l == 0) ? W10 : ((l == 1) ? W11 : W12);
  bf16_t* BtF = BtF3 + (size_t)l * 131072;
  const int col = blockIdx.x, row = threadIdx.x;
  const int k = col >> 2, ck = col & 3, m = row >> 2, cm = row & 3;
  float v = 0.f;
  if (cm == ck) v = (ck == 0 ? W0 : W1)[m * 64 + k];
  const int ct = col >> 6, cgrp = (col >> 4) & 3, cl = col & 15;
  const int kc = row >> 5, quad = (row >> 3) & 3, off = row & 7;
  const size_t base = (size_t)(ct * 8 + kc) * 4096 + cgrp * 512 + quad * 128 + cl * 8 + off;
  const bf16_t hi = (bf16_t)v;
  BtF[base] = hi;
  BtF[base + 2048] = (bf16_t)(v - (float)hi);
}

// ---------------------------------------------------------------- FFT (fused radix-2 pairs)
// twiddle table -> global (once per launch)
__global__ void k_tw(float2* __restrict__ twg) {
  const int j = blockIdx.x * 256 + threadIdx.x;
  if (j < kFN / 2) {
    float s, c;
    sincosf(-6.283185307179586f * (float)j / (float)kFN, &s, &c);
    twg[j].x = c; twg[j].y = s;
  }
}

// forward DIF, two radix-2 stages fused per barrier: natural in -> bit-reversed out
__device__ void fft_dif(float2* z, const float2* tw) {
  const int p = threadIdx.x;
#pragma unroll
  for (int m = 256; m >= 1; m >>= 2) {     // fused spans (2m, m): (512,256)...(2,1)
    __syncthreads();
    const int pm = p & (m - 1);
    const int j = ((p & ~(m - 1)) << 2) | pm;
    const int tm2 = 512 / (2 * m), tm1 = 512 / m;
    const float2 x0 = z[zi(j)], x1 = z[zi(j + m)];
    const float2 x2 = z[zi(j + 2 * m)], x3 = z[zi(j + 3 * m)];
    const float2 w2 = tw[pm * tm2], w2b = tw[(pm + m) * tm2], w1 = tw[pm * tm1];
    const float2 a0 = cadd(x0, x2), a2 = cmul(csub(x0, x2), w2);
    const float2 a1 = cadd(x1, x3), a3 = cmul(csub(x1, x3), w2b);
    z[zi(j)]         = cadd(a0, a1);
    z[zi(j + m)]     = cmul(csub(a0, a1), w1);
    z[zi(j + 2 * m)] = cadd(a2, a3);
    z[zi(j + 3 * m)] = cmul(csub(a2, a3), w1);
  }
}

// inverse DIT, fused: bit-reversed in -> natural out (caller scales by 1/N)
__device__ void fft_dit_inv(float2* z, const float2* tw) {
  const int p = threadIdx.x;
#pragma unroll
  for (int m = 1; m <= 256; m <<= 2) {     // fused spans (m, 2m): (1,2)...(256,512)
    __syncthreads();
    const int pm = p & (m - 1);
    const int j = ((p & ~(m - 1)) << 2) | pm;
    const int tm2 = 512 / (2 * m), tm1 = 512 / m;
    const float2 x0 = z[zi(j)], x1 = z[zi(j + m)];
    const float2 x2 = z[zi(j + 2 * m)], x3 = z[zi(j + 3 * m)];
    const float2 w1 = tw[pm * tm1], w2 = tw[pm * tm2], w2b = tw[(pm + m) * tm2];
    const float2 c1 = cmulc(x1, w1), c3 = cmulc(x3, w1);
    const float2 b0 = cadd(x0, c1), b1 = csub(x0, c1);
    const float2 b2 = cadd(x2, c3), b3 = csub(x2, c3);
    const float2 d2 = cmulc(b2, w2), d3 = cmulc(b3, w2b);
    z[zi(j)]         = cadd(b0, d2);
    z[zi(j + 2 * m)] = csub(b0, d2);
    z[zi(j + m)]     = cadd(b1, d3);
    z[zi(j + 3 * m)] = csub(b1, d3);
  }
}

// filter spectrum, stored in DIF (bit-reversed) order; one block per channel
__global__ __launch_bounds__(256) void k_kf(const float* __restrict__ filt, int H,
                                            const float2* __restrict__ twg,
                                            float2* __restrict__ kf) {
  __shared__ float2 z[kFN + kFN / 16];
  __shared__ float2 tw[kFN / 2];
  const int c = blockIdx.x;
  for (int j = threadIdx.x; j < kFN / 2; j += 256) tw[j] = twg[j];
  for (int n = threadIdx.x; n < kFN; n += 256) {
    z[zi(n)].x = filt[n * H + c];
    z[zi(n)].y = 0.0f;
  }
  fft_dif(z, tw);
  __syncthreads();
  for (int j = threadIdx.x; j < kFN; j += 256) kf[c * kFN + j] = z[zi(j)];
}

// packed circular conv: two batch rows (same channel) per complex FFT
__global__ __launch_bounds__(256) void k_conv(float* kvt, const float2* __restrict__ kf,
                                              const float2* __restrict__ twg, int H) {
  __shared__ float2 z[kFN + kFN / 16];
  __shared__ float2 tw[kFN / 2];
  const int blk = blockIdx.x;              // pb*H + c
  const int c = blk % H;
  const int pb = blk / H;
  float* sig0 = kvt + (((size_t)((2 * pb) * H + c)) << 10);
  float* sig1 = kvt + (((size_t)((2 * pb + 1) * H + c)) << 10);
  for (int j = threadIdx.x; j < kFN / 2; j += 256) tw[j] = twg[j];
  for (int n = threadIdx.x; n < kFN; n += 256) {
    z[zi(n)].x = sig0[n];
    z[zi(n)].y = sig1[n];
  }
  fft_dif(z, tw);
  __syncthreads();
  for (int j = threadIdx.x; j < kFN; j += 256) {
    const float2 a = z[zi(j)];
    const float2 b = kf[c * kFN + j];
    float2 o;
    o.x = a.x * b.x - a.y * b.y;
    o.y = a.x * b.y + a.y * b.x;
    z[zi(j)] = o;
  }
  fft_dit_inv(z, tw);
  __syncthreads();
  const float s = 1.0f / (float)kFN;
  for (int n = threadIdx.x; n < kFN; n += 256) {
    sig0[n] = z[zi(n)].x * s;
    sig1[n] = z[zi(n)].y * s;
  }
}

// ---------------------------------------------------------------- GEMM 1 (split MFMA, LDS-DMA): q/k/v
// 128x64 tile (2 rb per block), XCD-swizzled; 72 MFMA per 40KB DMA chunk
__global__ __launch_bounds__(256) void k_qkv(const bf16_t* __restrict__ hsh,
    const bf16_t* __restrict__ wall, int H,
    float* __restrict__ qt, float* __restrict__ kvt) {
  __shared__ bf16_t lds[20480];            // 40 KB: A0 8K + A1 8K + B 24K
  const int gy = (H + 63) >> 6;
  const int bid = blockIdx.x;
  const int xcd = bid & 7, sseq = bid >> 3;
  const int ct = sseq % gy;
  const int rb2 = (sseq / gy) * 8 + xcd;
  const int rb0 = rb2 * 2, rb1 = rb0 + 1;
  const int t = threadIdx.x;
  const int lane = t & 63, wave = t >> 6;
  const int l15 = lane & 15, quad = lane >> 4;
  const int c0 = ct * 64;
  const int wr = (wave & 1) * 32, wc = (wave >> 1) * 32;
  const int wr16 = (wave & 1) * 2, wc16 = (wave >> 1) * 2;
  const int q128l = quad * 128 + l15 * 8;
  floatx4 aq[2][2][2] = {}, ak_[2][2][2] = {}, av_[2][2][2] = {};   // [rbx][i][j]
  for (int kt = 0; kt < 8; ++kt) {
    {
      const bf16_t* A0 = hsh + (size_t)(rb0 * 8 + kt) * 4096;
      const bf16_t* A1 = hsh + (size_t)(rb1 * 8 + kt) * 4096;
      const bf16_t* Bs = wall + (size_t)(ct * 8 + kt) * 12288;
#pragma unroll
      for (int s = 0; s < 10; ++s) {
        const int seg = wave * 10 + s;
        const bf16_t* src = (seg < 8) ? (A0 + seg * 512)
                          : (seg < 16) ? (A1 + (seg - 8) * 512)
                                       : (Bs + (seg - 16) * 512);
        glds16(src + lane * 8, &lds[seg * 512]);
      }
    }
    __syncthreads();
    bf16x8 ah[2][2], al[2][2];             // [rbx][i]
#pragma unroll
    for (int rbx = 0; rbx < 2; ++rbx)
#pragma unroll
      for (int i = 0; i < 2; ++i) {
        ah[rbx][i] = *(const bf16x8*)(lds + rbx * 4096 + ((wr16 + i) * 2 + 0) * 512 + q128l);
        al[rbx][i] = *(const bf16x8*)(lds + rbx * 4096 + ((wr16 + i) * 2 + 1) * 512 + q128l);
      }
#pragma unroll
    for (int mat = 0; mat < 3; ++mat) {
      const int bb = 8192 + mat * 4096;
#pragma unroll
      for (int j = 0; j < 2; ++j) {
        const bf16x8 bh = *(const bf16x8*)(lds + bb + (wc16 + j) * 512 + q128l);
        const bf16x8 bl = *(const bf16x8*)(lds + bb + 2048 + (wc16 + j) * 512 + q128l);
#pragma unroll
        for (int rbx = 0; rbx < 2; ++rbx)
#pragma unroll
          for (int i = 0; i < 2; ++i) {
            floatx4& a = (mat == 0) ? aq[rbx][i][j]
                       : (mat == 1) ? ak_[rbx][i][j] : av_[rbx][i][j];
            fma3(a, ah[rbx][i], al[rbx][i], bh, bl);
          }
      }
    }
    __syncthreads();
  }
#pragma unroll
  for (int rbx = 0; rbx < 2; ++rbx) {
    const int r0 = (rb0 + rbx) * 64;
    const int b = r0 >> 10;
    const int n0 = r0 & 1023;
#pragma unroll
    for (int j = 0; j < 2; ++j) {
      const int c = c0 + wc + j * 16 + l15;
      if (c < H) {
        const size_t rbw = (((size_t)(b * H + c)) << 10) + n0 + wr + quad * 4;
#pragma unroll
        for (int i = 0; i < 2; ++i) {
          float4 p;
          p.x = aq[rbx][i][j][0]; p.y = aq[rbx][i][j][1];
          p.z = aq[rbx][i][j][2]; p.w = aq[rbx][i][j][3];
          *(float4*)(qt + rbw + i * 16) = p;
        }
#pragma unroll
        for (int i = 0; i < 2; ++i) {
          float4 p;
          p.x = ak_[rbx][i][j][0] * av_[rbx][i][j][0];
          p.y = ak_[rbx][i][j][1] * av_[rbx][i][j][1];
          p.z = ak_[rbx][i][j][2] * av_[rbx][i][j][2];
          p.w = ak_[rbx][i][j][3] * av_[rbx][i][j][3];
          *(float4*)(kvt + rbw + i * 16) = p;
        }
      }
    }
  }
}

// ---------------------------------------------------------------- GEMM 2 (split MFMA): h += (q*conv) @ Wo
// XCD-swizzled: the 4 dt-blocks sharing one r0's qt/kvt strips run on one XCD
__global__ __launch_bounds__(256) void k_mix(const float* __restrict__ qt,
    const float* __restrict__ kvt, int H, int KT,
    const bf16_t* __restrict__ WoF, bf16_t* __restrict__ hsh) {
  __shared__ float smem[4352];             // As: 64 n x 36 ; epilogue: 64 x 68
  const int bid = blockIdx.x;
  const int xcd = bid & 7, sseq = bid >> 3;
  const int dt = sseq & 3;
  const int r0 = ((sseq >> 2) * 8 + xcd) * 64;
  const int t = threadIdx.x;
  const int lane = t & 63, wave = t >> 6;
  const int l15 = lane & 15, quad = lane >> 4;
  const int b = r0 >> 10, n0 = r0 & 1023;
  const int wr = (wave & 1) * 32, wc16 = (wave >> 1) * 2;
  const int q128l = quad * 128 + l15 * 8;
  floatx4 acc[2][2] = {};
  const int cl = t >> 3, n8 = (t & 7) * 8;
  for (int kt = 0; kt < KT; ++kt) {
    const int ck0 = kt * 32;
    __syncthreads();
    {
      const int c = ck0 + cl;
      float p[8] = {};
      if (c < H) {
        const size_t o = (((size_t)(b * H + c)) << 10) + n0 + n8;
        const float4 q0 = *(const float4*)(qt + o);
        const float4 q1 = *(const float4*)(qt + o + 4);
        const float4 v0 = *(const float4*)(kvt + o);
        const float4 v1 = *(const float4*)(kvt + o + 4);
        p[0] = q0.x * v0.x; p[1] = q0.y * v0.y; p[2] = q0.z * v0.z; p[3] = q0.w * v0.w;
        p[4] = q1.x * v1.x; p[5] = q1.y * v1.y; p[6] = q1.z * v1.z; p[7] = q1.w * v1.w;
      }
#pragma unroll
      for (int u = 0; u < 8; ++u) smem[(n8 + u) * 36 + cl] = p[u];
    }
    __syncthreads();
    bf16x8 ah0, al0, ah1, al1;
    load_split8(smem + (wr + l15) * 36 + quad * 8, ah0, al0);
    load_split8(smem + (wr + 16 + l15) * 36 + quad * 8, ah1, al1);
    const bf16_t* Bb = WoF + (size_t)(dt * 12 + kt) * 4096;
    const bf16x8 bh0 = *(const bf16x8*)(Bb + (wc16 + 0) * 512 + q128l);
    const bf16x8 bl0 = *(const bf16x8*)(Bb + 2048 + (wc16 + 0) * 512 + q128l);
    const bf16x8 bh1 = *(const bf16x8*)(Bb + (wc16 + 1) * 512 + q128l);
    const bf16x8 bl1 = *(const bf16x8*)(Bb + 2048 + (wc16 + 1) * 512 + q128l);
    fma3(acc[0][0], ah0, al0, bh0, bl0); fma3(acc[0][1], ah0, al0, bh1, bl1);
    fma3(acc[1][0], ah1, al1, bh0, bl0); fma3(acc[1][1], ah1, al1, bh1, bl1);
  }
  __syncthreads();
#pragma unroll
  for (int i = 0; i < 2; ++i)
#pragma unroll
    for (int j = 0; j < 2; ++j)
#pragma unroll
      for (int r = 0; r < 4; ++r)
        smem[(wr + i * 16 + quad * 4 + r) * 68 + (wave >> 1) * 32 + j * 16 + l15] = acc[i][j][r];
  __syncthreads();
  const int nl = t >> 2, q4 = t & 3;
  const int r = r0 + nl;
#pragma unroll
  for (int u8 = 0; u8 < 2; ++u8) {
    const int d8 = dt * 8 + q4 * 2 + u8;
    const size_t base = hidx(r, d8);
    U4 hi, lo;
    hi.u = *(const uint4*)(hsh + base);
    lo.u = *(const uint4*)(hsh + base + 512);
    U4 oh, ol;
#pragma unroll
    for (int i = 0; i < 8; ++i) {
      const float f = (float)hi.b[i] + (float)lo.b[i] + smem[nl * 68 + q4 * 16 + u8 * 8 + i];
      const bf16_t h_ = (bf16_t)f;
      oh.b[i] = h_; ol.b[i] = (bf16_t)(f - (float)h_);
    }
    *(uint4*)(hsh + base) = oh.u;
    *(uint4*)(hsh + base + 512) = ol.u;
  }
}

// ---------------------------------------------------------------- GEMM 3 (split MFMA, LDS-DMA): reg_linear + BN partials
// 128x64 tile (2 rb per block), XCD-swizzled
__global__ __launch_bounds__(256) void k_reg(const bf16_t* __restrict__ hsh,
    const bf16_t* __restrict__ BtF,
    float* __restrict__ y, float* __restrict__ partial) {
  __shared__ float smf[6144];              // 24 KB: DMA staging (A0 8K+A1 8K+B 8K) / epilogue alias
  __shared__ float red[256];
  bf16_t* lds = (bf16_t*)smf;
  const int bid = blockIdx.x;
  const int xcd = bid & 7, sseq = bid >> 3;
  const int ct = sseq & 3;
  const int rb2 = (sseq >> 2) * 8 + xcd;
  const int rb0 = rb2 * 2, rb1 = rb0 + 1;
  const int t = threadIdx.x;
  const int lane = t & 63, wave = t >> 6;
  const int l15 = lane & 15, quad = lane >> 4;
  const int c0 = ct * 64;
  const int wr = (wave & 1) * 32, wc = (wave >> 1) * 32;
  const int wr16 = (wave & 1) * 2, wc16 = (wave >> 1) * 2;
  const int q128l = quad * 128 + l15 * 8;
  floatx4 acc[2][2][2] = {};               // [rbx][i][j]
  for (int kt = 0; kt < 8; ++kt) {
    {
      const bf16_t* A0 = hsh + (size_t)(rb0 * 8 + kt) * 4096;
      const bf16_t* A1 = hsh + (size_t)(rb1 * 8 + kt) * 4096;
      const bf16_t* Bs = BtF + (size_t)(ct * 8 + kt) * 4096;
#pragma unroll
      for (int s = 0; s < 6; ++s) {
        const int seg = wave * 6 + s;
        const bf16_t* src = (seg < 8) ? (A0 + seg * 512)
                          : (seg < 16) ? (A1 + (seg - 8) * 512)
                                       : (Bs + (seg - 16) * 512);
        glds16(src + lane * 8, &lds[seg * 512]);
      }
    }
    __syncthreads();
    bf16x8 ah[2][2], al[2][2];
#pragma unroll
    for (int rbx = 0; rbx < 2; ++rbx)
#pragma unroll
      for (int i = 0; i < 2; ++i) {
        ah[rbx][i] = *(const bf16x8*)(lds + rbx * 4096 + ((wr16 + i) * 2 + 0) * 512 + q128l);
        al[rbx][i] = *(const bf16x8*)(lds + rbx * 4096 + ((wr16 + i) * 2 + 1) * 512 + q128l);
      }
#pragma unroll
    for (int j = 0; j < 2; ++j) {
      const bf16x8 bh = *(const bf16x8*)(lds + 8192 + (wc16 + j) * 512 + q128l);
      const bf16x8 bl = *(const bf16x8*)(lds + 8192 + 2048 + (wc16 + j) * 512 + q128l);
#pragma unroll
      for (int rbx = 0; rbx < 2; ++rbx)
#pragma unroll
        for (int i = 0; i < 2; ++i)
          fma3(acc[rbx][i][j], ah[rbx][i], al[rbx][i], bh, bl);
    }
    __syncthreads();
  }
  // per-column sum of squares, per rb
#pragma unroll
  for (int rbx = 0; rbx < 2; ++rbx)
#pragma unroll
    for (int j = 0; j < 2; ++j) {
      float s = 0.f;
#pragma unroll
      for (int i = 0; i < 2; ++i)
#pragma unroll
        for (int r = 0; r < 4; ++r)
          s = fmaf(acc[rbx][i][j][r], acc[rbx][i][j][r], s);
      s += __shfl_down(s, 32);
      s += __shfl_down(s, 16);
      if (lane < 16) red[rbx * 128 + wave * 32 + j * 16 + lane] = s;
    }
  // epilogue per rb (smf reused; staging reads all complete after loop barrier)
#pragma unroll
  for (int rbx = 0; rbx < 2; ++rbx) {
    __syncthreads();
#pragma unroll
    for (int i = 0; i < 2; ++i)
#pragma unroll
      for (int j = 0; j < 2; ++j)
#pragma unroll
        for (int r = 0; r < 4; ++r)
          smf[(wr + i * 16 + quad * 4 + r) * 68 + wc + j * 16 + l15] = acc[rbx][i][j][r];
    __syncthreads();
    const int nl = t >> 2, q4 = t & 3;
    const int r0 = (rb0 + rbx) * 64;
    const size_t gi = (size_t)(r0 + nl) * 256 + c0 + q4 * 16;
#pragma unroll
    for (int u = 0; u < 4; ++u) {
      float4 yv;
      yv.x = smf[nl * 68 + q4 * 16 + u * 4 + 0];
      yv.y = smf[nl * 68 + q4 * 16 + u * 4 + 1];
      yv.z = smf[nl * 68 + q4 * 16 + u * 4 + 2];
      yv.w = smf[nl * 68 + q4 * 16 + u * 4 + 3];
      *(float4*)(y + gi + u * 4) = yv;
    }
  }
  if (t < 64) {
    const int w0 = (t >= 32) ? 2 : 0;
    const float v0 = red[w0 * 32 + (t & 31)] + red[(w0 + 1) * 32 + (t & 31)];
    const float v1 = red[128 + w0 * 32 + (t & 31)] + red[128 + (w0 + 1) * 32 + (t & 31)];
    partial[(size_t)rb0 * 256 + c0 + t] = v0;   // race-free: one slot per column
    partial[(size_t)rb1 * 256 + c0 + t] = v1;
  }
}

// reduce partials over 1024 r-blocks -> stats[128]; 16 blocks, each owns 16 columns
__global__ __launch_bounds__(256) void k_stat(const float* __restrict__ partial,
                                              float* __restrict__ st) {
  __shared__ float sm1[16][16];
  __shared__ float tot[16];
  const int bb = blockIdx.x;               // 0..15
  const int t = threadIdx.x;
  const int col16 = t & 15, rgrp = t >> 4; // 16 cols x 16 row-groups
  const int c = bb * 16 + col16;
  float s = 0.f;
  for (int r = rgrp; r < 1024; r += 16) s += partial[(size_t)r * 256 + c];
  sm1[rgrp][col16] = s;
  __syncthreads();
  if (t < 16) {
    float v = 0.f;
#pragma unroll
    for (int g = 0; g < 16; ++g) v += sm1[g][t];
    tot[t] = v;
  }
  __syncthreads();
  if (t < 4) {
    const int m = bb * 4 + t;
    st[m] = tot[4 * t];
    st[64 + m] = tot[4 * t + 1] + tot[4 * t + 2] + tot[4 * t + 3];
  }
}

// ---------------------------------------------------------------- BN + norm-activation + residual
__global__ void k_bnact(const float* __restrict__ y, const float* __restrict__ stats,
    const float* __restrict__ g0, const float* __restrict__ g1, bf16_t* __restrict__ hsh) {
  const int idx = blockIdx.x * 256 + threadIdx.x;  // r*32 + d8
  const int r = idx >> 5, d8 = idx & 31;
  const int m0 = d8 * 2, m1 = m0 + 1;
  const float i00 = g0[m0] / sqrtf(stats[m0] * (1.0f / 65536.0f) + kEps);
  const float i10 = g1[m0] / sqrtf(stats[64 + m0] * (1.0f / 65536.0f) + kEps);
  const float i01 = g0[m1] / sqrtf(stats[m1] * (1.0f / 65536.0f) + kEps);
  const float i11 = g1[m1] / sqrtf(stats[64 + m1] * (1.0f / 65536.0f) + kEps);
  const float* yr = y + (size_t)r * 256 + d8 * 8;
  const float4 ya = *(const float4*)yr;
  const float4 yb = *(const float4*)(yr + 4);
  float a[8];
  {
    const float s = ya.x * i00;
    const float vx = ya.y * i10, vy = ya.z * i10, vz = ya.w * i10;
    const float so = s * sigmoidf(fabsf(s));
    const float vn = sqrtf(fmaf(vx, vx, fmaf(vy, vy, vz * vz)) + kEps);
    const float gv = sigmoidf(vn);
    a[0] = so; a[1] = vx * gv; a[2] = vy * gv; a[3] = vz * gv;
  }
  {
    const float s = yb.x * i01;
    const float vx = yb.y * i11, vy = yb.z * i11, vz = yb.w * i11;
    const float so = s * sigmoidf(fabsf(s));
    const float vn = sqrtf(fmaf(vx, vx, fmaf(vy, vy, vz * vz)) + kEps);
    const float gv = sigmoidf(vn);
    a[4] = so; a[5] = vx * gv; a[6] = vy * gv; a[7] = vz * gv;
  }
  const size_t base = hidx(r, d8);
  U4 hi, lo;
  hi.u = *(const uint4*)(hsh + base);
  lo.u = *(const uint4*)(hsh + base + 512);
  U4 oh, ol;
#pragma unroll
  for (int i = 0; i < 8; ++i) {
    const float f = (float)hi.b[i] + (float)lo.b[i] + a[i];
    const bf16_t h_ = (bf16_t)f;
    oh.b[i] = h_; ol.b[i] = (bf16_t)(f - (float)h_);
  }
  *(uint4*)(hsh + base) = oh.u;
  *(uint4*)(hsh + base + 512) = ol.u;
}

// ---------------------------------------------------------------- mean-pool + einsum
__global__ __launch_bounds__(256) void k_pool(const bf16_t* __restrict__ hsh,
    const float* __restrict__ w_out, float* __restrict__ out) {
  __shared__ float r0s[256], r1s[256], r2s[256];
  const int b = blockIdx.x;
  const int t = threadIdx.x;
  float p0 = 0, p1 = 0, p2 = 0;
  for (int idx = t; idx < kN * 32; idx += 256) {
    const int n = idx >> 5, d8 = idx & 31;
    const int r = (b << 10) + n;
    const size_t base = hidx(r, d8);
    U4 hi, lo;
    hi.u = *(const uint4*)(hsh + base);
    lo.u = *(const uint4*)(hsh + base + 512);
    const float w0 = w_out[d8 * 2], w1 = w_out[d8 * 2 + 1];
    p0 += ((float)hi.b[1] + (float)lo.b[1]) * w0 + ((float)hi.b[5] + (float)lo.b[5]) * w1;
    p1 += ((float)hi.b[2] + (float)lo.b[2]) * w0 + ((float)hi.b[6] + (float)lo.b[6]) * w1;
    p2 += ((float)hi.b[3] + (float)lo.b[3]) * w0 + ((float)hi.b[7] + (float)lo.b[7]) * w1;
  }
  r0s[t] = p0; r1s[t] = p1; r2s[t] = p2;
  __syncthreads();
  for (int s = 128; s > 0; s >>= 1) {
    if (t < s) { r0s[t] += r0s[t + s]; r1s[t] += r1s[t + s]; r2s[t] += r2s[t + s]; }
    __syncthreads();
  }
  if (t == 0) {
    out[b * 3 + 0] = r0s[0] * (1.0f / kN);
    out[b * 3 + 1] = r1s[0] * (1.0f / kN);
    out[b * 3 + 2] = r2s[0] * (1.0f / kN);
  }
}

} // namespace

extern "C" void kernel_launch(void* const* d_in, const int* in_sizes, int n_in,
                              void* d_out, int out_size, void* d_ws, size_t ws_size,
                              hipStream_t stream) {
  const float* x       = (const float*)d_in[0];
  const float* tok_emb = (const float*)d_in[1];
  const float* Wf      = (const float*)d_in[2];
  const float* wv      = (const float*)d_in[3];
  const float* w_out   = (const float*)d_in[4];

  float* ws    = (float*)d_ws;
  bf16_t* hsh  = (bf16_t*)ws;                          // 33,554,432 bf16 = 16,777,216 fl
  float*  kvt  = ws + 16777216;                        // 23,592,960 fl
  float*  qt   = kvt + 23592960;                       // 23,592,960 fl
  float*  y    = qt;                                   // alias: qt dead once k_mix done
  float*  partial = qt + 20000000;                     // 262,144 fl inside qt region, past y end
  float*  s0   = qt + 23592960;                        //     65,536 fl
  float*  kf   = s0 + 65536;                           //    737,280 fl
  bf16_t* wall3 = (bf16_t*)(kf + 737280);              // 1,474,560 bf16
  bf16_t* WoF3  = wall3 + 1474560;                     // 3 x 196,608 bf16
  bf16_t* BtF3  = WoF3 + 589824;                       // 3 x 131,072 bf16
  float* stats = (float*)(BtF3 + 393216);              // 384 fl
  float* twg   = stats + 384;                          // 1,024 fl (512 float2)

  k_tw<<<2, 256, 0, stream>>>((float2*)twg);
  k_s0<<<kN, 64, 0, stream>>>(tok_emb, Wf, s0);
  k_h0<<<8192, 256, 0, stream>>>(x, wv, s0, hsh);
  k_wqkv3<<<dim3(384, 3), 256, 0, stream>>>(
      (const float*)d_in[5], (const float*)d_in[6], (const float*)d_in[7],
      (const float*)d_in[14], (const float*)d_in[15], (const float*)d_in[16],
      (const float*)d_in[23], (const float*)d_in[24], (const float*)d_in[25], wall3);
  k_wo3<<<dim3(256, 3), 384, 0, stream>>>(
      (const float*)d_in[9], (const float*)d_in[18], (const float*)d_in[27], WoF3);
  k_bt3<<<dim3(256, 3), 256, 0, stream>>>(
      (const float*)d_in[10], (const float*)d_in[11],
      (const float*)d_in[19], (const float*)d_in[20],
      (const float*)d_in[28], (const float*)d_in[29], BtF3);

  for (int l = 0; l < 3; ++l) {
    const float* filt = (const float*)d_in[5 + 9 * l + 3];
    const float* g0   = (const float*)d_in[5 + 9 * l + 7];
    const float* g1   = (const float*)d_in[5 + 9 * l + 8];
    const int H = (l == 2) ? 160 : 360;
    const int gy = (H + 63) / 64;                      // 6 or 3
    const int KT = gy * 2;                             // K chunks of 32 (zero-padded weights)
    bf16_t* wall = wall3 + ((l == 2) ? 1179648 : (size_t)l * 589824);
    bf16_t* WoF  = WoF3 + (size_t)l * 196608;
    bf16_t* BtF  = BtF3 + (size_t)l * 131072;
    float* st = stats + l * 128;

    k_kf<<<H, 256, 0, stream>>>(filt, H, (const float2*)twg, (float2*)kf);
    k_qkv<<<gy * 512, 256, 0, stream>>>(hsh, wall, H, qt, kvt);
    k_conv<<<32 * H, 256, 0, stream>>>(kvt, (const float2*)kf, (const float2*)twg, H);
    k_mix<<<4096, 256, 0, stream>>>(qt, kvt, H, KT, WoF, hsh);
    k_reg<<<2048, 256, 0, stream>>>(hsh, BtF, y, partial);
    k_stat<<<16, 256, 0, stream>>>(partial, st);
    k_bnact<<<8192, 256, 0, stream>>>(y, st, g0, g1, hsh);
  }

  k_pool<<<64, 256, 0, stream>>>(hsh, w_out, (float*)d_out);
}

// Round 12
// 1274.758 us; speedup vs baseline: 2.0720x; 1.0050x over previous
//
#include <hip/hip_runtime.h>
#include <math.h>

namespace {

typedef __bf16 bf16_t;
typedef bf16_t bf16x8 __attribute__((ext_vector_type(8)));
typedef float floatx4 __attribute__((ext_vector_type(4)));

constexpr int kN = 1024;      // tokens
constexpr int kM = 64;        // multiplicity
constexpr int kP = 64;        // PE dim
constexpr float kEps = 1e-5f;
constexpr int kFN = 1024;     // FFT length

__device__ __forceinline__ float sigmoidf(float v) { return 1.0f / (1.0f + expf(-v)); }

__device__ __forceinline__ floatx4 mfma16(bf16x8 a, bf16x8 b, floatx4 c) {
  return __builtin_amdgcn_mfma_f32_16x16x32_bf16(a, b, c, 0, 0, 0);
}

// 3-term split product: acc += (ah+al)*(bh+bl) dropping al*bl
__device__ __forceinline__ void fma3(floatx4& acc, bf16x8 ah, bf16x8 al,
                                     bf16x8 bh, bf16x8 bl) {
  acc = mfma16(ah, bh, acc);
  acc = mfma16(ah, bl, acc);
  acc = mfma16(al, bh, acc);
}

// load 8 contiguous fp32 (LDS), split into hi/lo bf16 fragments
__device__ __forceinline__ void load_split8(const float* p, bf16x8& hi, bf16x8& lo) {
  const float4 u = *(const float4*)p;
  const float4 v = *(const float4*)(p + 4);
  const float a[8] = {u.x, u.y, u.z, u.w, v.x, v.y, v.z, v.w};
#pragma unroll
  for (int i = 0; i < 8; ++i) {
    const bf16_t h_ = (bf16_t)a[i];
    hi[i] = h_;
    lo[i] = (bf16_t)(a[i] - (float)h_);
  }
}

union U4 { uint4 u; bf16_t b[8]; };

// async 16B/lane global->LDS DMA (wave-uniform LDS base + lane*16 scatter)
__device__ __forceinline__ void glds16(const bf16_t* g, bf16_t* l) {
  __builtin_amdgcn_global_load_lds(
      (const __attribute__((address_space(1))) void*)g,
      (__attribute__((address_space(3))) void*)l, 16, 0, 0);
}

// hsh fragment-major index for (row r, 8-elem group d8), hi plane (lo = +512)
// layout: [rb(1024)][kc(8)][rgrp(4)][p(2)][quad(4)][rl(16)][off(8)]
__device__ __forceinline__ size_t hidx(int r, int d8) {
  const int rb = r >> 6, rr = r & 63;
  return (size_t)(rb * 8 + (d8 >> 2)) * 4096 + (rr >> 4) * 1024 + (d8 & 3) * 128 + (rr & 15) * 8;
}

// padded LDS index for FFT work array (breaks small-span bank conflicts)
__device__ __forceinline__ int zi(int i) { return i + (i >> 4); }

__device__ __forceinline__ float2 cadd(float2 a, float2 b) { return {a.x + b.x, a.y + b.y}; }
__device__ __forceinline__ float2 csub(float2 a, float2 b) { return {a.x - b.x, a.y - b.y}; }
__device__ __forceinline__ float2 cmul(float2 a, float2 w) {
  return {a.x * w.x - a.y * w.y, a.x * w.y + a.y * w.x};
}
__device__ __forceinline__ float2 cmulc(float2 a, float2 w) {   // a * conj(w)
  return {a.x * w.x + a.y * w.y, a.y * w.x - a.x * w.y};
}

// ---------------------------------------------------------------- init
// s0[n, m] = sum_p (pe[n,p] + tok_emb[tt[n],p]) * Wf[p,m]
__global__ void k_s0(const float* __restrict__ tok_emb, const float* __restrict__ Wf,
                     float* __restrict__ s0) {
  __shared__ float f[kP];
  const int n = blockIdx.x;
  const int t = threadIdx.x;                       // 64 threads
  const int tt = (n == kN - 1) ? 2 : (n & 1);
  const int j = t >> 1;
  const float cexp = (float)(-9.210340371976184 / 64.0);   // -ln(10000)/P
  const float divj = expf((float)(2 * j) * cexp);
  const float ang = (float)n * divj;
  const float pe = (t & 1) ? cosf(ang) : sinf(ang);
  f[t] = pe + tok_emb[tt * kP + t];
  __syncthreads();
  float acc = 0.0f;
#pragma unroll 8
  for (int p = 0; p < kP; ++p) acc = fmaf(f[p], Wf[p * kM + t], acc);
  s0[n * kM + t] = acc;
}

// h planes (fragment-major): irreps m0=d8*2, m1=m0+1 per thread
__global__ void k_h0(const float* __restrict__ x, const float* __restrict__ wv,
                     const float* __restrict__ s0, bf16_t* __restrict__ hsh) {
  const int idx = blockIdx.x * 256 + threadIdx.x;  // r*32 + d8
  const int r = idx >> 5, d8 = idx & 31;
  const int n = r & (kN - 1);
  const int m0 = d8 * 2, m1 = m0 + 1;
  const float w0 = wv[m0], w1 = wv[m1];
  const float x0 = x[r * 3 + 0], x1 = x[r * 3 + 1], x2 = x[r * 3 + 2];
  float f[8];
  f[0] = s0[n * kM + m0]; f[1] = x0 * w0; f[2] = x1 * w0; f[3] = x2 * w0;
  f[4] = s0[n * kM + m1]; f[5] = x0 * w1; f[6] = x1 * w1; f[7] = x2 * w1;
  U4 oh, ol;
#pragma unroll
  for (int i = 0; i < 8; ++i) {
    const bf16_t h_ = (bf16_t)f[i];
    oh.b[i] = h_; ol.b[i] = (bf16_t)(f[i] - (float)h_);
  }
  const size_t base = hidx(r, d8);
  *(uint4*)(hsh + base) = oh.u;
  *(uint4*)(hsh + base + 512) = ol.u;
}

// ---------------------------------------------------------------- weight prep (batched, all 3 layers)
// wall per (ct,kc): [mat(3)][p(2)][cgrp(4)][quad(4)][cl(16)][off(8)] = 12288 elems
__global__ void k_wqkv3(const float* __restrict__ Wq0, const float* __restrict__ Wk0,
                        const float* __restrict__ Wv0,
                        const float* __restrict__ Wq1, const float* __restrict__ Wk1,
                        const float* __restrict__ Wv1,
                        const float* __restrict__ Wq2, const float* __restrict__ Wk2,
                        const float* __restrict__ Wv2, bf16_t* __restrict__ wall3) {
  const int l = blockIdx.y;
  const int H = (l == 2) ? 160 : 360;
  const int gy = (l == 2) ? 3 : 6;
  const int c = blockIdx.x;    // 0..383
  if (c >= gy * 64) return;
  const int k = threadIdx.x;   // 0..255
  const float* Wq = (l == 0) ? Wq0 : ((l == 1) ? Wq1 : Wq2);
  const float* Wk = (l == 0) ? Wk0 : ((l == 1) ? Wk1 : Wk2);
  const float* Wv = (l == 0) ? Wv0 : ((l == 1) ? Wv1 : Wv2);
  bf16_t* wall = wall3 + ((l == 2) ? 1179648 : (size_t)l * 589824);
  const bool ok = c < H;
  const float w[3] = {ok ? Wq[k * H + c] : 0.f, ok ? Wk[k * H + c] : 0.f,
                      ok ? Wv[k * H + c] : 0.f};
  const int ct = c >> 6, cgrp = (c >> 4) & 3, cl = c & 15;
  const int kc = k >> 5, quad = (k >> 3) & 3, off = k & 7;
  const size_t base = (size_t)(ct * 8 + kc) * 12288 + cgrp * 512 + quad * 128 + cl * 8 + off;
#pragma unroll
  for (int mat = 0; mat < 3; ++mat) {
    const bf16_t hi = (bf16_t)w[mat];
    wall[base + mat * 4096] = hi;
    wall[base + mat * 4096 + 2048] = (bf16_t)(w[mat] - (float)hi);
  }
}

// WoF per (dt,kc of 12): [p(2)][dgrp(4)][quad(4)][dl(16)][off(8)] = 4096 elems
__global__ void k_wo3(const float* __restrict__ Wo0, const float* __restrict__ Wo1,
                      const float* __restrict__ Wo2, bf16_t* __restrict__ WoF3) {
  const int l = blockIdx.y;
  const int H = (l == 2) ? 160 : 360;
  const float* Wo = (l == 0) ? Wo0 : ((l == 1) ? Wo1 : Wo2);
  bf16_t* WoF = WoF3 + (size_t)l * 196608;
  const int d = blockIdx.x;    // 0..255
  const int c = threadIdx.x;   // 0..383
  const float w = (c < H) ? Wo[c * 256 + d] : 0.f;
  const int dt = d >> 6, dgrp = (d >> 4) & 3, dl = d & 15;
  const int kc = c >> 5, quad = (c >> 3) & 3, off = c & 7;
  const size_t base = (size_t)(dt * 12 + kc) * 4096 + dgrp * 512 + quad * 128 + dl * 8 + off;
  const bf16_t hi = (bf16_t)w;
  WoF[base] = hi;
  WoF[base + 2048] = (bf16_t)(w - (float)hi);
}

// BtF per (ct,kc of 8): [p(2)][cgrp(4)][quad(4)][cl(16)][off(8)] = 4096 elems
__global__ void k_bt3(const float* __restrict__ W00, const float* __restrict__ W10,
                      const float* __restrict__ W01, const float* __restrict__ W11,
                      const float* __restrict__ W02, const float* __restrict__ W12,
                      bf16_t* __restrict__ BtF3) {
  const int l = blockIdx.y;
  const float* W0 = (l == 0) ? W00 : ((l == 1) ? W01 : W02);
  const float* W1 = (l == 0) ? W10 : ((l == 1) ? W11 : W12);
  bf16_t* BtF = BtF3 + (size_t)l * 131072;
  const int col = blockIdx.x, row = threadIdx.x;
  const int k = col >> 2, ck = col & 3, m = row >> 2, cm = row & 3;
  float v = 0.f;
  if (cm == ck) v = (ck == 0 ? W0 : W1)[m * 64 + k];
  const int ct = col >> 6, cgrp = (col >> 4) & 3, cl = col & 15;
  const int kc = row >> 5, quad = (row >> 3) & 3, off = row & 7;
  const size_t base = (size_t)(ct * 8 + kc) * 4096 + cgrp * 512 + quad * 128 + cl * 8 + off;
  const bf16_t hi = (bf16_t)v;
  BtF[base] = hi;
  BtF[base + 2048] = (bf16_t)(v - (float)hi);
}

// ---------------------------------------------------------------- FFT (fused radix-2 pairs)
// twiddle table -> global (once per launch)
__global__ void k_tw(float2* __restrict__ twg) {
  const int j = blockIdx.x * 256 + threadIdx.x;
  if (j < kFN / 2) {
    float s, c;
    sincosf(-6.283185307179586f * (float)j / (float)kFN, &s, &c);
    twg[j].x = c; twg[j].y = s;
  }
}

// forward DIF, two radix-2 stages fused per barrier: natural in -> bit-reversed out
__device__ void fft_dif(float2* z, const float2* tw) {
  const int p = threadIdx.x;
#pragma unroll
  for (int m = 256; m >= 1; m >>= 2) {     // fused spans (2m, m): (512,256)...(2,1)
    __syncthreads();
    const int pm = p & (m - 1);
    const int j = ((p & ~(m - 1)) << 2) | pm;
    const int tm2 = 512 / (2 * m), tm1 = 512 / m;
    const float2 x0 = z[zi(j)], x1 = z[zi(j + m)];
    const float2 x2 = z[zi(j + 2 * m)], x3 = z[zi(j + 3 * m)];
    const float2 w2 = tw[pm * tm2], w2b = tw[(pm + m) * tm2], w1 = tw[pm * tm1];
    const float2 a0 = cadd(x0, x2), a2 = cmul(csub(x0, x2), w2);
    const float2 a1 = cadd(x1, x3), a3 = cmul(csub(x1, x3), w2b);
    z[zi(j)]         = cadd(a0, a1);
    z[zi(j + m)]     = cmul(csub(a0, a1), w1);
    z[zi(j + 2 * m)] = cadd(a2, a3);
    z[zi(j + 3 * m)] = cmul(csub(a2, a3), w1);
  }
}

// inverse DIT, fused: bit-reversed in -> natural out (caller scales by 1/N)
__device__ void fft_dit_inv(float2* z, const float2* tw) {
  const int p = threadIdx.x;
#pragma unroll
  for (int m = 1; m <= 256; m <<= 2) {     // fused spans (m, 2m): (1,2)...(256,512)
    __syncthreads();
    const int pm = p & (m - 1);
    const int j = ((p & ~(m - 1)) << 2) | pm;
    const int tm2 = 512 / (2 * m), tm1 = 512 / m;
    const float2 x0 = z[zi(j)], x1 = z[zi(j + m)];
    const float2 x2 = z[zi(j + 2 * m)], x3 = z[zi(j + 3 * m)];
    const float2 w1 = tw[pm * tm1], w2 = tw[pm * tm2], w2b = tw[(pm + m) * tm2];
    const float2 c1 = cmulc(x1, w1), c3 = cmulc(x3, w1);
    const float2 b0 = cadd(x0, c1), b1 = csub(x0, c1);
    const float2 b2 = cadd(x2, c3), b3 = csub(x2, c3);
    const float2 d2 = cmulc(b2, w2), d3 = cmulc(b3, w2b);
    z[zi(j)]         = cadd(b0, d2);
    z[zi(j + 2 * m)] = csub(b0, d2);
    z[zi(j + m)]     = cadd(b1, d3);
    z[zi(j + 3 * m)] = csub(b1, d3);
  }
}

// filter spectrum, stored in DIF (bit-reversed) order; one block per channel
__global__ __launch_bounds__(256) void k_kf(const float* __restrict__ filt, int H,
                                            const float2* __restrict__ twg,
                                            float2* __restrict__ kf) {
  __shared__ float2 z[kFN + kFN / 16];
  __shared__ float2 tw[kFN / 2];
  const int c = blockIdx.x;
  for (int j = threadIdx.x; j < kFN / 2; j += 256) tw[j] = twg[j];
  for (int n = threadIdx.x; n < kFN; n += 256) {
    z[zi(n)].x = filt[n * H + c];
    z[zi(n)].y = 0.0f;
  }
  fft_dif(z, tw);
  __syncthreads();
  for (int j = threadIdx.x; j < kFN; j += 256) kf[c * kFN + j] = z[zi(j)];
}

// packed circular conv + fused q-product: two batch rows (same channel) per complex FFT
// writes prod = conv * q in-place into kvt (identical rounding to prior q*(stored conv))
__global__ __launch_bounds__(256) void k_conv(float* kvt, const float* __restrict__ qt,
                                              const float2* __restrict__ kf,
                                              const float2* __restrict__ twg, int H) {
  __shared__ float2 z[kFN + kFN / 16];
  __shared__ float2 tw[kFN / 2];
  const int blk = blockIdx.x;              // pb*H + c
  const int c = blk % H;
  const int pb = blk / H;
  float* sig0 = kvt + (((size_t)((2 * pb) * H + c)) << 10);
  float* sig1 = kvt + (((size_t)((2 * pb + 1) * H + c)) << 10);
  const float* q0 = qt + (((size_t)((2 * pb) * H + c)) << 10);
  const float* q1 = qt + (((size_t)((2 * pb + 1) * H + c)) << 10);
  for (int j = threadIdx.x; j < kFN / 2; j += 256) tw[j] = twg[j];
  for (int n = threadIdx.x; n < kFN; n += 256) {
    z[zi(n)].x = sig0[n];
    z[zi(n)].y = sig1[n];
  }
  fft_dif(z, tw);
  __syncthreads();
  for (int j = threadIdx.x; j < kFN; j += 256) {
    const float2 a = z[zi(j)];
    const float2 b = kf[c * kFN + j];
    float2 o;
    o.x = a.x * b.x - a.y * b.y;
    o.y = a.x * b.y + a.y * b.x;
    z[zi(j)] = o;
  }
  fft_dit_inv(z, tw);
  __syncthreads();
  const float s = 1.0f / (float)kFN;
  for (int n = threadIdx.x; n < kFN; n += 256) {
    sig0[n] = (z[zi(n)].x * s) * q0[n];
    sig1[n] = (z[zi(n)].y * s) * q1[n];
  }
}

// ---------------------------------------------------------------- GEMM 1 (split MFMA, LDS-DMA): q/k/v
// 128x64 tile (2 rb per block), XCD-swizzled; 72 MFMA per 40KB DMA chunk
__global__ __launch_bounds__(256) void k_qkv(const bf16_t* __restrict__ hsh,
    const bf16_t* __restrict__ wall, int H,
    float* __restrict__ qt, float* __restrict__ kvt) {
  __shared__ bf16_t lds[20480];            // 40 KB: A0 8K + A1 8K + B 24K
  const int gy = (H + 63) >> 6;
  const int bid = blockIdx.x;
  const int xcd = bid & 7, sseq = bid >> 3;
  const int ct = sseq % gy;
  const int rb2 = (sseq / gy) * 8 + xcd;
  const int rb0 = rb2 * 2, rb1 = rb0 + 1;
  const int t = threadIdx.x;
  const int lane = t & 63, wave = t >> 6;
  const int l15 = lane & 15, quad = lane >> 4;
  const int c0 = ct * 64;
  const int wr = (wave & 1) * 32, wc = (wave >> 1) * 32;
  const int wr16 = (wave & 1) * 2, wc16 = (wave >> 1) * 2;
  const int q128l = quad * 128 + l15 * 8;
  floatx4 aq[2][2][2] = {}, ak_[2][2][2] = {}, av_[2][2][2] = {};   // [rbx][i][j]
  for (int kt = 0; kt < 8; ++kt) {
    {
      const bf16_t* A0 = hsh + (size_t)(rb0 * 8 + kt) * 4096;
      const bf16_t* A1 = hsh + (size_t)(rb1 * 8 + kt) * 4096;
      const bf16_t* Bs = wall + (size_t)(ct * 8 + kt) * 12288;
#pragma unroll
      for (int s = 0; s < 10; ++s) {
        const int seg = wave * 10 + s;
        const bf16_t* src = (seg < 8) ? (A0 + seg * 512)
                          : (seg < 16) ? (A1 + (seg - 8) * 512)
                                       : (Bs + (seg - 16) * 512);
        glds16(src + lane * 8, &lds[seg * 512]);
      }
    }
    __syncthreads();
    bf16x8 ah[2][2], al[2][2];             // [rbx][i]
#pragma unroll
    for (int rbx = 0; rbx < 2; ++rbx)
#pragma unroll
      for (int i = 0; i < 2; ++i) {
        ah[rbx][i] = *(const bf16x8*)(lds + rbx * 4096 + ((wr16 + i) * 2 + 0) * 512 + q128l);
        al[rbx][i] = *(const bf16x8*)(lds + rbx * 4096 + ((wr16 + i) * 2 + 1) * 512 + q128l);
      }
#pragma unroll
    for (int mat = 0; mat < 3; ++mat) {
      const int bb = 8192 + mat * 4096;
#pragma unroll
      for (int j = 0; j < 2; ++j) {
        const bf16x8 bh = *(const bf16x8*)(lds + bb + (wc16 + j) * 512 + q128l);
        const bf16x8 bl = *(const bf16x8*)(lds + bb + 2048 + (wc16 + j) * 512 + q128l);
#pragma unroll
        for (int rbx = 0; rbx < 2; ++rbx)
#pragma unroll
          for (int i = 0; i < 2; ++i) {
            floatx4& a = (mat == 0) ? aq[rbx][i][j]
                       : (mat == 1) ? ak_[rbx][i][j] : av_[rbx][i][j];
            fma3(a, ah[rbx][i], al[rbx][i], bh, bl);
          }
      }
    }
    __syncthreads();
  }
#pragma unroll
  for (int rbx = 0; rbx < 2; ++rbx) {
    const int r0 = (rb0 + rbx) * 64;
    const int b = r0 >> 10;
    const int n0 = r0 & 1023;
#pragma unroll
    for (int j = 0; j < 2; ++j) {
      const int c = c0 + wc + j * 16 + l15;
      if (c < H) {
        const size_t rbw = (((size_t)(b * H + c)) << 10) + n0 + wr + quad * 4;
#pragma unroll
        for (int i = 0; i < 2; ++i) {
          float4 p;
          p.x = aq[rbx][i][j][0]; p.y = aq[rbx][i][j][1];
          p.z = aq[rbx][i][j][2]; p.w = aq[rbx][i][j][3];
          *(float4*)(qt + rbw + i * 16) = p;
        }
#pragma unroll
        for (int i = 0; i < 2; ++i) {
          float4 p;
          p.x = ak_[rbx][i][j][0] * av_[rbx][i][j][0];
          p.y = ak_[rbx][i][j][1] * av_[rbx][i][j][1];
          p.z = ak_[rbx][i][j][2] * av_[rbx][i][j][2];
          p.w = ak_[rbx][i][j][3] * av_[rbx][i][j][3];
          *(float4*)(kvt + rbw + i * 16) = p;
        }
      }
    }
  }
}

// ---------------------------------------------------------------- GEMM 2 (split MFMA): h += prod @ Wo
// v2: one block per 64-row strip, all 256 output cols (no dt redundancy)
__global__ __launch_bounds__(256) void k_mix(const float* __restrict__ pv, int H, int KT,
    const bf16_t* __restrict__ WoF, bf16_t* __restrict__ hsh) {
  __shared__ float smem[4352];             // staging 64x36 (2304) / epilogue 64x68 (aliased)
  const int r0 = blockIdx.x * 64;
  const int t = threadIdx.x;
  const int lane = t & 63, wave = t >> 6;
  const int l15 = lane & 15, quad = lane >> 4;
  const int b = r0 >> 10, n0 = r0 & 1023;
  const int wr = (wave & 1) * 32, wh = wave >> 1;
  const int q128l = quad * 128 + l15 * 8;
  floatx4 acc[2][8] = {};                  // [i][j]: rows wr+i*16, col tile wh*8+j
  const int cl = t >> 3, n8 = (t & 7) * 8;
  for (int kt = 0; kt < KT; ++kt) {
    const int ck0 = kt * 32;
    __syncthreads();
    {
      const int c = ck0 + cl;
      float p[8] = {};
      if (c < H) {
        const size_t o = (((size_t)(b * H + c)) << 10) + n0 + n8;
        const float4 p0 = *(const float4*)(pv + o);
        const float4 p1 = *(const float4*)(pv + o + 4);
        p[0] = p0.x; p[1] = p0.y; p[2] = p0.z; p[3] = p0.w;
        p[4] = p1.x; p[5] = p1.y; p[6] = p1.z; p[7] = p1.w;
      }
#pragma unroll
      for (int u = 0; u < 8; ++u) smem[(n8 + u) * 36 + cl] = p[u];
    }
    __syncthreads();
    bf16x8 ah0, al0, ah1, al1;
    load_split8(smem + (wr + l15) * 36 + quad * 8, ah0, al0);
    load_split8(smem + (wr + 16 + l15) * 36 + quad * 8, ah1, al1);
#pragma unroll
    for (int j = 0; j < 8; ++j) {
      const int jj = wh * 8 + j;           // global 16-col tile 0..15
      const int dt = jj >> 2, dgrp = jj & 3;
      const bf16_t* Bb = WoF + (size_t)(dt * 12 + kt) * 4096 + dgrp * 512 + q128l;
      const bf16x8 bh = *(const bf16x8*)Bb;
      const bf16x8 bl = *(const bf16x8*)(Bb + 2048);
      fma3(acc[0][j], ah0, al0, bh, bl);
      fma3(acc[1][j], ah1, al1, bh, bl);
    }
  }
  // epilogue: 4 passes over 64-col groups through the shared buffer
  const int nl = t >> 2, q4 = t & 3;
  const int r = r0 + nl;
#pragma unroll
  for (int g = 0; g < 4; ++g) {
    __syncthreads();
    if (wh == (g >> 1)) {
#pragma unroll
      for (int jl = 0; jl < 4; ++jl) {
        const int j = (g & 1) * 4 + jl;
#pragma unroll
        for (int i = 0; i < 2; ++i)
#pragma unroll
          for (int rr = 0; rr < 4; ++rr)
            smem[(wr + i * 16 + quad * 4 + rr) * 68 + jl * 16 + l15] = acc[i][j][rr];
      }
    }
    __syncthreads();
#pragma unroll
    for (int u8 = 0; u8 < 2; ++u8) {
      const int d8 = g * 8 + q4 * 2 + u8;
      const size_t base = hidx(r, d8);
      U4 hi, lo;
      hi.u = *(const uint4*)(hsh + base);
      lo.u = *(const uint4*)(hsh + base + 512);
      U4 oh, ol;
#pragma unroll
      for (int i = 0; i < 8; ++i) {
        const float f = (float)hi.b[i] + (float)lo.b[i] +
                        smem[nl * 68 + (q4 * 2 + u8) * 8 + i];
        const bf16_t h_ = (bf16_t)f;
        oh.b[i] = h_; ol.b[i] = (bf16_t)(f - (float)h_);
      }
      *(uint4*)(hsh + base) = oh.u;
      *(uint4*)(hsh + base + 512) = ol.u;
    }
  }
}

// ---------------------------------------------------------------- GEMM 3 (split MFMA, LDS-DMA): reg_linear + BN partials
// 128x64 tile (2 rb per block), XCD-swizzled
__global__ __launch_bounds__(256) void k_reg(const bf16_t* __restrict__ hsh,
    const bf16_t* __restrict__ BtF,
    float* __restrict__ y, float* __restrict__ partial) {
  __shared__ float smf[6144];              // 24 KB: DMA staging (A0 8K+A1 8K+B 8K) / epilogue alias
  __shared__ float red[256];
  bf16_t* lds = (bf16_t*)smf;
  const int bid = blockIdx.x;
  const int xcd = bid & 7, sseq = bid >> 3;
  const int ct = sseq & 3;
  const int rb2 = (sseq >> 2) * 8 + xcd;
  const int rb0 = rb2 * 2, rb1 = rb0 + 1;
  const int t = threadIdx.x;
  const int lane = t & 63, wave = t >> 6;
  const int l15 = lane & 15, quad = lane >> 4;
  const int c0 = ct * 64;
  const int wr = (wave & 1) * 32, wc = (wave >> 1) * 32;
  const int wr16 = (wave & 1) * 2, wc16 = (wave >> 1) * 2;
  const int q128l = quad * 128 + l15 * 8;
  floatx4 acc[2][2][2] = {};               // [rbx][i][j]
  for (int kt = 0; kt < 8; ++kt) {
    {
      const bf16_t* A0 = hsh + (size_t)(rb0 * 8 + kt) * 4096;
      const bf16_t* A1 = hsh + (size_t)(rb1 * 8 + kt) * 4096;
      const bf16_t* Bs = BtF + (size_t)(ct * 8 + kt) * 4096;
#pragma unroll
      for (int s = 0; s < 6; ++s) {
        const int seg = wave * 6 + s;
        const bf16_t* src = (seg < 8) ? (A0 + seg * 512)
                          : (seg < 16) ? (A1 + (seg - 8) * 512)
                                       : (Bs + (seg - 16) * 512);
        glds16(src + lane * 8, &lds[seg * 512]);
      }
    }
    __syncthreads();
    bf16x8 ah[2][2], al[2][2];
#pragma unroll
    for (int rbx = 0; rbx < 2; ++rbx)
#pragma unroll
      for (int i = 0; i < 2; ++i) {
        ah[rbx][i] = *(const bf16x8*)(lds + rbx * 4096 + ((wr16 + i) * 2 + 0) * 512 + q128l);
        al[rbx][i] = *(const bf16x8*)(lds + rbx * 4096 + ((wr16 + i) * 2 + 1) * 512 + q128l);
      }
#pragma unroll
    for (int j = 0; j < 2; ++j) {
      const bf16x8 bh = *(const bf16x8*)(lds + 8192 + (wc16 + j) * 512 + q128l);
      const bf16x8 bl = *(const bf16x8*)(lds + 8192 + 2048 + (wc16 + j) * 512 + q128l);
#pragma unroll
      for (int rbx = 0; rbx < 2; ++rbx)
#pragma unroll
        for (int i = 0; i < 2; ++i)
          fma3(acc[rbx][i][j], ah[rbx][i], al[rbx][i], bh, bl);
    }
    __syncthreads();
  }
  // per-column sum of squares, per rb
#pragma unroll
  for (int rbx = 0; rbx < 2; ++rbx)
#pragma unroll
    for (int j = 0; j < 2; ++j) {
      float s = 0.f;
#pragma unroll
      for (int i = 0; i < 2; ++i)
#pragma unroll
        for (int r = 0; r < 4; ++r)
          s = fmaf(acc[rbx][i][j][r], acc[rbx][i][j][r], s);
      s += __shfl_down(s, 32);
      s += __shfl_down(s, 16);
      if (lane < 16) red[rbx * 128 + wave * 32 + j * 16 + lane] = s;
    }
  // epilogue per rb (smf reused; staging reads all complete after loop barrier)
#pragma unroll
  for (int rbx = 0; rbx < 2; ++rbx) {
    __syncthreads();
#pragma unroll
    for (int i = 0; i < 2; ++i)
#pragma unroll
      for (int j = 0; j < 2; ++j)
#pragma unroll
        for (int r = 0; r < 4; ++r)
          smf[(wr + i * 16 + quad * 4 + r) * 68 + wc + j * 16 + l15] = acc[rbx][i][j][r];
    __syncthreads();
    const int nl = t >> 2, q4 = t & 3;
    const int r0 = (rb0 + rbx) * 64;
    const size_t gi = (size_t)(r0 + nl) * 256 + c0 + q4 * 16;
#pragma unroll
    for (int u = 0; u < 4; ++u) {
      float4 yv;
      yv.x = smf[nl * 68 + q4 * 16 + u * 4 + 0];
      yv.y = smf[nl * 68 + q4 * 16 + u * 4 + 1];
      yv.z = smf[nl * 68 + q4 * 16 + u * 4 + 2];
      yv.w = smf[nl * 68 + q4 * 16 + u * 4 + 3];
      *(float4*)(y + gi + u * 4) = yv;
    }
  }
  if (t < 64) {
    const int w0 = (t >= 32) ? 2 : 0;
    const float v0 = red[w0 * 32 + (t & 31)] + red[(w0 + 1) * 32 + (t & 31)];
    const float v1 = red[128 + w0 * 32 + (t & 31)] + red[128 + (w0 + 1) * 32 + (t & 31)];
    partial[(size_t)rb0 * 256 + c0 + t] = v0;   // race-free: one slot per column
    partial[(size_t)rb1 * 256 + c0 + t] = v1;
  }
}

// reduce partials over 1024 r-blocks -> stats[128]; 16 blocks, each owns 16 columns
__global__ __launch_bounds__(256) void k_stat(const float* __restrict__ partial,
                                              float* __restrict__ st) {
  __shared__ float sm1[16][16];
  __shared__ float tot[16];
  const int bb = blockIdx.x;               // 0..15
  const int t = threadIdx.x;
  const int col16 = t & 15, rgrp = t >> 4; // 16 cols x 16 row-groups
  const int c = bb * 16 + col16;
  float s = 0.f;
  for (int r = rgrp; r < 1024; r += 16) s += partial[(size_t)r * 256 + c];
  sm1[rgrp][col16] = s;
  __syncthreads();
  if (t < 16) {
    float v = 0.f;
#pragma unroll
    for (int g = 0; g < 16; ++g) v += sm1[g][t];
    tot[t] = v;
  }
  __syncthreads();
  if (t < 4) {
    const int m = bb * 4 + t;
    st[m] = tot[4 * t];
    st[64 + m] = tot[4 * t + 1] + tot[4 * t + 2] + tot[4 * t + 3];
  }
}

// ---------------------------------------------------------------- BN + norm-activation + residual
__global__ void k_bnact(const float* __restrict__ y, const float* __restrict__ stats,
    const float* __restrict__ g0, const float* __restrict__ g1, bf16_t* __restrict__ hsh) {
  const int idx = blockIdx.x * 256 + threadIdx.x;  // r*32 + d8
  const int r = idx >> 5, d8 = idx & 31;
  const int m0 = d8 * 2, m1 = m0 + 1;
  const float i00 = g0[m0] / sqrtf(stats[m0] * (1.0f / 65536.0f) + kEps);
  const float i10 = g1[m0] / sqrtf(stats[64 + m0] * (1.0f / 65536.0f) + kEps);
  const float i01 = g0[m1] / sqrtf(stats[m1] * (1.0f / 65536.0f) + kEps);
  const float i11 = g1[m1] / sqrtf(stats[64 + m1] * (1.0f / 65536.0f) + kEps);
  const float* yr = y + (size_t)r * 256 + d8 * 8;
  const float4 ya = *(const float4*)yr;
  const float4 yb = *(const float4*)(yr + 4);
  float a[8];
  {
    const float s = ya.x * i00;
    const float vx = ya.y * i10, vy = ya.z * i10, vz = ya.w * i10;
    const float so = s * sigmoidf(fabsf(s));
    const float vn = sqrtf(fmaf(vx, vx, fmaf(vy, vy, vz * vz)) + kEps);
    const float gv = sigmoidf(vn);
    a[0] = so; a[1] = vx * gv; a[2] = vy * gv; a[3] = vz * gv;
  }
  {
    const float s = yb.x * i01;
    const float vx = yb.y * i11, vy = yb.z * i11, vz = yb.w * i11;
    const float so = s * sigmoidf(fabsf(s));
    const float vn = sqrtf(fmaf(vx, vx, fmaf(vy, vy, vz * vz)) + kEps);
    const float gv = sigmoidf(vn);
    a[4] = so; a[5] = vx * gv; a[6] = vy * gv; a[7] = vz * gv;
  }
  const size_t base = hidx(r, d8);
  U4 hi, lo;
  hi.u = *(const uint4*)(hsh + base);
  lo.u = *(const uint4*)(hsh + base + 512);
  U4 oh, ol;
#pragma unroll
  for (int i = 0; i < 8; ++i) {
    const float f = (float)hi.b[i] + (float)lo.b[i] + a[i];
    const bf16_t h_ = (bf16_t)f;
    oh.b[i] = h_; ol.b[i] = (bf16_t)(f - (float)h_);
  }
  *(uint4*)(hsh + base) = oh.u;
  *(uint4*)(hsh + base + 512) = ol.u;
}

// ---------------------------------------------------------------- mean-pool + einsum
__global__ __launch_bounds__(256) void k_pool(const bf16_t* __restrict__ hsh,
    const float* __restrict__ w_out, float* __restrict__ out) {
  __shared__ float r0s[256], r1s[256], r2s[256];
  const int b = blockIdx.x;
  const int t = threadIdx.x;
  float p0 = 0, p1 = 0, p2 = 0;
  for (int idx = t; idx < kN * 32; idx += 256) {
    const int n = idx >> 5, d8 = idx & 31;
    const int r = (b << 10) + n;
    const size_t base = hidx(r, d8);
    U4 hi, lo;
    hi.u = *(const uint4*)(hsh + base);
    lo.u = *(const uint4*)(hsh + base + 512);
    const float w0 = w_out[d8 * 2], w1 = w_out[d8 * 2 + 1];
    p0 += ((float)hi.b[1] + (float)lo.b[1]) * w0 + ((float)hi.b[5] + (float)lo.b[5]) * w1;
    p1 += ((float)hi.b[2] + (float)lo.b[2]) * w0 + ((float)hi.b[6] + (float)lo.b[6]) * w1;
    p2 += ((float)hi.b[3] + (float)lo.b[3]) * w0 + ((float)hi.b[7] + (float)lo.b[7]) * w1;
  }
  r0s[t] = p0; r1s[t] = p1; r2s[t] = p2;
  __syncthreads();
  for (int s = 128; s > 0; s >>= 1) {
    if (t < s) { r0s[t] += r0s[t + s]; r1s[t] += r1s[t + s]; r2s[t] += r2s[t + s]; }
    __syncthreads();
  }
  if (t == 0) {
    out[b * 3 + 0] = r0s[0] * (1.0f / kN);
    out[b * 3 + 1] = r1s[0] * (1.0f / kN);
    out[b * 3 + 2] = r2s[0] * (1.0f / kN);
  }
}

} // namespace

extern "C" void kernel_launch(void* const* d_in, const int* in_sizes, int n_in,
                              void* d_out, int out_size, void* d_ws, size_t ws_size,
                              hipStream_t stream) {
  const float* x       = (const float*)d_in[0];
  const float* tok_emb = (const float*)d_in[1];
  const float* Wf      = (const float*)d_in[2];
  const float* wv      = (const float*)d_in[3];
  const float* w_out   = (const float*)d_in[4];

  float* ws    = (float*)d_ws;
  bf16_t* hsh  = (bf16_t*)ws;                          // 33,554,432 bf16 = 16,777,216 fl
  float*  kvt  = ws + 16777216;                        // 23,592,960 fl
  float*  qt   = kvt + 23592960;                       // 23,592,960 fl
  float*  y    = qt;                                   // alias: qt dead once k_conv done
  float*  partial = qt + 20000000;                     // 262,144 fl inside qt region, past y end
  float*  s0   = qt + 23592960;                        //     65,536 fl
  float*  kf   = s0 + 65536;                           //    737,280 fl
  bf16_t* wall3 = (bf16_t*)(kf + 737280);              // 1,474,560 bf16
  bf16_t* WoF3  = wall3 + 1474560;                     // 3 x 196,608 bf16
  bf16_t* BtF3  = WoF3 + 589824;                       // 3 x 131,072 bf16
  float* stats = (float*)(BtF3 + 393216);              // 384 fl
  float* twg   = stats + 384;                          // 1,024 fl (512 float2)

  k_tw<<<2, 256, 0, stream>>>((float2*)twg);
  k_s0<<<kN, 64, 0, stream>>>(tok_emb, Wf, s0);
  k_h0<<<8192, 256, 0, stream>>>(x, wv, s0, hsh);
  k_wqkv3<<<dim3(384, 3), 256, 0, stream>>>(
      (const float*)d_in[5], (const float*)d_in[6], (const float*)d_in[7],
      (const float*)d_in[14], (const float*)d_in[15], (const float*)d_in[16],
      (const float*)d_in[23], (const float*)d_in[24], (const float*)d_in[25], wall3);
  k_wo3<<<dim3(256, 3), 384, 0, stream>>>(
      (const float*)d_in[9], (const float*)d_in[18], (const float*)d_in[27], WoF3);
  k_bt3<<<dim3(256, 3), 256, 0, stream>>>(
      (const float*)d_in[10], (const float*)d_in[11],
      (const float*)d_in[19], (const float*)d_in[20],
      (const float*)d_in[28], (const float*)d_in[29], BtF3);

  for (int l = 0; l < 3; ++l) {
    const float* filt = (const float*)d_in[5 + 9 * l + 3];
    const float* g0   = (const float*)d_in[5 + 9 * l + 7];
    const float* g1   = (const float*)d_in[5 + 9 * l + 8];
    const int H = (l == 2) ? 160 : 360;
    const int gy = (H + 63) / 64;                      // 6 or 3
    const int KT = gy * 2;                             // K chunks of 32 (zero-padded weights)
    bf16_t* wall = wall3 + ((l == 2) ? 1179648 : (size_t)l * 589824);
    bf16_t* WoF  = WoF3 + (size_t)l * 196608;
    bf16_t* BtF  = BtF3 + (size_t)l * 131072;
    float* st = stats + l * 128;

    k_kf<<<H, 256, 0, stream>>>(filt, H, (const float2*)twg, (float2*)kf);
    k_qkv<<<gy * 512, 256, 0, stream>>>(hsh, wall, H, qt, kvt);
    k_conv<<<32 * H, 256, 0, stream>>>(kvt, qt, (const float2*)kf, (const float2*)twg, H);
    k_mix<<<1024, 256, 0, stream>>>(kvt, H, KT, WoF, hsh);
    k_reg<<<2048, 256, 0, stream>>>(hsh, BtF, y, partial);
    k_stat<<<16, 256, 0, stream>>>(partial, st);
    k_bnact<<<8192, 256, 0, stream>>>(y, st, g0, g1, hsh);
  }

  k_pool<<<64, 256, 0, stream>>>(hsh, w_out, (float*)d_out);
}

// Round 13
// 1191.923 us; speedup vs baseline: 2.2160x; 1.0695x over previous
//
#include <hip/hip_runtime.h>
#include <math.h>

namespace {

typedef __bf16 bf16_t;
typedef bf16_t bf16x8 __attribute__((ext_vector_type(8)));
typedef float floatx4 __attribute__((ext_vector_type(4)));

constexpr int kN = 1024;      // tokens
constexpr int kM = 64;        // multiplicity
constexpr int kP = 64;        // PE dim
constexpr float kEps = 1e-5f;
constexpr int kFN = 1024;     // FFT length
constexpr size_t kYOFF = 16777216;   // ybf plane stride (bf16 elems)

__device__ __forceinline__ float sigmoidf(float v) { return 1.0f / (1.0f + expf(-v)); }

__device__ __forceinline__ floatx4 mfma16(bf16x8 a, bf16x8 b, floatx4 c) {
  return __builtin_amdgcn_mfma_f32_16x16x32_bf16(a, b, c, 0, 0, 0);
}

// 3-term split product: acc += (ah+al)*(bh+bl) dropping al*bl
__device__ __forceinline__ void fma3(floatx4& acc, bf16x8 ah, bf16x8 al,
                                     bf16x8 bh, bf16x8 bl) {
  acc = mfma16(ah, bh, acc);
  acc = mfma16(ah, bl, acc);
  acc = mfma16(al, bh, acc);
}

// load 8 contiguous fp32 (LDS), split into hi/lo bf16 fragments
__device__ __forceinline__ void load_split8(const float* p, bf16x8& hi, bf16x8& lo) {
  const float4 u = *(const float4*)p;
  const float4 v = *(const float4*)(p + 4);
  const float a[8] = {u.x, u.y, u.z, u.w, v.x, v.y, v.z, v.w};
#pragma unroll
  for (int i = 0; i < 8; ++i) {
    const bf16_t h_ = (bf16_t)a[i];
    hi[i] = h_;
    lo[i] = (bf16_t)(a[i] - (float)h_);
  }
}

union U4 { uint4 u; bf16_t b[8]; };
union Pk4 { uint2 u; bf16_t b[4]; };
union Ub2 { uint u; bf16_t b[2]; };

// async 16B/lane global->LDS DMA (wave-uniform LDS base + lane*16 scatter)
__device__ __forceinline__ void glds16(const bf16_t* g, bf16_t* l) {
  __builtin_amdgcn_global_load_lds(
      (const __attribute__((address_space(1))) void*)g,
      (__attribute__((address_space(3))) void*)l, 16, 0, 0);
}

// hsh fragment-major index for (row r, 8-elem group d8), hi plane (lo = +512)
__device__ __forceinline__ size_t hidx(int r, int d8) {
  const int rb = r >> 6, rr = r & 63;
  return (size_t)(rb * 8 + (d8 >> 2)) * 4096 + (rr >> 4) * 1024 + (d8 & 3) * 128 + (rr & 15) * 8;
}

// padded LDS index for FFT work array (breaks small-span bank conflicts)
__device__ __forceinline__ int zi(int i) { return i + (i >> 4); }

__device__ __forceinline__ float2 cadd(float2 a, float2 b) { return {a.x + b.x, a.y + b.y}; }
__device__ __forceinline__ float2 csub(float2 a, float2 b) { return {a.x - b.x, a.y - b.y}; }
__device__ __forceinline__ float2 cmul(float2 a, float2 w) {
  return {a.x * w.x - a.y * w.y, a.x * w.y + a.y * w.x};
}
__device__ __forceinline__ float2 cmulc(float2 a, float2 w) {   // a * conj(w)
  return {a.x * w.x + a.y * w.y, a.y * w.x - a.x * w.y};
}

// ---------------------------------------------------------------- init
__global__ void k_s0(const float* __restrict__ tok_emb, const float* __restrict__ Wf,
                     float* __restrict__ s0) {
  __shared__ float f[kP];
  const int n = blockIdx.x;
  const int t = threadIdx.x;                       // 64 threads
  const int tt = (n == kN - 1) ? 2 : (n & 1);
  const int j = t >> 1;
  const float cexp = (float)(-9.210340371976184 / 64.0);   // -ln(10000)/P
  const float divj = expf((float)(2 * j) * cexp);
  const float ang = (float)n * divj;
  const float pe = (t & 1) ? cosf(ang) : sinf(ang);
  f[t] = pe + tok_emb[tt * kP + t];
  __syncthreads();
  float acc = 0.0f;
#pragma unroll 8
  for (int p = 0; p < kP; ++p) acc = fmaf(f[p], Wf[p * kM + t], acc);
  s0[n * kM + t] = acc;
}

// h planes (fragment-major): irreps m0=d8*2, m1=m0+1 per thread
__global__ void k_h0(const float* __restrict__ x, const float* __restrict__ wv,
                     const float* __restrict__ s0, bf16_t* __restrict__ hsh) {
  const int idx = blockIdx.x * 256 + threadIdx.x;  // r*32 + d8
  const int r = idx >> 5, d8 = idx & 31;
  const int n = r & (kN - 1);
  const int m0 = d8 * 2, m1 = m0 + 1;
  const float w0 = wv[m0], w1 = wv[m1];
  const float x0 = x[r * 3 + 0], x1 = x[r * 3 + 1], x2 = x[r * 3 + 2];
  float f[8];
  f[0] = s0[n * kM + m0]; f[1] = x0 * w0; f[2] = x1 * w0; f[3] = x2 * w0;
  f[4] = s0[n * kM + m1]; f[5] = x0 * w1; f[6] = x1 * w1; f[7] = x2 * w1;
  U4 oh, ol;
#pragma unroll
  for (int i = 0; i < 8; ++i) {
    const bf16_t h_ = (bf16_t)f[i];
    oh.b[i] = h_; ol.b[i] = (bf16_t)(f[i] - (float)h_);
  }
  const size_t base = hidx(r, d8);
  *(uint4*)(hsh + base) = oh.u;
  *(uint4*)(hsh + base + 512) = ol.u;
}

// ---------------------------------------------------------------- weight prep (batched, all 3 layers)
__global__ void k_wqkv3(const float* __restrict__ Wq0, const float* __restrict__ Wk0,
                        const float* __restrict__ Wv0,
                        const float* __restrict__ Wq1, const float* __restrict__ Wk1,
                        const float* __restrict__ Wv1,
                        const float* __restrict__ Wq2, const float* __restrict__ Wk2,
                        const float* __restrict__ Wv2, bf16_t* __restrict__ wall3) {
  const int l = blockIdx.y;
  const int H = (l == 2) ? 160 : 360;
  const int gy = (l == 2) ? 3 : 6;
  const int c = blockIdx.x;    // 0..383
  if (c >= gy * 64) return;
  const int k = threadIdx.x;   // 0..255
  const float* Wq = (l == 0) ? Wq0 : ((l == 1) ? Wq1 : Wq2);
  const float* Wk = (l == 0) ? Wk0 : ((l == 1) ? Wk1 : Wk2);
  const float* Wv = (l == 0) ? Wv0 : ((l == 1) ? Wv1 : Wv2);
  bf16_t* wall = wall3 + ((l == 2) ? 1179648 : (size_t)l * 589824);
  const bool ok = c < H;
  const float w[3] = {ok ? Wq[k * H + c] : 0.f, ok ? Wk[k * H + c] : 0.f,
                      ok ? Wv[k * H + c] : 0.f};
  const int ct = c >> 6, cgrp = (c >> 4) & 3, cl = c & 15;
  const int kc = k >> 5, quad = (k >> 3) & 3, off = k & 7;
  const size_t base = (size_t)(ct * 8 + kc) * 12288 + cgrp * 512 + quad * 128 + cl * 8 + off;
#pragma unroll
  for (int mat = 0; mat < 3; ++mat) {
    const bf16_t hi = (bf16_t)w[mat];
    wall[base + mat * 4096] = hi;
    wall[base + mat * 4096 + 2048] = (bf16_t)(w[mat] - (float)hi);
  }
}

__global__ void k_wo3(const float* __restrict__ Wo0, const float* __restrict__ Wo1,
                      const float* __restrict__ Wo2, bf16_t* __restrict__ WoF3) {
  const int l = blockIdx.y;
  const int H = (l == 2) ? 160 : 360;
  const float* Wo = (l == 0) ? Wo0 : ((l == 1) ? Wo1 : Wo2);
  bf16_t* WoF = WoF3 + (size_t)l * 196608;
  const int d = blockIdx.x;    // 0..255
  const int c = threadIdx.x;   // 0..383
  const float w = (c < H) ? Wo[c * 256 + d] : 0.f;
  const int dt = d >> 6, dgrp = (d >> 4) & 3, dl = d & 15;
  const int kc = c >> 5, quad = (c >> 3) & 3, off = c & 7;
  const size_t base = (size_t)(dt * 12 + kc) * 4096 + dgrp * 512 + quad * 128 + dl * 8 + off;
  const bf16_t hi = (bf16_t)w;
  WoF[base] = hi;
  WoF[base + 2048] = (bf16_t)(w - (float)hi);
}

__global__ void k_bt3(const float* __restrict__ W00, const float* __restrict__ W10,
                      const float* __restrict__ W01, const float* __restrict__ W11,
                      const float* __restrict__ W02, const float* __restrict__ W12,
                      bf16_t* __restrict__ BtF3) {
  const int l = blockIdx.y;
  const float* W0 = (l == 0) ? W00 : ((l == 1) ? W01 : W02);
  const float* W1 = (l == 0) ? W10 : ((l == 1) ? W11 : W12);
  bf16_t* BtF = BtF3 + (size_t)l * 131072;
  const int col = blockIdx.x, row = threadIdx.x;
  const int k = col >> 2, ck = col & 3, m = row >> 2, cm = row & 3;
  float v = 0.f;
  if (cm == ck) v = (ck == 0 ? W0 : W1)[m * 64 + k];
  const int ct = col >> 6, cgrp = (col >> 4) & 3, cl = col & 15;
  const int kc = row >> 5, quad = (row >> 3) & 3, off = row & 7;
  const size_t base = (size_t)(ct * 8 + kc) * 4096 + cgrp * 512 + quad * 128 + cl * 8 + off;
  const bf16_t hi = (bf16_t)v;
  BtF[base] = hi;
  BtF[base + 2048] = (bf16_t)(v - (float)hi);
}

// ---------------------------------------------------------------- FFT (fused radix-2 pairs)
__global__ void k_tw(float2* __restrict__ twg) {
  const int j = blockIdx.x * 256 + threadIdx.x;
  if (j < kFN / 2) {
    float s, c;
    sincosf(-6.283185307179586f * (float)j / (float)kFN, &s, &c);
    twg[j].x = c; twg[j].y = s;
  }
}

// forward DIF, two radix-2 stages fused per barrier: natural in -> bit-reversed out
__device__ void fft_dif(float2* z, const float2* tw) {
  const int p = threadIdx.x;
#pragma unroll
  for (int m = 256; m >= 1; m >>= 2) {
    __syncthreads();
    const int pm = p & (m - 1);
    const int j = ((p & ~(m - 1)) << 2) | pm;
    const int tm2 = 512 / (2 * m), tm1 = 512 / m;
    const float2 x0 = z[zi(j)], x1 = z[zi(j + m)];
    const float2 x2 = z[zi(j + 2 * m)], x3 = z[zi(j + 3 * m)];
    const float2 w2 = tw[pm * tm2], w2b = tw[(pm + m) * tm2], w1 = tw[pm * tm1];
    const float2 a0 = cadd(x0, x2), a2 = cmul(csub(x0, x2), w2);
    const float2 a1 = cadd(x1, x3), a3 = cmul(csub(x1, x3), w2b);
    z[zi(j)]         = cadd(a0, a1);
    z[zi(j + m)]     = cmul(csub(a0, a1), w1);
    z[zi(j + 2 * m)] = cadd(a2, a3);
    z[zi(j + 3 * m)] = cmul(csub(a2, a3), w1);
  }
}

// inverse DIT, fused: bit-reversed in -> natural out (caller scales by 1/N)
__device__ void fft_dit_inv(float2* z, const float2* tw) {
  const int p = threadIdx.x;
#pragma unroll
  for (int m = 1; m <= 256; m <<= 2) {
    __syncthreads();
    const int pm = p & (m - 1);
    const int j = ((p & ~(m - 1)) << 2) | pm;
    const int tm2 = 512 / (2 * m), tm1 = 512 / m;
    const float2 x0 = z[zi(j)], x1 = z[zi(j + m)];
    const float2 x2 = z[zi(j + 2 * m)], x3 = z[zi(j + 3 * m)];
    const float2 w1 = tw[pm * tm1], w2 = tw[pm * tm2], w2b = tw[(pm + m) * tm2];
    const float2 c1 = cmulc(x1, w1), c3 = cmulc(x3, w1);
    const float2 b0 = cadd(x0, c1), b1 = csub(x0, c1);
    const float2 b2 = cadd(x2, c3), b3 = csub(x2, c3);
    const float2 d2 = cmulc(b2, w2), d3 = cmulc(b3, w2b);
    z[zi(j)]         = cadd(b0, d2);
    z[zi(j + 2 * m)] = csub(b0, d2);
    z[zi(j + m)]     = cadd(b1, d3);
    z[zi(j + 3 * m)] = csub(b1, d3);
  }
}

// filter spectra for ALL layers, DIF (bit-reversed) order; 880 blocks
__global__ __launch_bounds__(256) void k_kf3(const float* __restrict__ f0,
    const float* __restrict__ f1, const float* __restrict__ f2,
    const float2* __restrict__ twg, float2* __restrict__ kf3) {
  __shared__ float2 z[kFN + kFN / 16];
  __shared__ float2 tw[kFN / 2];
  const int bid = blockIdx.x;
  const int l = (bid < 360) ? 0 : ((bid < 720) ? 1 : 2);
  const int c = bid - ((l == 0) ? 0 : ((l == 1) ? 360 : 720));
  const int H = (l == 2) ? 160 : 360;
  const float* filt = (l == 0) ? f0 : ((l == 1) ? f1 : f2);
  float2* kf = kf3 + (size_t)l * 368640;
  for (int j = threadIdx.x; j < kFN / 2; j += 256) tw[j] = twg[j];
  for (int n = threadIdx.x; n < kFN; n += 256) {
    z[zi(n)].x = filt[n * H + c];
    z[zi(n)].y = 0.0f;
  }
  fft_dif(z, tw);
  __syncthreads();
  for (int j = threadIdx.x; j < kFN; j += 256) kf[c * kFN + j] = z[zi(j)];
}

// packed circular conv + fused q-product; bf16 inputs, fp32 FFT, fp32 prod out
__global__ __launch_bounds__(256) void k_conv(const bf16_t* __restrict__ kvb,
    const bf16_t* __restrict__ qb, float* __restrict__ prod,
    const float2* __restrict__ kf, const float2* __restrict__ twg, int H) {
  __shared__ float2 z[kFN + kFN / 16];
  __shared__ float2 tw[kFN / 2];
  const int blk = blockIdx.x;              // pb*H + c
  const int c = blk % H;
  const int pb = blk / H;
  const size_t off0 = ((size_t)((2 * pb) * H + c)) << 10;
  const size_t off1 = ((size_t)((2 * pb + 1) * H + c)) << 10;
  for (int j = threadIdx.x; j < kFN / 2; j += 256) tw[j] = twg[j];
  for (int n2 = threadIdx.x; n2 < 512; n2 += 256) {
    Ub2 a0, a1;
    a0.u = *(const uint*)(kvb + off0 + 2 * n2);
    a1.u = *(const uint*)(kvb + off1 + 2 * n2);
    z[zi(2 * n2)].x = (float)a0.b[0];     z[zi(2 * n2)].y = (float)a1.b[0];
    z[zi(2 * n2 + 1)].x = (float)a0.b[1]; z[zi(2 * n2 + 1)].y = (float)a1.b[1];
  }
  fft_dif(z, tw);
  __syncthreads();
  for (int j = threadIdx.x; j < kFN; j += 256) {
    const float2 a = z[zi(j)];
    const float2 b = kf[c * kFN + j];
    float2 o;
    o.x = a.x * b.x - a.y * b.y;
    o.y = a.x * b.y + a.y * b.x;
    z[zi(j)] = o;
  }
  fft_dit_inv(z, tw);
  __syncthreads();
  const float s = 1.0f / (float)kFN;
  for (int n2 = threadIdx.x; n2 < 512; n2 += 256) {
    Ub2 q0, q1;
    q0.u = *(const uint*)(qb + off0 + 2 * n2);
    q1.u = *(const uint*)(qb + off1 + 2 * n2);
    float2 p0, p1;
    p0.x = (z[zi(2 * n2)].x * s) * (float)q0.b[0];
    p0.y = (z[zi(2 * n2 + 1)].x * s) * (float)q0.b[1];
    p1.x = (z[zi(2 * n2)].y * s) * (float)q1.b[0];
    p1.y = (z[zi(2 * n2 + 1)].y * s) * (float)q1.b[1];
    *(float2*)(prod + off0 + 2 * n2) = p0;
    *(float2*)(prod + off1 + 2 * n2) = p1;
  }
}

// ---------------------------------------------------------------- GEMM 1 (split MFMA, LDS-DMA): q/k/v
// 128x64 tile (2 rb per block), XCD-swizzled; bf16 outputs
__global__ __launch_bounds__(256) void k_qkv(const bf16_t* __restrict__ hsh,
    const bf16_t* __restrict__ wall, int H,
    bf16_t* __restrict__ qtb, bf16_t* __restrict__ kvb) {
  __shared__ bf16_t lds[20480];            // 40 KB: A0 8K + A1 8K + B 24K
  const int gy = (H + 63) >> 6;
  const int bid = blockIdx.x;
  const int xcd = bid & 7, sseq = bid >> 3;
  const int ct = sseq % gy;
  const int rb2 = (sseq / gy) * 8 + xcd;
  const int rb0 = rb2 * 2, rb1 = rb0 + 1;
  const int t = threadIdx.x;
  const int lane = t & 63, wave = t >> 6;
  const int l15 = lane & 15, quad = lane >> 4;
  const int c0 = ct * 64;
  const int wr = (wave & 1) * 32, wc = (wave >> 1) * 32;
  const int wr16 = (wave & 1) * 2, wc16 = (wave >> 1) * 2;
  const int q128l = quad * 128 + l15 * 8;
  floatx4 aq[2][2][2] = {}, ak_[2][2][2] = {}, av_[2][2][2] = {};   // [rbx][i][j]
  for (int kt = 0; kt < 8; ++kt) {
    {
      const bf16_t* A0 = hsh + (size_t)(rb0 * 8 + kt) * 4096;
      const bf16_t* A1 = hsh + (size_t)(rb1 * 8 + kt) * 4096;
      const bf16_t* Bs = wall + (size_t)(ct * 8 + kt) * 12288;
#pragma unroll
      for (int s = 0; s < 10; ++s) {
        const int seg = wave * 10 + s;
        const bf16_t* src = (seg < 8) ? (A0 + seg * 512)
                          : (seg < 16) ? (A1 + (seg - 8) * 512)
                                       : (Bs + (seg - 16) * 512);
        glds16(src + lane * 8, &lds[seg * 512]);
      }
    }
    __syncthreads();
    bf16x8 ah[2][2], al[2][2];             // [rbx][i]
#pragma unroll
    for (int rbx = 0; rbx < 2; ++rbx)
#pragma unroll
      for (int i = 0; i < 2; ++i) {
        ah[rbx][i] = *(const bf16x8*)(lds + rbx * 4096 + ((wr16 + i) * 2 + 0) * 512 + q128l);
        al[rbx][i] = *(const bf16x8*)(lds + rbx * 4096 + ((wr16 + i) * 2 + 1) * 512 + q128l);
      }
#pragma unroll
    for (int mat = 0; mat < 3; ++mat) {
      const int bb = 8192 + mat * 4096;
#pragma unroll
      for (int j = 0; j < 2; ++j) {
        const bf16x8 bh = *(const bf16x8*)(lds + bb + (wc16 + j) * 512 + q128l);
        const bf16x8 bl = *(const bf16x8*)(lds + bb + 2048 + (wc16 + j) * 512 + q128l);
#pragma unroll
        for (int rbx = 0; rbx < 2; ++rbx)
#pragma unroll
          for (int i = 0; i < 2; ++i) {
            floatx4& a = (mat == 0) ? aq[rbx][i][j]
                       : (mat == 1) ? ak_[rbx][i][j] : av_[rbx][i][j];
            fma3(a, ah[rbx][i], al[rbx][i], bh, bl);
          }
      }
    }
    __syncthreads();
  }
#pragma unroll
  for (int rbx = 0; rbx < 2; ++rbx) {
    const int r0 = (rb0 + rbx) * 64;
    const int b = r0 >> 10;
    const int n0 = r0 & 1023;
#pragma unroll
    for (int j = 0; j < 2; ++j) {
      const int c = c0 + wc + j * 16 + l15;
      if (c < H) {
        const size_t rbw = (((size_t)(b * H + c)) << 10) + n0 + wr + quad * 4;
#pragma unroll
        for (int i = 0; i < 2; ++i) {
          Pk4 pq, pk;
#pragma unroll
          for (int r = 0; r < 4; ++r) {
            pq.b[r] = (bf16_t)aq[rbx][i][j][r];
            pk.b[r] = (bf16_t)(ak_[rbx][i][j][r] * av_[rbx][i][j][r]);
          }
          *(uint2*)(qtb + rbw + i * 16) = pq.u;
          *(uint2*)(kvb + rbw + i * 16) = pk.u;
        }
      }
    }
  }
}

// ---------------------------------------------------------------- GEMM 2 (split MFMA): h += prod @ Wo
// one block per 64-row strip, all 256 output cols
__global__ __launch_bounds__(256) void k_mix(const float* __restrict__ pv, int H, int KT,
    const bf16_t* __restrict__ WoF, bf16_t* __restrict__ hsh) {
  __shared__ float smem[4352];             // staging 64x36 (2304) / epilogue 64x68 (aliased)
  const int r0 = blockIdx.x * 64;
  const int t = threadIdx.x;
  const int lane = t & 63, wave = t >> 6;
  const int l15 = lane & 15, quad = lane >> 4;
  const int b = r0 >> 10, n0 = r0 & 1023;
  const int wr = (wave & 1) * 32, wh = wave >> 1;
  const int q128l = quad * 128 + l15 * 8;
  floatx4 acc[2][8] = {};                  // [i][j]: rows wr+i*16, col tile wh*8+j
  const int cl = t >> 3, n8 = (t & 7) * 8;
  for (int kt = 0; kt < KT; ++kt) {
    const int ck0 = kt * 32;
    __syncthreads();
    {
      const int c = ck0 + cl;
      float p[8] = {};
      if (c < H) {
        const size_t o = (((size_t)(b * H + c)) << 10) + n0 + n8;
        const float4 p0 = *(const float4*)(pv + o);
        const float4 p1 = *(const float4*)(pv + o + 4);
        p[0] = p0.x; p[1] = p0.y; p[2] = p0.z; p[3] = p0.w;
        p[4] = p1.x; p[5] = p1.y; p[6] = p1.z; p[7] = p1.w;
      }
#pragma unroll
      for (int u = 0; u < 8; ++u) smem[(n8 + u) * 36 + cl] = p[u];
    }
    __syncthreads();
    bf16x8 ah0, al0, ah1, al1;
    load_split8(smem + (wr + l15) * 36 + quad * 8, ah0, al0);
    load_split8(smem + (wr + 16 + l15) * 36 + quad * 8, ah1, al1);
#pragma unroll
    for (int j = 0; j < 8; ++j) {
      const int jj = wh * 8 + j;           // global 16-col tile 0..15
      const int dt = jj >> 2, dgrp = jj & 3;
      const bf16_t* Bb = WoF + (size_t)(dt * 12 + kt) * 4096 + dgrp * 512 + q128l;
      const bf16x8 bh = *(const bf16x8*)Bb;
      const bf16x8 bl = *(const bf16x8*)(Bb + 2048);
      fma3(acc[0][j], ah0, al0, bh, bl);
      fma3(acc[1][j], ah1, al1, bh, bl);
    }
  }
  // epilogue: 4 passes over 64-col groups through the shared buffer
  const int nl = t >> 2, q4 = t & 3;
  const int r = r0 + nl;
#pragma unroll
  for (int g = 0; g < 4; ++g) {
    __syncthreads();
    if (wh == (g >> 1)) {
#pragma unroll
      for (int jl = 0; jl < 4; ++jl) {
        const int j = (g & 1) * 4 + jl;
#pragma unroll
        for (int i = 0; i < 2; ++i)
#pragma unroll
          for (int rr = 0; rr < 4; ++rr)
            smem[(wr + i * 16 + quad * 4 + rr) * 68 + jl * 16 + l15] = acc[i][j][rr];
      }
    }
    __syncthreads();
#pragma unroll
    for (int u8 = 0; u8 < 2; ++u8) {
      const int d8 = g * 8 + q4 * 2 + u8;
      const size_t base = hidx(r, d8);
      U4 hi, lo;
      hi.u = *(const uint4*)(hsh + base);
      lo.u = *(const uint4*)(hsh + base + 512);
      U4 oh, ol;
#pragma unroll
      for (int i = 0; i < 8; ++i) {
        const float f = (float)hi.b[i] + (float)lo.b[i] +
                        smem[nl * 68 + (q4 * 2 + u8) * 8 + i];
        const bf16_t h_ = (bf16_t)f;
        oh.b[i] = h_; ol.b[i] = (bf16_t)(f - (float)h_);
      }
      *(uint4*)(hsh + base) = oh.u;
      *(uint4*)(hsh + base + 512) = ol.u;
    }
  }
}

// ---------------------------------------------------------------- GEMM 3 (split MFMA, LDS-DMA): reg_linear + BN partials
// 128x64 tile (2 rb per block), XCD-swizzled; y output as split-bf16
__global__ __launch_bounds__(256) void k_reg(const bf16_t* __restrict__ hsh,
    const bf16_t* __restrict__ BtF,
    bf16_t* __restrict__ ybf, float* __restrict__ partial) {
  __shared__ float smf[6144];              // 24 KB: DMA staging / epilogue alias
  __shared__ float red[256];
  bf16_t* lds = (bf16_t*)smf;
  const int bid = blockIdx.x;
  const int xcd = bid & 7, sseq = bid >> 3;
  const int ct = sseq & 3;
  const int rb2 = (sseq >> 2) * 8 + xcd;
  const int rb0 = rb2 * 2, rb1 = rb0 + 1;
  const int t = threadIdx.x;
  const int lane = t & 63, wave = t >> 6;
  const int l15 = lane & 15, quad = lane >> 4;
  const int c0 = ct * 64;
  const int wr = (wave & 1) * 32, wc = (wave >> 1) * 32;
  const int wr16 = (wave & 1) * 2, wc16 = (wave >> 1) * 2;
  const int q128l = quad * 128 + l15 * 8;
  floatx4 acc[2][2][2] = {};               // [rbx][i][j]
  for (int kt = 0; kt < 8; ++kt) {
    {
      const bf16_t* A0 = hsh + (size_t)(rb0 * 8 + kt) * 4096;
      const bf16_t* A1 = hsh + (size_t)(rb1 * 8 + kt) * 4096;
      const bf16_t* Bs = BtF + (size_t)(ct * 8 + kt) * 4096;
#pragma unroll
      for (int s = 0; s < 6; ++s) {
        const int seg = wave * 6 + s;
        const bf16_t* src = (seg < 8) ? (A0 + seg * 512)
                          : (seg < 16) ? (A1 + (seg - 8) * 512)
                                       : (Bs + (seg - 16) * 512);
        glds16(src + lane * 8, &lds[seg * 512]);
      }
    }
    __syncthreads();
    bf16x8 ah[2][2], al[2][2];
#pragma unroll
    for (int rbx = 0; rbx < 2; ++rbx)
#pragma unroll
      for (int i = 0; i < 2; ++i) {
        ah[rbx][i] = *(const bf16x8*)(lds + rbx * 4096 + ((wr16 + i) * 2 + 0) * 512 + q128l);
        al[rbx][i] = *(const bf16x8*)(lds + rbx * 4096 + ((wr16 + i) * 2 + 1) * 512 + q128l);
      }
#pragma unroll
    for (int j = 0; j < 2; ++j) {
      const bf16x8 bh = *(const bf16x8*)(lds + 8192 + (wc16 + j) * 512 + q128l);
      const bf16x8 bl = *(const bf16x8*)(lds + 8192 + 2048 + (wc16 + j) * 512 + q128l);
#pragma unroll
      for (int rbx = 0; rbx < 2; ++rbx)
#pragma unroll
        for (int i = 0; i < 2; ++i)
          fma3(acc[rbx][i][j], ah[rbx][i], al[rbx][i], bh, bl);
    }
    __syncthreads();
  }
  // per-column sum of squares, per rb
#pragma unroll
  for (int rbx = 0; rbx < 2; ++rbx)
#pragma unroll
    for (int j = 0; j < 2; ++j) {
      float s = 0.f;
#pragma unroll
      for (int i = 0; i < 2; ++i)
#pragma unroll
        for (int r = 0; r < 4; ++r)
          s = fmaf(acc[rbx][i][j][r], acc[rbx][i][j][r], s);
      s += __shfl_down(s, 32);
      s += __shfl_down(s, 16);
      if (lane < 16) red[rbx * 128 + wave * 32 + j * 16 + lane] = s;
    }
  // epilogue per rb
#pragma unroll
  for (int rbx = 0; rbx < 2; ++rbx) {
    __syncthreads();
#pragma unroll
    for (int i = 0; i < 2; ++i)
#pragma unroll
      for (int j = 0; j < 2; ++j)
#pragma unroll
        for (int r = 0; r < 4; ++r)
          smf[(wr + i * 16 + quad * 4 + r) * 68 + wc + j * 16 + l15] = acc[rbx][i][j][r];
    __syncthreads();
    const int nl = t >> 2, q4 = t & 3;
    const int r0 = (rb0 + rbx) * 64;
    const size_t gi = (size_t)(r0 + nl) * 256 + c0 + q4 * 16;
#pragma unroll
    for (int u2 = 0; u2 < 2; ++u2) {
      U4 oh, ol;
#pragma unroll
      for (int i = 0; i < 8; ++i) {
        const float f = smf[nl * 68 + q4 * 16 + u2 * 8 + i];
        const bf16_t h_ = (bf16_t)f;
        oh.b[i] = h_; ol.b[i] = (bf16_t)(f - (float)h_);
      }
      *(uint4*)(ybf + gi + u2 * 8) = oh.u;
      *(uint4*)(ybf + kYOFF + gi + u2 * 8) = ol.u;
    }
  }
  if (t < 64) {
    const int w0 = (t >= 32) ? 2 : 0;
    const float v0 = red[w0 * 32 + (t & 31)] + red[(w0 + 1) * 32 + (t & 31)];
    const float v1 = red[128 + w0 * 32 + (t & 31)] + red[128 + (w0 + 1) * 32 + (t & 31)];
    partial[(size_t)rb0 * 256 + c0 + t] = v0;   // race-free: one slot per column
    partial[(size_t)rb1 * 256 + c0 + t] = v1;
  }
}

// reduce partials over 1024 r-blocks -> stats[128]; 16 blocks, each owns 16 columns
__global__ __launch_bounds__(256) void k_stat(const float* __restrict__ partial,
                                              float* __restrict__ st) {
  __shared__ float sm1[16][16];
  __shared__ float tot[16];
  const int bb = blockIdx.x;               // 0..15
  const int t = threadIdx.x;
  const int col16 = t & 15, rgrp = t >> 4;
  const int c = bb * 16 + col16;
  float s = 0.f;
  for (int r = rgrp; r < 1024; r += 16) s += partial[(size_t)r * 256 + c];
  sm1[rgrp][col16] = s;
  __syncthreads();
  if (t < 16) {
    float v = 0.f;
#pragma unroll
    for (int g = 0; g < 16; ++g) v += sm1[g][t];
    tot[t] = v;
  }
  __syncthreads();
  if (t < 4) {
    const int m = bb * 4 + t;
    st[m] = tot[4 * t];
    st[64 + m] = tot[4 * t + 1] + tot[4 * t + 2] + tot[4 * t + 3];
  }
}

// ---------------------------------------------------------------- BN + norm-activation + residual
__global__ void k_bnact(const bf16_t* __restrict__ ybf, const float* __restrict__ stats,
    const float* __restrict__ g0, const float* __restrict__ g1, bf16_t* __restrict__ hsh) {
  const int idx = blockIdx.x * 256 + threadIdx.x;  // r*32 + d8
  const int r = idx >> 5, d8 = idx & 31;
  const int m0 = d8 * 2, m1 = m0 + 1;
  const float i00 = g0[m0] / sqrtf(stats[m0] * (1.0f / 65536.0f) + kEps);
  const float i10 = g1[m0] / sqrtf(stats[64 + m0] * (1.0f / 65536.0f) + kEps);
  const float i01 = g0[m1] / sqrtf(stats[m1] * (1.0f / 65536.0f) + kEps);
  const float i11 = g1[m1] / sqrtf(stats[64 + m1] * (1.0f / 65536.0f) + kEps);
  const size_t ye = (size_t)r * 256 + d8 * 8;
  U4 yh, yl;
  yh.u = *(const uint4*)(ybf + ye);
  yl.u = *(const uint4*)(ybf + kYOFF + ye);
  float yv[8];
#pragma unroll
  for (int i = 0; i < 8; ++i) yv[i] = (float)yh.b[i] + (float)yl.b[i];
  float a[8];
  {
    const float s = yv[0] * i00;
    const float vx = yv[1] * i10, vy = yv[2] * i10, vz = yv[3] * i10;
    const float so = s * sigmoidf(fabsf(s));
    const float vn = sqrtf(fmaf(vx, vx, fmaf(vy, vy, vz * vz)) + kEps);
    const float gv = sigmoidf(vn);
    a[0] = so; a[1] = vx * gv; a[2] = vy * gv; a[3] = vz * gv;
  }
  {
    const float s = yv[4] * i01;
    const float vx = yv[5] * i11, vy = yv[6] * i11, vz = yv[7] * i11;
    const float so = s * sigmoidf(fabsf(s));
    const float vn = sqrtf(fmaf(vx, vx, fmaf(vy, vy, vz * vz)) + kEps);
    const float gv = sigmoidf(vn);
    a[4] = so; a[5] = vx * gv; a[6] = vy * gv; a[7] = vz * gv;
  }
  const size_t base = hidx(r, d8);
  U4 hi, lo;
  hi.u = *(const uint4*)(hsh + base);
  lo.u = *(const uint4*)(hsh + base + 512);
  U4 oh, ol;
#pragma unroll
  for (int i = 0; i < 8; ++i) {
    const float f = (float)hi.b[i] + (float)lo.b[i] + a[i];
    const bf16_t h_ = (bf16_t)f;
    oh.b[i] = h_; ol.b[i] = (bf16_t)(f - (float)h_);
  }
  *(uint4*)(hsh + base) = oh.u;
  *(uint4*)(hsh + base + 512) = ol.u;
}

// ---------------------------------------------------------------- mean-pool + einsum
__global__ __launch_bounds__(256) void k_pool(const bf16_t* __restrict__ hsh,
    const float* __restrict__ w_out, float* __restrict__ out) {
  __shared__ float r0s[256], r1s[256], r2s[256];
  const int b = blockIdx.x;
  const int t = threadIdx.x;
  float p0 = 0, p1 = 0, p2 = 0;
  for (int idx = t; idx < kN * 32; idx += 256) {
    const int n = idx >> 5, d8 = idx & 31;
    const int r = (b << 10) + n;
    const size_t base = hidx(r, d8);
    U4 hi, lo;
    hi.u = *(const uint4*)(hsh + base);
    lo.u = *(const uint4*)(hsh + base + 512);
    const float w0 = w_out[d8 * 2], w1 = w_out[d8 * 2 + 1];
    p0 += ((float)hi.b[1] + (float)lo.b[1]) * w0 + ((float)hi.b[5] + (float)lo.b[5]) * w1;
    p1 += ((float)hi.b[2] + (float)lo.b[2]) * w0 + ((float)hi.b[6] + (float)lo.b[6]) * w1;
    p2 += ((float)hi.b[3] + (float)lo.b[3]) * w0 + ((float)hi.b[7] + (float)lo.b[7]) * w1;
  }
  r0s[t] = p0; r1s[t] = p1; r2s[t] = p2;
  __syncthreads();
  for (int s = 128; s > 0; s >>= 1) {
    if (t < s) { r0s[t] += r0s[t + s]; r1s[t] += r1s[t + s]; r2s[t] += r2s[t + s]; }
    __syncthreads();
  }
  if (t == 0) {
    out[b * 3 + 0] = r0s[0] * (1.0f / kN);
    out[b * 3 + 1] = r1s[0] * (1.0f / kN);
    out[b * 3 + 2] = r2s[0] * (1.0f / kN);
  }
}

} // namespace

extern "C" void kernel_launch(void* const* d_in, const int* in_sizes, int n_in,
                              void* d_out, int out_size, void* d_ws, size_t ws_size,
                              hipStream_t stream) {
  const float* x       = (const float*)d_in[0];
  const float* tok_emb = (const float*)d_in[1];
  const float* Wf      = (const float*)d_in[2];
  const float* wv      = (const float*)d_in[3];
  const float* w_out   = (const float*)d_in[4];

  float* ws    = (float*)d_ws;
  bf16_t* hsh  = (bf16_t*)ws;                          // 16,777,216 fl (2 bf16 planes)
  bf16_t* kvb  = (bf16_t*)(ws + 16777216);             // 23,592,960 bf16 = 11,796,480 fl
  bf16_t* qtb  = (bf16_t*)(ws + 28573696);             // 11,796,480 fl
  float*  prod = ws + 40370176;                        // 23,592,960 fl
  bf16_t* ybf  = (bf16_t*)prod;                        // alias: prod dead when y live (16.8M fl)
  float*  partial = prod + 20000000;                   // 262,144 fl inside prod region
  float*  s0   = prod + 23592960;                      //     65,536 fl
  float*  kf3  = s0 + 65536;                           //  1,802,240 fl (3 layers)
  bf16_t* wall3 = (bf16_t*)(kf3 + 1802240);            // 1,474,560 bf16
  bf16_t* WoF3  = wall3 + 1474560;                     // 3 x 196,608 bf16
  bf16_t* BtF3  = WoF3 + 589824;                       // 3 x 131,072 bf16
  float* stats = (float*)(BtF3 + 393216);              // 384 fl
  float* twg   = stats + 384;                          // 1,024 fl (512 float2)

  k_tw<<<2, 256, 0, stream>>>((float2*)twg);
  k_s0<<<kN, 64, 0, stream>>>(tok_emb, Wf, s0);
  k_h0<<<8192, 256, 0, stream>>>(x, wv, s0, hsh);
  k_wqkv3<<<dim3(384, 3), 256, 0, stream>>>(
      (const float*)d_in[5], (const float*)d_in[6], (const float*)d_in[7],
      (const float*)d_in[14], (const float*)d_in[15], (const float*)d_in[16],
      (const float*)d_in[23], (const float*)d_in[24], (const float*)d_in[25], wall3);
  k_wo3<<<dim3(256, 3), 384, 0, stream>>>(
      (const float*)d_in[9], (const float*)d_in[18], (const float*)d_in[27], WoF3);
  k_bt3<<<dim3(256, 3), 256, 0, stream>>>(
      (const float*)d_in[10], (const float*)d_in[11],
      (const float*)d_in[19], (const float*)d_in[20],
      (const float*)d_in[28], (const float*)d_in[29], BtF3);
  k_kf3<<<880, 256, 0, stream>>>(
      (const float*)d_in[8], (const float*)d_in[17], (const float*)d_in[26],
      (const float2*)twg, (float2*)kf3);

  for (int l = 0; l < 3; ++l) {
    const float* g0   = (const float*)d_in[5 + 9 * l + 7];
    const float* g1   = (const float*)d_in[5 + 9 * l + 8];
    const int H = (l == 2) ? 160 : 360;
    const int gy = (H + 63) / 64;                      // 6 or 3
    const int KT = gy * 2;                             // K chunks of 32 (zero-padded weights)
    bf16_t* wall = wall3 + ((l == 2) ? 1179648 : (size_t)l * 589824);
    bf16_t* WoF  = WoF3 + (size_t)l * 196608;
    bf16_t* BtF  = BtF3 + (size_t)l * 131072;
    const float2* kf = (const float2*)kf3 + (size_t)l * 368640;
    float* st = stats + l * 128;

    k_qkv<<<gy * 512, 256, 0, stream>>>(hsh, wall, H, qtb, kvb);
    k_conv<<<32 * H, 256, 0, stream>>>(kvb, qtb, prod, kf, (const float2*)twg, H);
    k_mix<<<1024, 256, 0, stream>>>(prod, H, KT, WoF, hsh);
    k_reg<<<2048, 256, 0, stream>>>(hsh, BtF, ybf, partial);
    k_stat<<<16, 256, 0, stream>>>(partial, st);
    k_bnact<<<8192, 256, 0, stream>>>(ybf, st, g0, g1, hsh);
  }

  k_pool<<<64, 256, 0, stream>>>(hsh, w_out, (float*)d_out);
}